// Round 9
// baseline (487.348 us; speedup 1.0000x reference)
//
#include <hip/hip_runtime.h>
#include <math.h>

#define BB 64
#define NN 197
#define HH 10
#define DD 64
#define CC 640
#define C3 1920
#define LR 64
#define MTOT (BB*NN)          // 12608
#define SCALE 0.125f

typedef unsigned short u16;
typedef __bf16 bf16x8 __attribute__((ext_vector_type(8)));
typedef float f32x4 __attribute__((ext_vector_type(4)));

__device__ __forceinline__ void split_bf16(float f, u16& hi, u16& lo) {
  unsigned u = __float_as_uint(f);
  unsigned r = u + 0x7FFF + ((u >> 16) & 1);
  u16 hb = (u16)(r >> 16);
  float fh = __uint_as_float((unsigned)hb << 16);
  float dl = f - fh;
  unsigned u2 = __float_as_uint(dl);
  unsigned r2 = u2 + 0x7FFF + ((u2 >> 16) & 1);
  hi = hb; lo = (u16)(r2 >> 16);
}

__device__ __forceinline__ u16 bf16rn(float f) {
  unsigned u = __float_as_uint(f);
  return (u16)((u + 0x7FFF + ((u >> 16) & 1)) >> 16);
}
__device__ __forceinline__ float bf16tof(u16 v) {
  return __uint_as_float((unsigned)v << 16);
}

// ---------------------------------------------------------------------------
// K1: w_eff = perm3(w_qkv + (lora_a @ lora_b)^T) -> bf16 hi/lo split
// ---------------------------------------------------------------------------
__global__ __launch_bounds__(256) void k_weff(
    const float* __restrict__ w_qkv, const float* __restrict__ la,
    const float* __restrict__ lb, u16* __restrict__ whi, u16* __restrict__ wlo) {
  int idx = blockIdx.x * 256 + threadIdx.x;      // covers 1920*640
  int i = idx / CC, j = idx % CC;
  int src = 3 * (i % CC) + (i / CC);
  float acc = w_qkv[(size_t)src * CC + j];
  const float* laj = la + (size_t)j * LR;
  const float* lbs = lb + src;
  #pragma unroll 8
  for (int r = 0; r < LR; ++r) acc = fmaf(laj[r], lbs[(size_t)r * C3], acc);
  u16 h, l; split_bf16(acc, h, l);
  whi[idx] = h; wlo[idx] = l;
}

// fp32 -> bf16 hi/lo split
__global__ __launch_bounds__(256) void k_cvt(
    const float* __restrict__ in, u16* __restrict__ hi, u16* __restrict__ lo, int n4) {
  int i = blockIdx.x * 256 + threadIdx.x;
  if (i >= n4) return;
  float4 v = ((const float4*)in)[i];
  float f[4] = {v.x, v.y, v.z, v.w};
  ushort4 H, L;
  u16 hh, ll;
  split_bf16(f[0], hh, ll); H.x = hh; L.x = ll;
  split_bf16(f[1], hh, ll); H.y = hh; L.y = ll;
  split_bf16(f[2], hh, ll); H.z = hh; L.z = ll;
  split_bf16(f[3], hh, ll); H.w = hh; L.w = ll;
  ((ushort4*)hi)[i] = H;
  ((ushort4*)lo)[i] = L;
}

__device__ __forceinline__ int perm640(int i) {
  return (i < 214) ? 3 * i : (i < 427 ? 3 * (i - 214) + 1 : 3 * (i - 427) + 2);
}

__global__ __launch_bounds__(256) void k_cvtw(
    const float* __restrict__ wp, u16* __restrict__ hi, u16* __restrict__ lo) {
  int idx = blockIdx.x * 256 + threadIdx.x;      // covers 640*640
  int i = idx / CC, j = idx % CC;
  float v = wp[(size_t)perm640(i) * CC + j];
  u16 h, l; split_bf16(v, h, l);
  hi[idx] = h; lo[idx] = l;
}

// tabK: rows 0..29 tkv, 30..59 tkh, 60..63 zero -> bf16 hi/lo [64][64]
__global__ __launch_bounds__(256) void k_prep(
    const float* __restrict__ tkv, const float* __restrict__ tkh,
    u16* __restrict__ thi, u16* __restrict__ tlo) {
  for (int idx = threadIdx.x; idx < 4096; idx += 256) {
    int row = idx >> 6, d = idx & 63;
    float v = row < 30 ? tkv[row * 64 + d] : (row < 60 ? tkh[(row - 30) * 64 + d] : 0.f);
    u16 hh, ll; split_bf16(v, hh, ll);
    thi[idx] = hh; tlo[idx] = ll;
  }
}

// ---------------------------------------------------------------------------
// Split-bf16 MFMA GEMM, fused 3-pass (hh, lh, hl per k-step). 128x128, BK=64.
// ---------------------------------------------------------------------------
template<int OSPLIT>
__global__ __launch_bounds__(256) void k_gemm_mfma(
    const u16* __restrict__ Ahi, const u16* __restrict__ Alo,
    const u16* __restrict__ Bhi, const u16* __restrict__ Blo,
    const float* __restrict__ bias, float* __restrict__ Cc,
    u16* __restrict__ Chi, u16* __restrict__ Clo,
    int M, int Nc) {
  __shared__ u16 AsH[128][64];
  __shared__ u16 AsL[128][64];
  __shared__ u16 BsH[128][64];
  __shared__ u16 BsL[128][64];
  int t = threadIdx.x, w = t >> 6, l = t & 63;
  int m0 = blockIdx.x * 128, n0 = blockIdx.y * 128;
  int wr = w >> 1, wc = w & 1;
  f32x4 acc[4][4] = {};
  int srow = l >> 3;
  int scol = (l & 7) * 8;

  for (int k0 = 0; k0 < 640; k0 += 64) {
    #pragma unroll
    for (int j = 0; j < 4; ++j) {
      int row = 32 * w + 8 * j + srow;
      int ga = m0 + row; if (ga >= M) ga = M - 1;
      size_t offA = (size_t)ga * 640 + k0 + scol;
      size_t offB = (size_t)(n0 + row) * 640 + k0 + scol;
      __builtin_amdgcn_global_load_lds(
          (const __attribute__((address_space(1))) void*)(Ahi + offA),
          (__attribute__((address_space(3))) void*)(&AsH[32 * w + 8 * j][0]), 16, 0, 0);
      __builtin_amdgcn_global_load_lds(
          (const __attribute__((address_space(1))) void*)(Alo + offA),
          (__attribute__((address_space(3))) void*)(&AsL[32 * w + 8 * j][0]), 16, 0, 0);
      __builtin_amdgcn_global_load_lds(
          (const __attribute__((address_space(1))) void*)(Bhi + offB),
          (__attribute__((address_space(3))) void*)(&BsH[32 * w + 8 * j][0]), 16, 0, 0);
      __builtin_amdgcn_global_load_lds(
          (const __attribute__((address_space(1))) void*)(Blo + offB),
          (__attribute__((address_space(3))) void*)(&BsL[32 * w + 8 * j][0]), 16, 0, 0);
    }
    __syncthreads();
    int fr = l & 15, fq = l >> 4;
    #pragma unroll
    for (int ks = 0; ks < 2; ++ks) {
      bf16x8 ah[4], al[4], bh[4], bl[4];
      #pragma unroll
      for (int mi = 0; mi < 4; ++mi) {
        ah[mi] = *(const bf16x8*)&AsH[wr * 64 + 16 * mi + fr][ks * 32 + fq * 8];
        al[mi] = *(const bf16x8*)&AsL[wr * 64 + 16 * mi + fr][ks * 32 + fq * 8];
        bh[mi] = *(const bf16x8*)&BsH[wc * 64 + 16 * mi + fr][ks * 32 + fq * 8];
        bl[mi] = *(const bf16x8*)&BsL[wc * 64 + 16 * mi + fr][ks * 32 + fq * 8];
      }
      #pragma unroll
      for (int mi = 0; mi < 4; ++mi)
        #pragma unroll
        for (int ni = 0; ni < 4; ++ni) {
          acc[mi][ni] = __builtin_amdgcn_mfma_f32_16x16x32_bf16(ah[mi], bh[ni], acc[mi][ni], 0, 0, 0);
          acc[mi][ni] = __builtin_amdgcn_mfma_f32_16x16x32_bf16(al[mi], bh[ni], acc[mi][ni], 0, 0, 0);
          acc[mi][ni] = __builtin_amdgcn_mfma_f32_16x16x32_bf16(ah[mi], bl[ni], acc[mi][ni], 0, 0, 0);
        }
    }
    __syncthreads();
  }

  int fr = l & 15, fq = l >> 4;
  #pragma unroll
  for (int mi = 0; mi < 4; ++mi) {
    #pragma unroll
    for (int ni = 0; ni < 4; ++ni) {
      int col = n0 + wc * 64 + 16 * ni + fr;
      float bv = bias[col];
      #pragma unroll
      for (int r = 0; r < 4; ++r) {
        int row = m0 + wr * 64 + 16 * mi + fq * 4 + r;
        if (row < M) {
          float val = acc[mi][ni][r] + bv;
          if (OSPLIT) {
            u16 hh, ll; split_bf16(val, hh, ll);
            Chi[(size_t)row * Nc + col] = hh;
            Clo[(size_t)row * Nc + col] = ll;
          } else {
            Cc[(size_t)row * Nc + col] = val;
          }
        }
      }
    }
  }
}

// ---------------------------------------------------------------------------
// Fused MFMA attention v5: 1024 threads = 16 waves = 4 waves/SIMD with ONE
// block/CU (occupancy by geometry; no 2-block requirement). k-split:
// wave = (qgrp 0..7, khalf 0..1); khalf0 owns score frags 0..8, khalf1 frags
// 9..12 + table frags 13..16. sacc[9] (36 regs) -> total regs fit <=128.
// Khi+Klo resident simultaneously (no serial restage). Softmax merged via
// mpart/spart LDS exchange. LDS 126,976 B:
//   [0,34816)        Akhi[272][64]u16 swz     | post-B2: mpart[128][2]f32 @0,
//   [34816,69632)    Aklo[272][64]u16 swz     |   spart @1024, P[128][224]u16
//   [69632,98304)    Vh[64][224]u16 swz       |   swz @4096, BvBh[128][32]bf16
//   [98304,106496)   TvT[64][64]bf16 swz      |   @61440
//   [106496,126976)  PvB[128] stride160 | post-B6: W[128][64]bf16 swz
// ---------------------------------------------------------------------------
__global__ __launch_bounds__(1024, 4) void k_attn(
    const u16* __restrict__ qkvhi, const u16* __restrict__ qkvlo,
    const u16* __restrict__ tabKhi, const u16* __restrict__ tabKlo,
    const float* __restrict__ tvv, const float* __restrict__ tvh,
    u16* __restrict__ ohi, u16* __restrict__ olo) {
  __shared__ __align__(16) unsigned char LDS[126976];
  unsigned char* Akhi = LDS;
  unsigned char* Aklo = LDS + 34816;
  unsigned char* Vh   = LDS + 69632;
  unsigned char* TvT  = LDS + 98304;
  unsigned char* PvB  = LDS + 106496;
  unsigned char* Wb   = LDS + 106496;
  float* mpart = (float*)LDS;
  float* spart = (float*)(LDS + 1024);
  unsigned char* Pm = LDS + 4096;
  u16* BvBh = (u16*)(LDS + 61440);

  int bh = blockIdx.x, b = bh / HH, h = bh % HH, qt = blockIdx.y;
  int t = threadIdx.x, w = t >> 6, l = t & 63;
  int fr = l & 15, fq = l >> 4;
  int qgrp = w & 7, kh = w >> 3;
  int q0 = 128 * qt;
  const size_t qbase = (size_t)(b * NN) * C3;

  // ---- staging: K hi+lo + tables (glds, pre-swizzled source) ----
  int kr = l >> 3;
  int chunk = ((l & 7) ^ (kr & 7)) * 8;
  for (int i = w; i < 34; i += 16) {
    int rr = 8 * i + kr;
    const u16 *sh, *sl;
    if (rr < 208) {
      int kk = rr > 196 ? 196 : rr;
      sh = qkvhi + qbase + (size_t)kk * C3 + CC + h * DD + chunk;
      sl = qkvlo + qbase + (size_t)kk * C3 + CC + h * DD + chunk;
    } else {
      int tr = rr - 208;
      sh = tabKhi + tr * 64 + chunk;
      sl = tabKlo + tr * 64 + chunk;
    }
    __builtin_amdgcn_global_load_lds(
        (const __attribute__((address_space(1))) void*)sh,
        (__attribute__((address_space(3))) void*)(Akhi + i * 1024), 16, 0, 0);
    __builtin_amdgcn_global_load_lds(
        (const __attribute__((address_space(1))) void*)sl,
        (__attribute__((address_space(3))) void*)(Aklo + i * 1024), 16, 0, 0);
  }
  // V^T hi [64d][224k] swz
  for (int idx = t; idx < 1576; idx += 1024) {
    int k = idx >> 3, d0v = (idx & 7) * 8;
    size_t off = qbase + (size_t)k * C3 + 2 * CC + h * DD + d0v;
    uint4 vh4 = *(const uint4*)(qkvhi + off);
    u16 eh[8] = {(u16)vh4.x, (u16)(vh4.x >> 16), (u16)vh4.y, (u16)(vh4.y >> 16),
                 (u16)vh4.z, (u16)(vh4.z >> 16), (u16)vh4.w, (u16)(vh4.w >> 16)};
    #pragma unroll
    for (int jj = 0; jj < 8; ++jj) {
      int d = d0v + jj;
      int byte = (d * 224 + k) * 2; byte ^= (((d & 7) ^ ((d >> 3) & 7)) << 4);
      *(u16*)(Vh + byte) = eh[jj];
    }
  }
  for (int idx = t; idx < 64 * 27; idx += 1024) {   // V pad cols 197..223
    int d = idx / 27, k = 197 + idx % 27;
    int byte = (d * 224 + k) * 2; byte ^= (((d & 7) ^ ((d >> 3) & 7)) << 4);
    *(u16*)(Vh + byte) = 0;
  }
  // TvT [64d][64t]
  for (int i = t; i < 4096; i += 1024) {
    int d = i >> 6, tt = i & 63;
    float vv = 0.f;
    if (tt < 30) vv = tvv[tt * 64 + d];
    else if (tt >= 32 && tt < 62) vv = tvh[(tt - 32) * 64 + d];
    int byte = (d * 64 + tt) * 2; byte ^= (((d & 7) ^ ((d >> 3) & 7)) << 4);
    *(u16*)(TvT + byte) = bf16rn(vv);
  }
  // Q frags
  bool active = (q0 + 16 * qgrp) < NN;
  bf16x8 qh[2], ql_[2];
  {
    int qg = q0 + 16 * qgrp + fr; int qc = qg > 196 ? 196 : qg;
    const u16* qr  = qkvhi + qbase + (size_t)qc * C3 + h * DD;
    const u16* qr2 = qkvlo + qbase + (size_t)qc * C3 + h * DD;
    qh[0]  = *(const bf16x8*)(qr + 8 * fq);
    qh[1]  = *(const bf16x8*)(qr + 32 + 8 * fq);
    ql_[0] = *(const bf16x8*)(qr2 + 8 * fq);
    ql_[1] = *(const bf16x8*)(qr2 + 32 + 8 * fq);
  }
  __syncthreads();   // B1: staging done

  // ---- S passes (3-pass split), own frags only ----
  f32x4 sacc[9] = {};
  if (active) {
    if (kh == 0) {
      #pragma unroll
      for (int ks = 0; ks < 2; ++ks)
        #pragma unroll
        for (int j = 0; j < 9; ++j) {
          int row = 16 * j + fr;
          int byte = row * 128 + 64 * ks + 16 * fq; byte ^= (row & 7) << 4;
          bf16x8 kf = *(const bf16x8*)(Akhi + byte);
          bf16x8 lf = *(const bf16x8*)(Aklo + byte);
          sacc[j] = __builtin_amdgcn_mfma_f32_16x16x32_bf16(qh[ks],  kf, sacc[j], 0, 0, 0);
          sacc[j] = __builtin_amdgcn_mfma_f32_16x16x32_bf16(ql_[ks], kf, sacc[j], 0, 0, 0);
          sacc[j] = __builtin_amdgcn_mfma_f32_16x16x32_bf16(qh[ks],  lf, sacc[j], 0, 0, 0);
        }
    } else {
      #pragma unroll
      for (int ks = 0; ks < 2; ++ks)
        #pragma unroll
        for (int j = 0; j < 8; ++j) {
          int row = 16 * (9 + j) + fr;
          int byte = row * 128 + 64 * ks + 16 * fq; byte ^= (row & 7) << 4;
          bf16x8 kf = *(const bf16x8*)(Akhi + byte);
          bf16x8 lf = *(const bf16x8*)(Aklo + byte);
          sacc[j] = __builtin_amdgcn_mfma_f32_16x16x32_bf16(qh[ks],  kf, sacc[j], 0, 0, 0);
          sacc[j] = __builtin_amdgcn_mfma_f32_16x16x32_bf16(ql_[ks], kf, sacc[j], 0, 0, 0);
          sacc[j] = __builtin_amdgcn_mfma_f32_16x16x32_bf16(qh[ks],  lf, sacc[j], 0, 0, 0);
        }
      // table frags (j 4..7 = nf 13..16) -> PvB (stride 160B, conflict-free)
      #pragma unroll
      for (int j = 4; j < 8; ++j)
        #pragma unroll
        for (int r = 0; r < 4; ++r) {
          int c = 16 * (j - 4) + fr;
          if (c < 60) {
            int row = 16 * qgrp + 4 * fq + r;
            *(u16*)(PvB + row * 160 + 2 * c) = bf16rn(sacc[j][r]);
          }
        }
    }
  }
  __syncthreads();   // B2: PvB ready, all K reads complete

  // ---- gather + partial max ----
  int nsc = kh ? 4 : 9;
  float mrow[4] = {-1e30f, -1e30f, -1e30f, -1e30f};
  if (active) {
    #pragma unroll
    for (int r = 0; r < 4; ++r) {
      int qrl = 16 * qgrp + 4 * fq + r;
      int qg = q0 + qrl;
      int qc = qg > 196 ? 196 : qg;
      int gq = (qc > 0) ? (qc - 1) / 14 : 0;
      int cq = (qc > 0) ? (qc - 1) % 14 : 0;
      for (int j = 0; j < 9; ++j) {
        if (j >= nsc) break;
        int k = 16 * (kh ? 9 + j : j) + fr;
        float s;
        if (k < 197) {
          int fv  = (qc == 0 || k == 0) ? 0 : ((k - 1) / 14 - gq + 15);
          int fh2 = (qc == 0 || k == 0) ? 0 : ((k - 1) % 14 - cq + 15);
          float pv = bf16tof(*(const u16*)(PvB + qrl * 160 + 2 * fv));
          float ph = bf16tof(*(const u16*)(PvB + qrl * 160 + 2 * (30 + fh2)));
          s = (sacc[j][r] + pv + ph) * SCALE;
        } else s = -1e30f;
        sacc[j][r] = s;
        mrow[r] = fmaxf(mrow[r], s);
      }
    }
    #pragma unroll
    for (int r = 0; r < 4; ++r)
      #pragma unroll
      for (int mk = 1; mk < 16; mk <<= 1) mrow[r] = fmaxf(mrow[r], __shfl_xor(mrow[r], mk));
    if (fr == 0) {
      #pragma unroll
      for (int r = 0; r < 4; ++r) mpart[(16 * qgrp + 4 * fq + r) * 2 + kh] = mrow[r];
    }
  }
  __syncthreads();   // B3: partial maxes ready

  // ---- exp (global max) + partial sum ----
  if (active) {
    float ssum[4] = {0.f, 0.f, 0.f, 0.f};
    #pragma unroll
    for (int r = 0; r < 4; ++r) {
      int qrl = 16 * qgrp + 4 * fq + r;
      float m = fmaxf(mpart[qrl * 2], mpart[qrl * 2 + 1]);
      for (int j = 0; j < 9; ++j) {
        if (j >= nsc) break;
        float e = __expf(sacc[j][r] - m);
        sacc[j][r] = e;
        ssum[r] += e;
      }
    }
    #pragma unroll
    for (int r = 0; r < 4; ++r)
      #pragma unroll
      for (int mk = 1; mk < 16; mk <<= 1) ssum[r] += __shfl_xor(ssum[r], mk);
    if (fr == 0) {
      #pragma unroll
      for (int r = 0; r < 4; ++r) spart[(16 * qgrp + 4 * fq + r) * 2 + kh] = ssum[r];
    }
  }
  __syncthreads();   // B4: partial sums ready

  // ---- P write (bf16, swz; zeros for invalid k / inactive rows) ----
  {
    float invr[4] = {0.f, 0.f, 0.f, 0.f};
    if (active) {
      #pragma unroll
      for (int r = 0; r < 4; ++r) {
        int qrl = 16 * qgrp + 4 * fq + r;
        invr[r] = 1.f / (spart[qrl * 2] + spart[qrl * 2 + 1]);
      }
    }
    int nwr = kh ? 5 : 9;       // kh1 also zero-fills frag 13 (k 208..223)
    for (int j = 0; j < 9; ++j) {
      if (j >= nwr) break;
      #pragma unroll
      for (int r = 0; r < 4; ++r) {
        int k = 16 * (kh ? 9 + j : j) + fr;
        int row = 16 * qgrp + 4 * fq + r;
        float p = 0.f;
        if (active && j < nsc && k < 197) p = sacc[j][r] * invr[r];
        int byte = (row * 448 + 2 * k); byte ^= (((row & 7) ^ ((row >> 3) & 7)) << 4);
        *(u16*)(Pm + byte) = bf16rn(p);
      }
    }
  }
  __syncthreads();   // B5: P ready everywhere

  // ---- AV (hi-only): wave (qf=qgrp, dh=kh) ----
  int prow = 16 * qgrp + fr;
  int pswz = ((prow & 7) ^ ((prow >> 3) & 7)) << 4;
  int vrow0 = 32 * kh + fr, vrow1 = vrow0 + 16;
  int vswz0 = ((vrow0 & 7) ^ ((vrow0 >> 3) & 7)) << 4;
  int vswz1 = ((vrow1 & 7) ^ ((vrow1 >> 3) & 7)) << 4;
  f32x4 ov0 = {}, ov1 = {};
  #pragma unroll
  for (int ks = 0; ks < 7; ++ks) {
    int co = 64 * ks + 16 * fq;
    bf16x8 pah = *(const bf16x8*)(Pm + ((prow * 448 + co) ^ pswz));
    bf16x8 v0  = *(const bf16x8*)(Vh + ((vrow0 * 448 + co) ^ vswz0));
    bf16x8 v1  = *(const bf16x8*)(Vh + ((vrow1 * 448 + co) ^ vswz1));
    ov0 = __builtin_amdgcn_mfma_f32_16x16x32_bf16(pah, v0, ov0, 0, 0, 0);
    ov1 = __builtin_amdgcn_mfma_f32_16x16x32_bf16(pah, v1, ov1, 0, 0, 0);
  }

  // bucket sums over P -> BvBh bf16 [128][32]
  for (int s = t; s < 3840; s += 1024) {
    int q = s / 30, rem = s % 30;
    int isH = rem >= 15 ? 1 : 0, a = rem - 15 * isH;
    int sw = ((q & 7) ^ ((q >> 3) & 7)) << 4;
    float acc = 0.f;
    if (a == 14) {
      acc = bf16tof(*(const u16*)(Pm + (((q * 448 + 0)) ^ sw)));
    } else if (!isH) {
      int k0b = 1 + 14 * a;
      #pragma unroll
      for (int j = 0; j < 14; ++j)
        acc += bf16tof(*(const u16*)(Pm + ((q * 448 + 2 * (k0b + j)) ^ sw)));
    } else {
      #pragma unroll
      for (int i2 = 0; i2 < 14; ++i2)
        acc += bf16tof(*(const u16*)(Pm + ((q * 448 + 2 * (1 + a + 14 * i2)) ^ sw)));
    }
    BvBh[q * 32 + 16 * isH + a] = bf16rn(acc);
  }
  __syncthreads();   // B6: BvBh ready; PvB dead since B3

  // ---- W build [128][64] bf16 (overlays PvB region) ----
  for (int i = t; i < 8192; i += 1024) {
    int q = i >> 6, tt = i & 63;
    int half = tt >> 5, u = tt & 31;
    int qg = q0 + q;
    float val = 0.f;
    if (qg == 0) {
      if (u == 0) {
        #pragma unroll
        for (int a = 0; a < 15; ++a) val += bf16tof(BvBh[q * 32 + 16 * half + a]);
      }
    } else if (qg < NN) {
      int m = qg - 1;
      int sel = half ? (m % 14) : (m / 14);
      if (u == 0) val = bf16tof(BvBh[q * 32 + 16 * half + 14]);
      else {
        int a = u - 15 + sel;
        if (a >= 0 && a < 14) val = bf16tof(BvBh[q * 32 + 16 * half + a]);
      }
    }
    int byte = (q * 128 + 2 * tt); byte ^= (((q & 7) ^ ((q >> 3) & 7)) << 4);
    *(u16*)(Wb + byte) = bf16rn(val);
  }
  __syncthreads();   // B7: W ready

  // ---- rel-v MFMA: out_rel = W @ TvT ----
  f32x4 rv0 = {}, rv1 = {};
  #pragma unroll
  for (int ks2 = 0; ks2 < 2; ++ks2) {
    int co = 64 * ks2 + 16 * fq;
    bf16x8 wa = *(const bf16x8*)(Wb + ((prow * 128 + co) ^ pswz));
    bf16x8 t0 = *(const bf16x8*)(TvT + ((vrow0 * 128 + co) ^ vswz0));
    bf16x8 t1 = *(const bf16x8*)(TvT + ((vrow1 * 128 + co) ^ vswz1));
    rv0 = __builtin_amdgcn_mfma_f32_16x16x32_bf16(wa, t0, rv0, 0, 0, 0);
    rv1 = __builtin_amdgcn_mfma_f32_16x16x32_bf16(wa, t1, rv1, 0, 0, 0);
  }

  // ---- store ----
  #pragma unroll
  for (int r = 0; r < 4; ++r) {
    int qrl = 16 * qgrp + 4 * fq + r;
    int qg = q0 + qrl;
    if (qg >= NN) continue;
    float o0 = ov0[r] + rv0[r];
    float o1 = ov1[r] + rv1[r];
    int d0 = 32 * kh + fr, d1 = d0 + 16;
    size_t ob = (size_t)(b * NN + qg) * CC + h * DD;
    u16 hh, ll;
    split_bf16(o0, hh, ll); ohi[ob + d0] = hh; olo[ob + d0] = ll;
    split_bf16(o1, hh, ll); ohi[ob + d1] = hh; olo[ob + d1] = ll;
  }
}

// ---------------------------------------------------------------------------
// Workspace (u16 units, 135.7 MB):
//   qkvhi 24,207,360 | qkvlo 24,207,360 | xhi/xlo 2x8,069,120 (reused ohi/olo)
//   weffhi/lo 2x1,228,800 | wphi/lo 2x409,600 | tabKhi/lo 2x4,096
// ---------------------------------------------------------------------------
extern "C" void kernel_launch(void* const* d_in, const int* in_sizes, int n_in,
                              void* d_out, int out_size, void* d_ws, size_t ws_size,
                              hipStream_t stream) {
  (void)in_sizes; (void)n_in; (void)out_size; (void)ws_size;
  const float* x     = (const float*)d_in[0];
  const float* w_qkv = (const float*)d_in[1];
  const float* b_qkv = (const float*)d_in[2];
  const float* la    = (const float*)d_in[3];
  const float* lb    = (const float*)d_in[4];
  const float* tkv   = (const float*)d_in[5];
  const float* tkh   = (const float*)d_in[6];
  const float* tvv   = (const float*)d_in[7];
  const float* tvh   = (const float*)d_in[8];
  const float* wp    = (const float*)d_in[9];
  const float* b_p   = (const float*)d_in[10];

  u16* qkvhi  = (u16*)d_ws;
  u16* qkvlo  = qkvhi + (size_t)24207360;
  u16* xhi    = qkvlo + (size_t)24207360;
  u16* xlo    = xhi + (size_t)8069120;
  u16* ohi    = xhi;                       // alias (x splits dead after gemm1)
  u16* olo    = xlo;
  u16* weffhi = xlo + (size_t)8069120;
  u16* wefflo = weffhi + (size_t)1228800;
  u16* wphi   = wefflo + (size_t)1228800;
  u16* wplo   = wphi + (size_t)409600;
  u16* tabKhi = wplo + (size_t)409600;
  u16* tabKlo = tabKhi + (size_t)4096;

  k_weff<<<(C3 * CC) / 256, 256, 0, stream>>>(w_qkv, la, lb, weffhi, wefflo);
  k_cvtw<<<(CC * CC) / 256, 256, 0, stream>>>(wp, wphi, wplo);
  k_prep<<<1, 256, 0, stream>>>(tkv, tkh, tabKhi, tabKlo);
  int n4x = (MTOT * CC) / 4;
  k_cvt<<<(n4x + 255) / 256, 256, 0, stream>>>(x, xhi, xlo, n4x);

  // qkv = x @ weff^T + b_qkv -> split bf16 output
  dim3 g1((MTOT + 127) / 128, C3 / 128);
  k_gemm_mfma<1><<<g1, dim3(256), 0, stream>>>(xhi, xlo, weffhi, wefflo, b_qkv,
                                               nullptr, qkvhi, qkvlo, MTOT, C3);

  // fused attention -> ohi/olo split
  k_attn<<<dim3(BB * HH, 2), 1024, 0, stream>>>(qkvhi, qkvlo, tabKhi, tabKlo,
                                                tvv, tvh, ohi, olo);

  // out = o @ perm3(w_proj)^T + b_proj
  dim3 g2((MTOT + 127) / 128, CC / 128);
  k_gemm_mfma<0><<<g2, dim3(256), 0, stream>>>(ohi, olo, wphi, wplo, b_p,
                                               (float*)d_out, nullptr, nullptr, MTOT, CC);
}

// Round 10
// 355.949 us; speedup vs baseline: 1.3692x; 1.3692x over previous
//
#include <hip/hip_runtime.h>
#include <math.h>

#define BB 64
#define NN 197
#define HH 10
#define DD 64
#define CC 640
#define C3 1920
#define LR 64
#define MTOT (BB*NN)          // 12608
#define SCALE 0.125f

typedef unsigned short u16;
typedef __bf16 bf16x8 __attribute__((ext_vector_type(8)));
typedef float f32x4 __attribute__((ext_vector_type(4)));

__device__ __forceinline__ void split_bf16(float f, u16& hi, u16& lo) {
  unsigned u = __float_as_uint(f);
  unsigned r = u + 0x7FFF + ((u >> 16) & 1);
  u16 hb = (u16)(r >> 16);
  float fh = __uint_as_float((unsigned)hb << 16);
  float dl = f - fh;
  unsigned u2 = __float_as_uint(dl);
  unsigned r2 = u2 + 0x7FFF + ((u2 >> 16) & 1);
  hi = hb; lo = (u16)(r2 >> 16);
}

__device__ __forceinline__ u16 bf16rn(float f) {
  unsigned u = __float_as_uint(f);
  return (u16)((u + 0x7FFF + ((u >> 16) & 1)) >> 16);
}
__device__ __forceinline__ float bf16tof(u16 v) {
  return __uint_as_float((unsigned)v << 16);
}

// ---------------------------------------------------------------------------
// K1: w_eff = perm3(w_qkv + (lora_a @ lora_b)^T) -> bf16 hi/lo split
// ---------------------------------------------------------------------------
__global__ __launch_bounds__(256) void k_weff(
    const float* __restrict__ w_qkv, const float* __restrict__ la,
    const float* __restrict__ lb, u16* __restrict__ whi, u16* __restrict__ wlo) {
  int idx = blockIdx.x * 256 + threadIdx.x;      // covers 1920*640
  int i = idx / CC, j = idx % CC;
  int src = 3 * (i % CC) + (i / CC);
  float acc = w_qkv[(size_t)src * CC + j];
  const float* laj = la + (size_t)j * LR;
  const float* lbs = lb + src;
  #pragma unroll 8
  for (int r = 0; r < LR; ++r) acc = fmaf(laj[r], lbs[(size_t)r * C3], acc);
  u16 h, l; split_bf16(acc, h, l);
  whi[idx] = h; wlo[idx] = l;
}

// fp32 -> bf16 hi/lo split
__global__ __launch_bounds__(256) void k_cvt(
    const float* __restrict__ in, u16* __restrict__ hi, u16* __restrict__ lo, int n4) {
  int i = blockIdx.x * 256 + threadIdx.x;
  if (i >= n4) return;
  float4 v = ((const float4*)in)[i];
  float f[4] = {v.x, v.y, v.z, v.w};
  ushort4 H, L;
  u16 hh, ll;
  split_bf16(f[0], hh, ll); H.x = hh; L.x = ll;
  split_bf16(f[1], hh, ll); H.y = hh; L.y = ll;
  split_bf16(f[2], hh, ll); H.z = hh; L.z = ll;
  split_bf16(f[3], hh, ll); H.w = hh; L.w = ll;
  ((ushort4*)hi)[i] = H;
  ((ushort4*)lo)[i] = L;
}

__device__ __forceinline__ int perm640(int i) {
  return (i < 214) ? 3 * i : (i < 427 ? 3 * (i - 214) + 1 : 3 * (i - 427) + 2);
}

__global__ __launch_bounds__(256) void k_cvtw(
    const float* __restrict__ wp, u16* __restrict__ hi, u16* __restrict__ lo) {
  int idx = blockIdx.x * 256 + threadIdx.x;      // covers 640*640
  int i = idx / CC, j = idx % CC;
  float v = wp[(size_t)perm640(i) * CC + j];
  u16 h, l; split_bf16(v, h, l);
  hi[idx] = h; lo[idx] = l;
}

// tabK: rows 0..29 tkv, 30..59 tkh, 60..63 zero -> bf16 hi/lo [64][64]
__global__ __launch_bounds__(256) void k_prep(
    const float* __restrict__ tkv, const float* __restrict__ tkh,
    u16* __restrict__ thi, u16* __restrict__ tlo) {
  for (int idx = threadIdx.x; idx < 4096; idx += 256) {
    int row = idx >> 6, d = idx & 63;
    float v = row < 30 ? tkv[row * 64 + d] : (row < 60 ? tkh[(row - 30) * 64 + d] : 0.f);
    u16 hh, ll; split_bf16(v, hh, ll);
    thi[idx] = hh; tlo[idx] = ll;
  }
}

// ---------------------------------------------------------------------------
// Split-bf16 MFMA GEMM, fused 3-pass (hh, lh, hl per k-step). 128x128, BK=64.
// ---------------------------------------------------------------------------
template<int OSPLIT>
__global__ __launch_bounds__(256) void k_gemm_mfma(
    const u16* __restrict__ Ahi, const u16* __restrict__ Alo,
    const u16* __restrict__ Bhi, const u16* __restrict__ Blo,
    const float* __restrict__ bias, float* __restrict__ Cc,
    u16* __restrict__ Chi, u16* __restrict__ Clo,
    int M, int Nc) {
  __shared__ u16 AsH[128][64];
  __shared__ u16 AsL[128][64];
  __shared__ u16 BsH[128][64];
  __shared__ u16 BsL[128][64];
  int t = threadIdx.x, w = t >> 6, l = t & 63;
  int m0 = blockIdx.x * 128, n0 = blockIdx.y * 128;
  int wr = w >> 1, wc = w & 1;
  f32x4 acc[4][4] = {};
  int srow = l >> 3;
  int scol = (l & 7) * 8;

  for (int k0 = 0; k0 < 640; k0 += 64) {
    #pragma unroll
    for (int j = 0; j < 4; ++j) {
      int row = 32 * w + 8 * j + srow;
      int ga = m0 + row; if (ga >= M) ga = M - 1;
      size_t offA = (size_t)ga * 640 + k0 + scol;
      size_t offB = (size_t)(n0 + row) * 640 + k0 + scol;
      __builtin_amdgcn_global_load_lds(
          (const __attribute__((address_space(1))) void*)(Ahi + offA),
          (__attribute__((address_space(3))) void*)(&AsH[32 * w + 8 * j][0]), 16, 0, 0);
      __builtin_amdgcn_global_load_lds(
          (const __attribute__((address_space(1))) void*)(Alo + offA),
          (__attribute__((address_space(3))) void*)(&AsL[32 * w + 8 * j][0]), 16, 0, 0);
      __builtin_amdgcn_global_load_lds(
          (const __attribute__((address_space(1))) void*)(Bhi + offB),
          (__attribute__((address_space(3))) void*)(&BsH[32 * w + 8 * j][0]), 16, 0, 0);
      __builtin_amdgcn_global_load_lds(
          (const __attribute__((address_space(1))) void*)(Blo + offB),
          (__attribute__((address_space(3))) void*)(&BsL[32 * w + 8 * j][0]), 16, 0, 0);
    }
    __syncthreads();
    int fr = l & 15, fq = l >> 4;
    #pragma unroll
    for (int ks = 0; ks < 2; ++ks) {
      bf16x8 ah[4], al[4], bh[4], bl[4];
      #pragma unroll
      for (int mi = 0; mi < 4; ++mi) {
        ah[mi] = *(const bf16x8*)&AsH[wr * 64 + 16 * mi + fr][ks * 32 + fq * 8];
        al[mi] = *(const bf16x8*)&AsL[wr * 64 + 16 * mi + fr][ks * 32 + fq * 8];
        bh[mi] = *(const bf16x8*)&BsH[wc * 64 + 16 * mi + fr][ks * 32 + fq * 8];
        bl[mi] = *(const bf16x8*)&BsL[wc * 64 + 16 * mi + fr][ks * 32 + fq * 8];
      }
      #pragma unroll
      for (int mi = 0; mi < 4; ++mi)
        #pragma unroll
        for (int ni = 0; ni < 4; ++ni) {
          acc[mi][ni] = __builtin_amdgcn_mfma_f32_16x16x32_bf16(ah[mi], bh[ni], acc[mi][ni], 0, 0, 0);
          acc[mi][ni] = __builtin_amdgcn_mfma_f32_16x16x32_bf16(al[mi], bh[ni], acc[mi][ni], 0, 0, 0);
          acc[mi][ni] = __builtin_amdgcn_mfma_f32_16x16x32_bf16(ah[mi], bl[ni], acc[mi][ni], 0, 0, 0);
        }
    }
    __syncthreads();
  }

  int fr = l & 15, fq = l >> 4;
  #pragma unroll
  for (int mi = 0; mi < 4; ++mi) {
    #pragma unroll
    for (int ni = 0; ni < 4; ++ni) {
      int col = n0 + wc * 64 + 16 * ni + fr;
      float bv = bias[col];
      #pragma unroll
      for (int r = 0; r < 4; ++r) {
        int row = m0 + wr * 64 + 16 * mi + fq * 4 + r;
        if (row < M) {
          float val = acc[mi][ni][r] + bv;
          if (OSPLIT) {
            u16 hh, ll; split_bf16(val, hh, ll);
            Chi[(size_t)row * Nc + col] = hh;
            Clo[(size_t)row * Nc + col] = ll;
          } else {
            Cc[(size_t)row * Nc + col] = val;
          }
        }
      }
    }
  }
}

// ---------------------------------------------------------------------------
// Fused MFMA attention v6: 512 thr (8 waves), q-tile 128, LDS 126,976 B,
// launch_bounds (512,2) [the proven no-spill point, r7/r8]. Since 2 blocks/CU
// never materialize (reg footprint), use the full LDS for ONE block:
// Khi+Klo resident together -> single fused 3-pass S (3 MFMA/frag), no serial
// restage; single-shot P[128][224] overlaying dead K; one AV / bucket / W /
// rel-v pass (no p-loop). 5 barriers total (vs 12 in v4).
// LDS map:
//   [0,34816)       Akhi[272][64]u16 swz | post-B2: Pm[128][224]u16 swz @0
//   [34816,69632)   Aklo[272][64]u16 swz |          BvBh[128][32]bf16 @57344
//   [69632,98304)   Vh[64][224]u16 swz
//   [98304,106496)  TvT[64][64]bf16 swz
//   [106496,126976) PvB[128] stride160   | post-B4: Wb[128][64]bf16 swz
// ---------------------------------------------------------------------------
__global__ __launch_bounds__(512, 2) void k_attn(
    const u16* __restrict__ qkvhi, const u16* __restrict__ qkvlo,
    const u16* __restrict__ tabKhi, const u16* __restrict__ tabKlo,
    const float* __restrict__ tvv, const float* __restrict__ tvh,
    u16* __restrict__ ohi, u16* __restrict__ olo) {
  __shared__ __align__(16) unsigned char LDS[126976];
  unsigned char* Akhi = LDS;
  unsigned char* Aklo = LDS + 34816;
  unsigned char* Vh   = LDS + 69632;
  unsigned char* TvT  = LDS + 98304;
  unsigned char* PvB  = LDS + 106496;
  unsigned char* Wb   = LDS + 106496;
  unsigned char* Pm   = LDS;
  u16* BvBh = (u16*)(LDS + 57344);

  int bh = blockIdx.x, b = bh / HH, h = bh % HH, qt = blockIdx.y;
  int t = threadIdx.x, w = t >> 6, l = t & 63;
  int fr = l & 15, fq = l >> 4;
  int q0 = 128 * qt;
  const size_t qbase = (size_t)(b * NN) * C3;

  // ---- staging: K hi+lo + tables (glds, pre-swizzled source) ----
  int kr = l >> 3;
  int chunk = ((l & 7) ^ (kr & 7)) * 8;
  for (int i = w; i < 34; i += 8) {
    int rr = 8 * i + kr;
    const u16 *sh, *sl;
    if (rr < 208) {
      int kk = rr > 196 ? 196 : rr;
      sh = qkvhi + qbase + (size_t)kk * C3 + CC + h * DD + chunk;
      sl = qkvlo + qbase + (size_t)kk * C3 + CC + h * DD + chunk;
    } else {
      int tr = rr - 208;
      sh = tabKhi + tr * 64 + chunk;
      sl = tabKlo + tr * 64 + chunk;
    }
    __builtin_amdgcn_global_load_lds(
        (const __attribute__((address_space(1))) void*)sh,
        (__attribute__((address_space(3))) void*)(Akhi + i * 1024), 16, 0, 0);
    __builtin_amdgcn_global_load_lds(
        (const __attribute__((address_space(1))) void*)sl,
        (__attribute__((address_space(3))) void*)(Aklo + i * 1024), 16, 0, 0);
  }
  // V^T hi [64d][224k] swz
  for (int idx = t; idx < 1576; idx += 512) {
    int k = idx >> 3, d0v = (idx & 7) * 8;
    size_t off = qbase + (size_t)k * C3 + 2 * CC + h * DD + d0v;
    uint4 vh4 = *(const uint4*)(qkvhi + off);
    u16 eh[8] = {(u16)vh4.x, (u16)(vh4.x >> 16), (u16)vh4.y, (u16)(vh4.y >> 16),
                 (u16)vh4.z, (u16)(vh4.z >> 16), (u16)vh4.w, (u16)(vh4.w >> 16)};
    #pragma unroll
    for (int jj = 0; jj < 8; ++jj) {
      int d = d0v + jj;
      int byte = (d * 224 + k) * 2; byte ^= (((d & 7) ^ ((d >> 3) & 7)) << 4);
      *(u16*)(Vh + byte) = eh[jj];
    }
  }
  for (int idx = t; idx < 64 * 27; idx += 512) {   // V pad cols 197..223
    int d = idx / 27, k = 197 + idx % 27;
    int byte = (d * 224 + k) * 2; byte ^= (((d & 7) ^ ((d >> 3) & 7)) << 4);
    *(u16*)(Vh + byte) = 0;
  }
  // TvT [64d][64t]
  for (int i = t; i < 4096; i += 512) {
    int d = i >> 6, tt = i & 63;
    float vv = 0.f;
    if (tt < 30) vv = tvv[tt * 64 + d];
    else if (tt >= 32 && tt < 62) vv = tvh[(tt - 32) * 64 + d];
    int byte = (d * 64 + tt) * 2; byte ^= (((d & 7) ^ ((d >> 3) & 7)) << 4);
    *(u16*)(TvT + byte) = bf16rn(vv);
  }
  // Q frags
  bool active = (q0 + 16 * w) < NN;
  bf16x8 qh[2], ql_[2];
  {
    int qg = q0 + 16 * w + fr; int qc = qg > 196 ? 196 : qg;
    const u16* qr  = qkvhi + qbase + (size_t)qc * C3 + h * DD;
    const u16* qr2 = qkvlo + qbase + (size_t)qc * C3 + h * DD;
    qh[0]  = *(const bf16x8*)(qr + 8 * fq);
    qh[1]  = *(const bf16x8*)(qr + 32 + 8 * fq);
    ql_[0] = *(const bf16x8*)(qr2 + 8 * fq);
    ql_[1] = *(const bf16x8*)(qr2 + 32 + 8 * fq);
  }
  __syncthreads();   // B1: staging done

  // ---- S: fused 3-pass (qh.Khi, ql.Khi, qh.Klo) over 17 frags ----
  unsigned pk01[13], pk23[13];
  {
    f32x4 sacc[17] = {};
    if (active) {
      #pragma unroll
      for (int ks = 0; ks < 2; ++ks)
        #pragma unroll
        for (int nf = 0; nf < 17; ++nf) {
          int row = 16 * nf + fr;
          int byte = row * 128 + 64 * ks + 16 * fq; byte ^= (row & 7) << 4;
          bf16x8 kf = *(const bf16x8*)(Akhi + byte);
          bf16x8 lf = *(const bf16x8*)(Aklo + byte);
          sacc[nf] = __builtin_amdgcn_mfma_f32_16x16x32_bf16(qh[ks],  kf, sacc[nf], 0, 0, 0);
          sacc[nf] = __builtin_amdgcn_mfma_f32_16x16x32_bf16(ql_[ks], kf, sacc[nf], 0, 0, 0);
          sacc[nf] = __builtin_amdgcn_mfma_f32_16x16x32_bf16(qh[ks],  lf, sacc[nf], 0, 0, 0);
        }
      // Pv/Ph table frags -> PvB (own rows; stride 160B, conflict-free)
      #pragma unroll
      for (int nf = 13; nf < 17; ++nf)
        #pragma unroll
        for (int r = 0; r < 4; ++r) {
          int c = 16 * (nf - 13) + fr;
          if (c < 60) {
            int row = 16 * w + 4 * fq + r;
            *(u16*)(PvB + row * 160 + 2 * c) = bf16rn(sacc[nf][r]);
          }
        }
      // gather + softmax (same-wave PvB reads; no barrier needed)
      float ex[13][4];
      float mrow[4] = {-1e30f, -1e30f, -1e30f, -1e30f};
      #pragma unroll
      for (int r = 0; r < 4; ++r) {
        int qrl = 16 * w + 4 * fq + r; int qg = q0 + qrl;
        int qc = qg > 196 ? 196 : qg;
        int gq = (qc > 0) ? (qc - 1) / 14 : 0;
        int cq = (qc > 0) ? (qc - 1) % 14 : 0;
        #pragma unroll
        for (int nf = 0; nf < 13; ++nf) {
          int k = 16 * nf + fr;
          float s;
          if (k < 197) {
            int fv  = (qc == 0 || k == 0) ? 0 : ((k - 1) / 14 - gq + 15);
            int fh2 = (qc == 0 || k == 0) ? 0 : ((k - 1) % 14 - cq + 15);
            float pv = bf16tof(*(const u16*)(PvB + qrl * 160 + 2 * fv));
            float ph = bf16tof(*(const u16*)(PvB + qrl * 160 + 2 * (30 + fh2)));
            s = (sacc[nf][r] + pv + ph) * SCALE;
          } else s = -1e30f;
          ex[nf][r] = s;
          mrow[r] = fmaxf(mrow[r], s);
        }
      }
      #pragma unroll
      for (int r = 0; r < 4; ++r)
        #pragma unroll
        for (int mk = 1; mk < 16; mk <<= 1) mrow[r] = fmaxf(mrow[r], __shfl_xor(mrow[r], mk));
      float sum[4] = {0.f, 0.f, 0.f, 0.f};
      #pragma unroll
      for (int nf = 0; nf < 13; ++nf)
        #pragma unroll
        for (int r = 0; r < 4; ++r) {
          ex[nf][r] = __expf(ex[nf][r] - mrow[r]);
          sum[r] += ex[nf][r];
        }
      float inv[4];
      #pragma unroll
      for (int r = 0; r < 4; ++r) {
        #pragma unroll
        for (int mk = 1; mk < 16; mk <<= 1) sum[r] += __shfl_xor(sum[r], mk);
        inv[r] = 1.f / sum[r];
      }
      #pragma unroll
      for (int nf = 0; nf < 13; ++nf) {
        pk01[nf] = (unsigned)bf16rn(ex[nf][0] * inv[0]) |
                   ((unsigned)bf16rn(ex[nf][1] * inv[1]) << 16);
        pk23[nf] = (unsigned)bf16rn(ex[nf][2] * inv[2]) |
                   ((unsigned)bf16rn(ex[nf][3] * inv[3]) << 16);
      }
    } else {
      #pragma unroll
      for (int nf = 0; nf < 13; ++nf) { pk01[nf] = 0; pk23[nf] = 0; }
    }
  }
  __syncthreads();   // B2: all K reads done everywhere -> K region reusable

  // ---- P write: each wave writes its 16 rows x 224 cols (zeros beyond) ----
  #pragma unroll
  for (int nf = 0; nf < 14; ++nf)
    #pragma unroll
    for (int r = 0; r < 4; ++r) {
      int k = 16 * nf + fr;
      int row = 16 * w + 4 * fq + r;
      u16 val = 0;
      if (nf < 13) {
        unsigned pk = (r < 2) ? pk01[nf] : pk23[nf];
        val = (r & 1) ? (u16)(pk >> 16) : (u16)(pk & 0xFFFF);
      }
      int byte = row * 448 + 2 * k; byte ^= (((row & 7) ^ ((row >> 3) & 7)) << 4);
      *(u16*)(Pm + byte) = val;
    }
  __syncthreads();   // B3: P visible

  // ---- AV (hi-only): wave w -> q rows 16w.., all 4 d-frags ----
  int prow = 16 * w + fr;
  int pswz = ((prow & 7) ^ ((prow >> 3) & 7)) << 4;
  f32x4 ov[4] = {};
  #pragma unroll
  for (int ks = 0; ks < 7; ++ks) {
    int co = 64 * ks + 16 * fq;
    bf16x8 pah = *(const bf16x8*)(Pm + ((prow * 448 + co) ^ pswz));
    #pragma unroll
    for (int nf = 0; nf < 4; ++nf) {
      int vrow = 16 * nf + fr;
      int vswz = ((vrow & 7) ^ ((vrow >> 3) & 7)) << 4;
      bf16x8 v = *(const bf16x8*)(Vh + ((vrow * 448 + co) ^ vswz));
      ov[nf] = __builtin_amdgcn_mfma_f32_16x16x32_bf16(pah, v, ov[nf], 0, 0, 0);
    }
  }

  // ---- bucket sums over P -> BvBh bf16 [128][32] ----
  for (int s = t; s < 3840; s += 512) {
    int q = s / 30, rem = s % 30;
    int isH = rem >= 15 ? 1 : 0, a = rem - 15 * isH;
    int sw = ((q & 7) ^ ((q >> 3) & 7)) << 4;
    float acc = 0.f;
    if (a == 14) {
      acc = bf16tof(*(const u16*)(Pm + ((q * 448 + 0) ^ sw)));
    } else if (!isH) {
      int k0b = 1 + 14 * a;
      #pragma unroll
      for (int j = 0; j < 14; ++j)
        acc += bf16tof(*(const u16*)(Pm + ((q * 448 + 2 * (k0b + j)) ^ sw)));
    } else {
      #pragma unroll
      for (int i2 = 0; i2 < 14; ++i2)
        acc += bf16tof(*(const u16*)(Pm + ((q * 448 + 2 * (1 + a + 14 * i2)) ^ sw)));
    }
    BvBh[q * 32 + 16 * isH + a] = bf16rn(acc);
  }
  __syncthreads();   // B4: BvBh ready; PvB dead -> Wb region free

  // ---- W build [128][64] bf16 ----
  for (int i = t; i < 8192; i += 512) {
    int q = i >> 6, tt = i & 63;
    int half = tt >> 5, u = tt & 31;
    int qg = q0 + q;
    float val = 0.f;
    if (qg == 0) {
      if (u == 0) {
        #pragma unroll
        for (int a = 0; a < 15; ++a) val += bf16tof(BvBh[q * 32 + 16 * half + a]);
      }
    } else if (qg < NN) {
      int m = qg - 1;
      int sel = half ? (m % 14) : (m / 14);
      if (u == 0) val = bf16tof(BvBh[q * 32 + 16 * half + 14]);
      else {
        int a = u - 15 + sel;
        if (a >= 0 && a < 14) val = bf16tof(BvBh[q * 32 + 16 * half + a]);
      }
    }
    int byte = q * 128 + 2 * tt; byte ^= (((q & 7) ^ ((q >> 3) & 7)) << 4);
    *(u16*)(Wb + byte) = bf16rn(val);
  }
  __syncthreads();   // B5: W ready

  // ---- rel-v MFMA: out_rel = W @ TvT ----
  f32x4 rv[4] = {};
  #pragma unroll
  for (int ks2 = 0; ks2 < 2; ++ks2) {
    int co = 64 * ks2 + 16 * fq;
    bf16x8 wa = *(const bf16x8*)(Wb + ((prow * 128 + co) ^ pswz));
    #pragma unroll
    for (int nf = 0; nf < 4; ++nf) {
      int vrow = 16 * nf + fr;
      int vswz = ((vrow & 7) ^ ((vrow >> 3) & 7)) << 4;
      bf16x8 tv = *(const bf16x8*)(TvT + ((vrow * 128 + co) ^ vswz));
      rv[nf] = __builtin_amdgcn_mfma_f32_16x16x32_bf16(wa, tv, rv[nf], 0, 0, 0);
    }
  }

  // ---- store ----
  #pragma unroll
  for (int r = 0; r < 4; ++r) {
    int qrl = 16 * w + 4 * fq + r;
    int qg = q0 + qrl;
    if (qg >= NN) continue;
    size_t ob = (size_t)(b * NN + qg) * CC + h * DD;
    #pragma unroll
    for (int nf = 0; nf < 4; ++nf) {
      int d = 16 * nf + fr;
      float o = ov[nf][r] + rv[nf][r];
      u16 hh, ll;
      split_bf16(o, hh, ll);
      ohi[ob + d] = hh; olo[ob + d] = ll;
    }
  }
}

// ---------------------------------------------------------------------------
// Workspace (u16 units, 135.7 MB):
//   qkvhi 24,207,360 | qkvlo 24,207,360 | xhi/xlo 2x8,069,120 (reused ohi/olo)
//   weffhi/lo 2x1,228,800 | wphi/lo 2x409,600 | tabKhi/lo 2x4,096
// ---------------------------------------------------------------------------
extern "C" void kernel_launch(void* const* d_in, const int* in_sizes, int n_in,
                              void* d_out, int out_size, void* d_ws, size_t ws_size,
                              hipStream_t stream) {
  (void)in_sizes; (void)n_in; (void)out_size; (void)ws_size;
  const float* x     = (const float*)d_in[0];
  const float* w_qkv = (const float*)d_in[1];
  const float* b_qkv = (const float*)d_in[2];
  const float* la    = (const float*)d_in[3];
  const float* lb    = (const float*)d_in[4];
  const float* tkv   = (const float*)d_in[5];
  const float* tkh   = (const float*)d_in[6];
  const float* tvv   = (const float*)d_in[7];
  const float* tvh   = (const float*)d_in[8];
  const float* wp    = (const float*)d_in[9];
  const float* b_p   = (const float*)d_in[10];

  u16* qkvhi  = (u16*)d_ws;
  u16* qkvlo  = qkvhi + (size_t)24207360;
  u16* xhi    = qkvlo + (size_t)24207360;
  u16* xlo    = xhi + (size_t)8069120;
  u16* ohi    = xhi;                       // alias (x splits dead after gemm1)
  u16* olo    = xlo;
  u16* weffhi = xlo + (size_t)8069120;
  u16* wefflo = weffhi + (size_t)1228800;
  u16* wphi   = wefflo + (size_t)1228800;
  u16* wplo   = wphi + (size_t)409600;
  u16* tabKhi = wplo + (size_t)409600;
  u16* tabKlo = tabKhi + (size_t)4096;

  k_weff<<<(C3 * CC) / 256, 256, 0, stream>>>(w_qkv, la, lb, weffhi, wefflo);
  k_cvtw<<<(CC * CC) / 256, 256, 0, stream>>>(wp, wphi, wplo);
  k_prep<<<1, 256, 0, stream>>>(tkv, tkh, tabKhi, tabKlo);
  int n4x = (MTOT * CC) / 4;
  k_cvt<<<(n4x + 255) / 256, 256, 0, stream>>>(x, xhi, xlo, n4x);

  // qkv = x @ weff^T + b_qkv -> split bf16 output
  dim3 g1((MTOT + 127) / 128, C3 / 128);
  k_gemm_mfma<1><<<g1, dim3(256), 0, stream>>>(xhi, xlo, weffhi, wefflo, b_qkv,
                                               nullptr, qkvhi, qkvlo, MTOT, C3);

  // fused attention -> ohi/olo split
  k_attn<<<dim3(BB * HH, 2), 512, 0, stream>>>(qkvhi, qkvlo, tabKhi, tabKlo,
                                               tvv, tvh, ohi, olo);

  // out = o @ perm3(w_proj)^T + b_proj
  dim3 g2((MTOT + 127) / 128, CC / 128);
  k_gemm_mfma<0><<<g2, dim3(256), 0, stream>>>(ohi, olo, wphi, wplo, b_p,
                                               (float*)d_out, nullptr, nullptr, MTOT, CC);
}

// Round 11
// 337.855 us; speedup vs baseline: 1.4425x; 1.0536x over previous
//
#include <hip/hip_runtime.h>
#include <math.h>

#define BB 64
#define NN 197
#define HH 10
#define DD 64
#define CC 640
#define C3 1920
#define LR 64
#define MTOT (BB*NN)          // 12608
#define SCALE 0.125f

typedef unsigned short u16;
typedef __bf16 bf16x8 __attribute__((ext_vector_type(8)));
typedef float f32x4 __attribute__((ext_vector_type(4)));

__device__ __forceinline__ void split_bf16(float f, u16& hi, u16& lo) {
  unsigned u = __float_as_uint(f);
  unsigned r = u + 0x7FFF + ((u >> 16) & 1);
  u16 hb = (u16)(r >> 16);
  float fh = __uint_as_float((unsigned)hb << 16);
  float dl = f - fh;
  unsigned u2 = __float_as_uint(dl);
  unsigned r2 = u2 + 0x7FFF + ((u2 >> 16) & 1);
  hi = hb; lo = (u16)(r2 >> 16);
}

__device__ __forceinline__ u16 bf16rn(float f) {
  unsigned u = __float_as_uint(f);
  return (u16)((u + 0x7FFF + ((u >> 16) & 1)) >> 16);
}
__device__ __forceinline__ float bf16tof(u16 v) {
  return __uint_as_float((unsigned)v << 16);
}

// ---------------------------------------------------------------------------
// K1: w_eff = perm3(w_qkv + (lora_a @ lora_b)^T) -> bf16 hi/lo split
// ---------------------------------------------------------------------------
__global__ __launch_bounds__(256) void k_weff(
    const float* __restrict__ w_qkv, const float* __restrict__ la,
    const float* __restrict__ lb, u16* __restrict__ whi, u16* __restrict__ wlo) {
  int idx = blockIdx.x * 256 + threadIdx.x;      // covers 1920*640
  int i = idx / CC, j = idx % CC;
  int src = 3 * (i % CC) + (i / CC);
  float acc = w_qkv[(size_t)src * CC + j];
  const float* laj = la + (size_t)j * LR;
  const float* lbs = lb + src;
  #pragma unroll 8
  for (int r = 0; r < LR; ++r) acc = fmaf(laj[r], lbs[(size_t)r * C3], acc);
  u16 h, l; split_bf16(acc, h, l);
  whi[idx] = h; wlo[idx] = l;
}

// fp32 -> bf16 hi/lo split
__global__ __launch_bounds__(256) void k_cvt(
    const float* __restrict__ in, u16* __restrict__ hi, u16* __restrict__ lo, int n4) {
  int i = blockIdx.x * 256 + threadIdx.x;
  if (i >= n4) return;
  float4 v = ((const float4*)in)[i];
  float f[4] = {v.x, v.y, v.z, v.w};
  ushort4 H, L;
  u16 hh, ll;
  split_bf16(f[0], hh, ll); H.x = hh; L.x = ll;
  split_bf16(f[1], hh, ll); H.y = hh; L.y = ll;
  split_bf16(f[2], hh, ll); H.z = hh; L.z = ll;
  split_bf16(f[3], hh, ll); H.w = hh; L.w = ll;
  ((ushort4*)hi)[i] = H;
  ((ushort4*)lo)[i] = L;
}

__device__ __forceinline__ int perm640(int i) {
  return (i < 214) ? 3 * i : (i < 427 ? 3 * (i - 214) + 1 : 3 * (i - 427) + 2);
}

__global__ __launch_bounds__(256) void k_cvtw(
    const float* __restrict__ wp, u16* __restrict__ hi, u16* __restrict__ lo) {
  int idx = blockIdx.x * 256 + threadIdx.x;      // covers 640*640
  int i = idx / CC, j = idx % CC;
  float v = wp[(size_t)perm640(i) * CC + j];
  u16 h, l; split_bf16(v, h, l);
  hi[idx] = h; lo[idx] = l;
}

// ---------------------------------------------------------------------------
// k_prep: (a) tabK rows 0..29 tkv, 30..59 tkh, 60..63 zero -> bf16 hi/lo.
// (b) gM: bucket one-hot matrix M [32 rows][224 k], PRE-SWIZZLE-LINEARIZED
// for direct glds staging into the V-tile's swizzled layout:
//   tile addr for (row,k): a = (row*448 + 2k) ^ (g(row)<<4),
//   g(row) = (row&7)^((row>>3)&7)   [injective map, closed on the region]
// gM linear byte b holds the (row,k) value whose a == b.
// ---------------------------------------------------------------------------
__global__ __launch_bounds__(256) void k_prep(
    const float* __restrict__ tkv, const float* __restrict__ tkh,
    u16* __restrict__ thi, u16* __restrict__ tlo, u16* __restrict__ gM) {
  for (int idx = threadIdx.x; idx < 4096; idx += 256) {
    int row = idx >> 6, d = idx & 63;
    float v = row < 30 ? tkv[row * 64 + d] : (row < 60 ? tkh[(row - 30) * 64 + d] : 0.f);
    u16 hh, ll; split_bf16(v, hh, ll);
    thi[idx] = hh; tlo[idx] = ll;
  }
  for (int j = threadIdx.x; j < 7168; j += 256) {
    int b = 2 * j;
    u16 v = 0;
    int r0 = b / 448;
    for (int dr = -1; dr <= 1; ++dr) {
      int row = r0 + dr;
      if (row < 0 || row >= 32) continue;
      int g = (row & 7) ^ ((row >> 3) & 7);
      int off = (b ^ (g << 4)) - row * 448;
      if (off >= 0 && off < 448) {
        int k = off >> 1;
        if (k < 197) {
          int a1 = (k == 0) ? 14 : (k - 1) / 14;
          int a2 = (k == 0) ? 14 : (k - 1) % 14;
          if (row < 16) { if (row == a1) v = 0x3F80; }
          else          { if (row - 16 == a2) v = 0x3F80; }
        }
        break;
      }
    }
    gM[j] = v;
  }
}

// ---------------------------------------------------------------------------
// Split-bf16 MFMA GEMM, fused 3-pass (hh, lh, hl per k-step). 128x128, BK=64.
// ---------------------------------------------------------------------------
template<int OSPLIT>
__global__ __launch_bounds__(256) void k_gemm_mfma(
    const u16* __restrict__ Ahi, const u16* __restrict__ Alo,
    const u16* __restrict__ Bhi, const u16* __restrict__ Blo,
    const float* __restrict__ bias, float* __restrict__ Cc,
    u16* __restrict__ Chi, u16* __restrict__ Clo,
    int M, int Nc) {
  __shared__ u16 AsH[128][64];
  __shared__ u16 AsL[128][64];
  __shared__ u16 BsH[128][64];
  __shared__ u16 BsL[128][64];
  int t = threadIdx.x, w = t >> 6, l = t & 63;
  int m0 = blockIdx.x * 128, n0 = blockIdx.y * 128;
  int wr = w >> 1, wc = w & 1;
  f32x4 acc[4][4] = {};
  int srow = l >> 3;
  int scol = (l & 7) * 8;

  for (int k0 = 0; k0 < 640; k0 += 64) {
    #pragma unroll
    for (int j = 0; j < 4; ++j) {
      int row = 32 * w + 8 * j + srow;
      int ga = m0 + row; if (ga >= M) ga = M - 1;
      size_t offA = (size_t)ga * 640 + k0 + scol;
      size_t offB = (size_t)(n0 + row) * 640 + k0 + scol;
      __builtin_amdgcn_global_load_lds(
          (const __attribute__((address_space(1))) void*)(Ahi + offA),
          (__attribute__((address_space(3))) void*)(&AsH[32 * w + 8 * j][0]), 16, 0, 0);
      __builtin_amdgcn_global_load_lds(
          (const __attribute__((address_space(1))) void*)(Alo + offA),
          (__attribute__((address_space(3))) void*)(&AsL[32 * w + 8 * j][0]), 16, 0, 0);
      __builtin_amdgcn_global_load_lds(
          (const __attribute__((address_space(1))) void*)(Bhi + offB),
          (__attribute__((address_space(3))) void*)(&BsH[32 * w + 8 * j][0]), 16, 0, 0);
      __builtin_amdgcn_global_load_lds(
          (const __attribute__((address_space(1))) void*)(Blo + offB),
          (__attribute__((address_space(3))) void*)(&BsL[32 * w + 8 * j][0]), 16, 0, 0);
    }
    __syncthreads();
    int fr = l & 15, fq = l >> 4;
    #pragma unroll
    for (int ks = 0; ks < 2; ++ks) {
      bf16x8 ah[4], al[4], bh[4], bl[4];
      #pragma unroll
      for (int mi = 0; mi < 4; ++mi) {
        ah[mi] = *(const bf16x8*)&AsH[wr * 64 + 16 * mi + fr][ks * 32 + fq * 8];
        al[mi] = *(const bf16x8*)&AsL[wr * 64 + 16 * mi + fr][ks * 32 + fq * 8];
        bh[mi] = *(const bf16x8*)&BsH[wc * 64 + 16 * mi + fr][ks * 32 + fq * 8];
        bl[mi] = *(const bf16x8*)&BsL[wc * 64 + 16 * mi + fr][ks * 32 + fq * 8];
      }
      #pragma unroll
      for (int mi = 0; mi < 4; ++mi)
        #pragma unroll
        for (int ni = 0; ni < 4; ++ni) {
          acc[mi][ni] = __builtin_amdgcn_mfma_f32_16x16x32_bf16(ah[mi], bh[ni], acc[mi][ni], 0, 0, 0);
          acc[mi][ni] = __builtin_amdgcn_mfma_f32_16x16x32_bf16(al[mi], bh[ni], acc[mi][ni], 0, 0, 0);
          acc[mi][ni] = __builtin_amdgcn_mfma_f32_16x16x32_bf16(ah[mi], bl[ni], acc[mi][ni], 0, 0, 0);
        }
    }
    __syncthreads();
  }

  int fr = l & 15, fq = l >> 4;
  #pragma unroll
  for (int mi = 0; mi < 4; ++mi) {
    #pragma unroll
    for (int ni = 0; ni < 4; ++ni) {
      int col = n0 + wc * 64 + 16 * ni + fr;
      float bv = bias[col];
      #pragma unroll
      for (int r = 0; r < 4; ++r) {
        int row = m0 + wr * 64 + 16 * mi + fq * 4 + r;
        if (row < M) {
          float val = acc[mi][ni][r] + bv;
          if (OSPLIT) {
            u16 hh, ll; split_bf16(val, hh, ll);
            Chi[(size_t)row * Nc + col] = hh;
            Clo[(size_t)row * Nc + col] = ll;
          } else {
            Cc[(size_t)row * Nc + col] = val;
          }
        }
      }
    }
  }
}

// ---------------------------------------------------------------------------
// Fused MFMA attention v7: r10 structure (512 thr, q-tile 128, 5 barriers,
// Khi+Klo resident, single-shot P) with VALU hot-loop elimination:
// (1) bucket sums via MFMA: M one-hot rows appended to V tile (rows 64..95),
//     staged via glds from pre-swizzled gM -> kills ~105 LDS scalar reads +
//     ~350 VALU ops/thread (incl. int div/mod) of the bucket loop.
// (2) gather div/mod-by-14 hoisted out of the r-loop (kd[13]/km[13]).
// (3) P written directly from live ex[]/inv[] (no pk pack/unpack).
// LDS 157,696 B:
//   [0,34816)       Akhi[272][64]u16 swz | post-B2: Pm[128][224]u16 swz @0
//   [34816,69632)   Aklo[272][64]u16 swz |   (Pm ends 57,344)
//   [69632,112640)  VhM[96][224]u16 swz (rows 64..95 = M one-hot)
//   [112640,120832) TvT[64][64]bf16 swz
//   [120832,141312) PvB[128]x160B | post-B3: BvBh[128][32]f32
//   [141312,157696) Wb[128][64]u16 swz
// ---------------------------------------------------------------------------
__global__ __launch_bounds__(512, 2) void k_attn(
    const u16* __restrict__ qkvhi, const u16* __restrict__ qkvlo,
    const u16* __restrict__ tabKhi, const u16* __restrict__ tabKlo,
    const u16* __restrict__ gM,
    const float* __restrict__ tvv, const float* __restrict__ tvh,
    u16* __restrict__ ohi, u16* __restrict__ olo) {
  __shared__ __align__(16) unsigned char LDS[157696];
  unsigned char* Akhi = LDS;
  unsigned char* Aklo = LDS + 34816;
  unsigned char* VhM  = LDS + 69632;
  unsigned char* TvT  = LDS + 112640;
  unsigned char* PvB  = LDS + 120832;
  float* BvBh = (float*)(LDS + 120832);
  unsigned char* Wb   = LDS + 141312;
  unsigned char* Pm   = LDS;

  int bh = blockIdx.x, b = bh / HH, h = bh % HH, qt = blockIdx.y;
  int t = threadIdx.x, w = t >> 6, l = t & 63;
  int fr = l & 15, fq = l >> 4;
  int q0 = 128 * qt;
  const size_t qbase = (size_t)(b * NN) * C3;

  // ---- staging: K hi+lo + tables (glds, pre-swizzled source) ----
  int kr = l >> 3;
  int chunk = ((l & 7) ^ (kr & 7)) * 8;
  for (int i = w; i < 34; i += 8) {
    int rr = 8 * i + kr;
    const u16 *sh, *sl;
    if (rr < 208) {
      int kk = rr > 196 ? 196 : rr;
      sh = qkvhi + qbase + (size_t)kk * C3 + CC + h * DD + chunk;
      sl = qkvlo + qbase + (size_t)kk * C3 + CC + h * DD + chunk;
    } else {
      int tr = rr - 208;
      sh = tabKhi + tr * 64 + chunk;
      sl = tabKlo + tr * 64 + chunk;
    }
    __builtin_amdgcn_global_load_lds(
        (const __attribute__((address_space(1))) void*)sh,
        (__attribute__((address_space(3))) void*)(Akhi + i * 1024), 16, 0, 0);
    __builtin_amdgcn_global_load_lds(
        (const __attribute__((address_space(1))) void*)sl,
        (__attribute__((address_space(3))) void*)(Aklo + i * 1024), 16, 0, 0);
  }
  // M one-hot rows: glds from pre-swizzled gM -> VhM rows 64..95 (linear dest)
  for (int i = w; i < 14; i += 8) {
    __builtin_amdgcn_global_load_lds(
        (const __attribute__((address_space(1))) void*)(gM + i * 512 + l * 8),
        (__attribute__((address_space(3))) void*)(VhM + 28672 + i * 1024), 16, 0, 0);
  }
  // V^T hi [64d][224k] swz
  for (int idx = t; idx < 1576; idx += 512) {
    int k = idx >> 3, d0v = (idx & 7) * 8;
    size_t off = qbase + (size_t)k * C3 + 2 * CC + h * DD + d0v;
    uint4 vh4 = *(const uint4*)(qkvhi + off);
    u16 eh[8] = {(u16)vh4.x, (u16)(vh4.x >> 16), (u16)vh4.y, (u16)(vh4.y >> 16),
                 (u16)vh4.z, (u16)(vh4.z >> 16), (u16)vh4.w, (u16)(vh4.w >> 16)};
    #pragma unroll
    for (int jj = 0; jj < 8; ++jj) {
      int d = d0v + jj;
      int byte = (d * 224 + k) * 2; byte ^= (((d & 7) ^ ((d >> 3) & 7)) << 4);
      *(u16*)(VhM + byte) = eh[jj];
    }
  }
  for (int idx = t; idx < 64 * 27; idx += 512) {   // V pad cols 197..223
    int d = idx / 27, k = 197 + idx % 27;
    int byte = (d * 224 + k) * 2; byte ^= (((d & 7) ^ ((d >> 3) & 7)) << 4);
    *(u16*)(VhM + byte) = 0;
  }
  // TvT [64d][64t]
  for (int i = t; i < 4096; i += 512) {
    int d = i >> 6, tt = i & 63;
    float vv = 0.f;
    if (tt < 30) vv = tvv[tt * 64 + d];
    else if (tt >= 32 && tt < 62) vv = tvh[(tt - 32) * 64 + d];
    int byte = (d * 64 + tt) * 2; byte ^= (((d & 7) ^ ((d >> 3) & 7)) << 4);
    *(u16*)(TvT + byte) = bf16rn(vv);
  }
  // Q frags
  bool active = (q0 + 16 * w) < NN;
  bf16x8 qh[2], ql_[2];
  {
    int qg = q0 + 16 * w + fr; int qc = qg > 196 ? 196 : qg;
    const u16* qr  = qkvhi + qbase + (size_t)qc * C3 + h * DD;
    const u16* qr2 = qkvlo + qbase + (size_t)qc * C3 + h * DD;
    qh[0]  = *(const bf16x8*)(qr + 8 * fq);
    qh[1]  = *(const bf16x8*)(qr + 32 + 8 * fq);
    ql_[0] = *(const bf16x8*)(qr2 + 8 * fq);
    ql_[1] = *(const bf16x8*)(qr2 + 32 + 8 * fq);
  }
  __syncthreads();   // B1: staging done

  // ---- S: fused 3-pass; PvB; gather (hoisted idx); softmax; keep ex+inv ----
  float ex[13][4];
  float inv[4];
  if (active) {
    f32x4 sacc[17] = {};
    #pragma unroll
    for (int ks = 0; ks < 2; ++ks)
      #pragma unroll
      for (int nf = 0; nf < 17; ++nf) {
        int row = 16 * nf + fr;
        int byte = row * 128 + 64 * ks + 16 * fq; byte ^= (row & 7) << 4;
        bf16x8 kf = *(const bf16x8*)(Akhi + byte);
        bf16x8 lf = *(const bf16x8*)(Aklo + byte);
        sacc[nf] = __builtin_amdgcn_mfma_f32_16x16x32_bf16(qh[ks],  kf, sacc[nf], 0, 0, 0);
        sacc[nf] = __builtin_amdgcn_mfma_f32_16x16x32_bf16(ql_[ks], kf, sacc[nf], 0, 0, 0);
        sacc[nf] = __builtin_amdgcn_mfma_f32_16x16x32_bf16(qh[ks],  lf, sacc[nf], 0, 0, 0);
      }
    #pragma unroll
    for (int nf = 13; nf < 17; ++nf)
      #pragma unroll
      for (int r = 0; r < 4; ++r) {
        int c = 16 * (nf - 13) + fr;
        if (c < 60) {
          int row = 16 * w + 4 * fq + r;
          *(u16*)(PvB + row * 160 + 2 * c) = bf16rn(sacc[nf][r]);
        }
      }
    // hoisted per-k indices (div/mod by 14 once, not per-r)
    int kd[13], km[13];
    #pragma unroll
    for (int nf = 0; nf < 13; ++nf) {
      int k = 16 * nf + fr;
      int kk = (k >= 1) ? (k - 1) : 0;
      kd[nf] = kk / 14; km[nf] = kk % 14;
    }
    float mrow[4] = {-1e30f, -1e30f, -1e30f, -1e30f};
    #pragma unroll
    for (int r = 0; r < 4; ++r) {
      int qrl = 16 * w + 4 * fq + r; int qg = q0 + qrl;
      int qc = qg > 196 ? 196 : qg;
      int gq = (qc > 0) ? (qc - 1) / 14 : 0;
      int cq = (qc > 0) ? (qc - 1) % 14 : 0;
      const unsigned char* rowb = PvB + qrl * 160;
      int dv = 2 * (15 - gq);
      int dh = 60 + 2 * (15 - cq);
      #pragma unroll
      for (int nf = 0; nf < 13; ++nf) {
        int k = 16 * nf + fr;
        float s;
        if (k < 197) {
          float pv, ph;
          if (qc == 0 || k == 0) {
            pv = bf16tof(*(const u16*)(rowb));
            ph = bf16tof(*(const u16*)(rowb + 60));
          } else {
            pv = bf16tof(*(const u16*)(rowb + dv + 2 * kd[nf]));
            ph = bf16tof(*(const u16*)(rowb + dh + 2 * km[nf]));
          }
          s = (sacc[nf][r] + pv + ph) * SCALE;
        } else s = -1e30f;
        ex[nf][r] = s;
        mrow[r] = fmaxf(mrow[r], s);
      }
    }
    #pragma unroll
    for (int r = 0; r < 4; ++r)
      #pragma unroll
      for (int mk = 1; mk < 16; mk <<= 1) mrow[r] = fmaxf(mrow[r], __shfl_xor(mrow[r], mk));
    float sum[4] = {0.f, 0.f, 0.f, 0.f};
    #pragma unroll
    for (int nf = 0; nf < 13; ++nf)
      #pragma unroll
      for (int r = 0; r < 4; ++r) {
        ex[nf][r] = __expf(ex[nf][r] - mrow[r]);
        sum[r] += ex[nf][r];
      }
    #pragma unroll
    for (int r = 0; r < 4; ++r) {
      #pragma unroll
      for (int mk = 1; mk < 16; mk <<= 1) sum[r] += __shfl_xor(sum[r], mk);
      inv[r] = 1.f / sum[r];
    }
  }
  __syncthreads();   // B2: all K/PvB reads done -> regions reusable

  // ---- P write (direct from ex; zeros for pad / inactive) ----
  #pragma unroll
  for (int nf = 0; nf < 14; ++nf)
    #pragma unroll
    for (int r = 0; r < 4; ++r) {
      int k = 16 * nf + fr;
      int row = 16 * w + 4 * fq + r;
      float p = 0.f;
      if (active && nf < 13 && k < 197) p = ex[nf][r] * inv[r];
      int byte = row * 448 + 2 * k; byte ^= (((row & 7) ^ ((row >> 3) & 7)) << 4);
      *(u16*)(Pm + byte) = bf16rn(p);
    }
  __syncthreads();   // B3: P visible

  // ---- AV + bucket MFMAs: wave w -> q rows 16w.., 4 d-frags + 2 M-frags ----
  int prow = 16 * w + fr;
  int pswz = ((prow & 7) ^ ((prow >> 3) & 7)) << 4;
  f32x4 ov[4] = {};
  f32x4 om[2] = {};
  #pragma unroll
  for (int ks = 0; ks < 7; ++ks) {
    int co = 64 * ks + 16 * fq;
    bf16x8 pah = *(const bf16x8*)(Pm + ((prow * 448 + co) ^ pswz));
    #pragma unroll
    for (int nf = 0; nf < 4; ++nf) {
      int vrow = 16 * nf + fr;
      int vswz = ((vrow & 7) ^ ((vrow >> 3) & 7)) << 4;
      bf16x8 v = *(const bf16x8*)(VhM + ((vrow * 448 + co) ^ vswz));
      ov[nf] = __builtin_amdgcn_mfma_f32_16x16x32_bf16(pah, v, ov[nf], 0, 0, 0);
    }
    #pragma unroll
    for (int mf = 0; mf < 2; ++mf) {
      int mr = 64 + 16 * mf + fr;
      int mswz = ((mr & 7) ^ ((mr >> 3) & 7)) << 4;
      bf16x8 mv = *(const bf16x8*)(VhM + ((mr * 448 + co) ^ mswz));
      om[mf] = __builtin_amdgcn_mfma_f32_16x16x32_bf16(pah, mv, om[mf], 0, 0, 0);
    }
  }
  // bucket results -> BvBh f32 [128][32]
  #pragma unroll
  for (int mf = 0; mf < 2; ++mf)
    #pragma unroll
    for (int r = 0; r < 4; ++r)
      BvBh[(16 * w + 4 * fq + r) * 32 + 16 * mf + fr] = om[mf][r];
  __syncthreads();   // B4: BvBh ready

  // ---- W build [128][64] bf16 ----
  for (int i = t; i < 8192; i += 512) {
    int q = i >> 6, tt = i & 63;
    int half = tt >> 5, u = tt & 31;
    int qg = q0 + q;
    float val = 0.f;
    if (qg == 0) {
      if (u == 0) {
        #pragma unroll
        for (int a = 0; a < 15; ++a) val += BvBh[q * 32 + 16 * half + a];
      }
    } else if (qg < NN) {
      int m = qg - 1;
      int sel = half ? (m % 14) : (m / 14);
      if (u == 0) val = BvBh[q * 32 + 16 * half + 14];
      else {
        int a = u - 15 + sel;
        if (a >= 0 && a < 14) val = BvBh[q * 32 + 16 * half + a];
      }
    }
    int byte = q * 128 + 2 * tt; byte ^= (((q & 7) ^ ((q >> 3) & 7)) << 4);
    *(u16*)(Wb + byte) = bf16rn(val);
  }
  __syncthreads();   // B5: W ready

  // ---- rel-v MFMA: out_rel = W @ TvT ----
  f32x4 rv[4] = {};
  #pragma unroll
  for (int ks2 = 0; ks2 < 2; ++ks2) {
    int co = 64 * ks2 + 16 * fq;
    bf16x8 wa = *(const bf16x8*)(Wb + ((prow * 128 + co) ^ pswz));
    #pragma unroll
    for (int nf = 0; nf < 4; ++nf) {
      int vrow = 16 * nf + fr;
      int vswz = ((vrow & 7) ^ ((vrow >> 3) & 7)) << 4;
      bf16x8 tv = *(const bf16x8*)(TvT + ((vrow * 128 + co) ^ vswz));
      rv[nf] = __builtin_amdgcn_mfma_f32_16x16x32_bf16(wa, tv, rv[nf], 0, 0, 0);
    }
  }

  // ---- store ----
  #pragma unroll
  for (int r = 0; r < 4; ++r) {
    int qrl = 16 * w + 4 * fq + r;
    int qg = q0 + qrl;
    if (qg >= NN) continue;
    size_t ob = (size_t)(b * NN + qg) * CC + h * DD;
    #pragma unroll
    for (int nf = 0; nf < 4; ++nf) {
      int d = 16 * nf + fr;
      float o = ov[nf][r] + rv[nf][r];
      u16 hh, ll;
      split_bf16(o, hh, ll);
      ohi[ob + d] = hh; olo[ob + d] = ll;
    }
  }
}

// ---------------------------------------------------------------------------
// Workspace (u16 units, ~135.7 MB):
//   qkvhi 24,207,360 | qkvlo 24,207,360 | xhi/xlo 2x8,069,120 (reused ohi/olo)
//   weffhi/lo 2x1,228,800 | wphi/lo 2x409,600 | tabKhi/lo 2x4,096 | gM 7,168
// ---------------------------------------------------------------------------
extern "C" void kernel_launch(void* const* d_in, const int* in_sizes, int n_in,
                              void* d_out, int out_size, void* d_ws, size_t ws_size,
                              hipStream_t stream) {
  (void)in_sizes; (void)n_in; (void)out_size; (void)ws_size;
  const float* x     = (const float*)d_in[0];
  const float* w_qkv = (const float*)d_in[1];
  const float* b_qkv = (const float*)d_in[2];
  const float* la    = (const float*)d_in[3];
  const float* lb    = (const float*)d_in[4];
  const float* tkv   = (const float*)d_in[5];
  const float* tkh   = (const float*)d_in[6];
  const float* tvv   = (const float*)d_in[7];
  const float* tvh   = (const float*)d_in[8];
  const float* wp    = (const float*)d_in[9];
  const float* b_p   = (const float*)d_in[10];

  u16* qkvhi  = (u16*)d_ws;
  u16* qkvlo  = qkvhi + (size_t)24207360;
  u16* xhi    = qkvlo + (size_t)24207360;
  u16* xlo    = xhi + (size_t)8069120;
  u16* ohi    = xhi;                       // alias (x splits dead after gemm1)
  u16* olo    = xlo;
  u16* weffhi = xlo + (size_t)8069120;
  u16* wefflo = weffhi + (size_t)1228800;
  u16* wphi   = wefflo + (size_t)1228800;
  u16* wplo   = wphi + (size_t)409600;
  u16* tabKhi = wplo + (size_t)409600;
  u16* tabKlo = tabKhi + (size_t)4096;
  u16* gM     = tabKlo + (size_t)4096;

  k_weff<<<(C3 * CC) / 256, 256, 0, stream>>>(w_qkv, la, lb, weffhi, wefflo);
  k_cvtw<<<(CC * CC) / 256, 256, 0, stream>>>(wp, wphi, wplo);
  k_prep<<<1, 256, 0, stream>>>(tkv, tkh, tabKhi, tabKlo, gM);
  int n4x = (MTOT * CC) / 4;
  k_cvt<<<(n4x + 255) / 256, 256, 0, stream>>>(x, xhi, xlo, n4x);

  // qkv = x @ weff^T + b_qkv -> split bf16 output
  dim3 g1((MTOT + 127) / 128, C3 / 128);
  k_gemm_mfma<1><<<g1, dim3(256), 0, stream>>>(xhi, xlo, weffhi, wefflo, b_qkv,
                                               nullptr, qkvhi, qkvlo, MTOT, C3);

  // fused attention -> ohi/olo split
  k_attn<<<dim3(BB * HH, 2), 512, 0, stream>>>(qkvhi, qkvlo, tabKhi, tabKlo, gM,
                                               tvv, tvh, ohi, olo);

  // out = o @ perm3(w_proj)^T + b_proj
  dim3 g2((MTOT + 127) / 128, CC / 128);
  k_gemm_mfma<0><<<g2, dim3(256), 0, stream>>>(ohi, olo, wphi, wplo, b_p,
                                               (float*)d_out, nullptr, nullptr, MTOT, CC);
}

// Round 12
// 301.533 us; speedup vs baseline: 1.6162x; 1.1205x over previous
//
#include <hip/hip_runtime.h>
#include <math.h>

#define BB 64
#define NN 197
#define HH 10
#define DD 64
#define CC 640
#define C3 1920
#define LR 64
#define MTOT (BB*NN)          // 12608
#define SCALE 0.125f

typedef unsigned short u16;
typedef __bf16 bf16x8 __attribute__((ext_vector_type(8)));
typedef float f32x4 __attribute__((ext_vector_type(4)));

__device__ __forceinline__ void split_bf16(float f, u16& hi, u16& lo) {
  unsigned u = __float_as_uint(f);
  unsigned r = u + 0x7FFF + ((u >> 16) & 1);
  u16 hb = (u16)(r >> 16);
  float fh = __uint_as_float((unsigned)hb << 16);
  float dl = f - fh;
  unsigned u2 = __float_as_uint(dl);
  unsigned r2 = u2 + 0x7FFF + ((u2 >> 16) & 1);
  hi = hb; lo = (u16)(r2 >> 16);
}

__device__ __forceinline__ u16 bf16rn(float f) {
  unsigned u = __float_as_uint(f);
  return (u16)((u + 0x7FFF + ((u >> 16) & 1)) >> 16);
}
__device__ __forceinline__ float bf16tof(u16 v) {
  return __uint_as_float((unsigned)v << 16);
}

// ---------------------------------------------------------------------------
// K1: w_eff = perm3(w_qkv + (lora_a @ lora_b)^T) -> bf16 hi/lo split
// ---------------------------------------------------------------------------
__global__ __launch_bounds__(256) void k_weff(
    const float* __restrict__ w_qkv, const float* __restrict__ la,
    const float* __restrict__ lb, u16* __restrict__ whi, u16* __restrict__ wlo) {
  int idx = blockIdx.x * 256 + threadIdx.x;      // covers 1920*640
  int i = idx / CC, j = idx % CC;
  int src = 3 * (i % CC) + (i / CC);
  float acc = w_qkv[(size_t)src * CC + j];
  const float* laj = la + (size_t)j * LR;
  const float* lbs = lb + src;
  #pragma unroll 8
  for (int r = 0; r < LR; ++r) acc = fmaf(laj[r], lbs[(size_t)r * C3], acc);
  u16 h, l; split_bf16(acc, h, l);
  whi[idx] = h; wlo[idx] = l;
}

// fp32 -> bf16 hi/lo split
__global__ __launch_bounds__(256) void k_cvt(
    const float* __restrict__ in, u16* __restrict__ hi, u16* __restrict__ lo, int n4) {
  int i = blockIdx.x * 256 + threadIdx.x;
  if (i >= n4) return;
  float4 v = ((const float4*)in)[i];
  float f[4] = {v.x, v.y, v.z, v.w};
  ushort4 H, L;
  u16 hh, ll;
  split_bf16(f[0], hh, ll); H.x = hh; L.x = ll;
  split_bf16(f[1], hh, ll); H.y = hh; L.y = ll;
  split_bf16(f[2], hh, ll); H.z = hh; L.z = ll;
  split_bf16(f[3], hh, ll); H.w = hh; L.w = ll;
  ((ushort4*)hi)[i] = H;
  ((ushort4*)lo)[i] = L;
}

__device__ __forceinline__ int perm640(int i) {
  return (i < 214) ? 3 * i : (i < 427 ? 3 * (i - 214) + 1 : 3 * (i - 427) + 2);
}

__global__ __launch_bounds__(256) void k_cvtw(
    const float* __restrict__ wp, u16* __restrict__ hi, u16* __restrict__ lo) {
  int idx = blockIdx.x * 256 + threadIdx.x;      // covers 640*640
  int i = idx / CC, j = idx % CC;
  float v = wp[(size_t)perm640(i) * CC + j];
  u16 h, l; split_bf16(v, h, l);
  hi[idx] = h; lo[idx] = l;
}

// ---------------------------------------------------------------------------
// k_prep: (a) tabK rows 0..29 tkv, 30..59 tkh, 60..63 zero -> bf16 hi/lo.
// (b) gM: bucket one-hot matrix M [32 rows][224 k], pre-swizzle-linearized
// for direct glds staging into the V-tile's swizzled layout.
// ---------------------------------------------------------------------------
__global__ __launch_bounds__(256) void k_prep(
    const float* __restrict__ tkv, const float* __restrict__ tkh,
    u16* __restrict__ thi, u16* __restrict__ tlo, u16* __restrict__ gM) {
  for (int idx = threadIdx.x; idx < 4096; idx += 256) {
    int row = idx >> 6, d = idx & 63;
    float v = row < 30 ? tkv[row * 64 + d] : (row < 60 ? tkh[(row - 30) * 64 + d] : 0.f);
    u16 hh, ll; split_bf16(v, hh, ll);
    thi[idx] = hh; tlo[idx] = ll;
  }
  for (int j = threadIdx.x; j < 7168; j += 256) {
    int b = 2 * j;
    u16 v = 0;
    int r0 = b / 448;
    for (int dr = -1; dr <= 1; ++dr) {
      int row = r0 + dr;
      if (row < 0 || row >= 32) continue;
      int g = (row & 7) ^ ((row >> 3) & 7);
      int off = (b ^ (g << 4)) - row * 448;
      if (off >= 0 && off < 448) {
        int k = off >> 1;
        if (k < 197) {
          int a1 = (k == 0) ? 14 : (k - 1) / 14;
          int a2 = (k == 0) ? 14 : (k - 1) % 14;
          if (row < 16) { if (row == a1) v = 0x3F80; }
          else          { if (row - 16 == a2) v = 0x3F80; }
        }
        break;
      }
    }
    gM[j] = v;
  }
}

// ---------------------------------------------------------------------------
// Split-bf16 MFMA GEMM, fused 3-pass. 128x128, BK=64. Round-12 changes:
// (1) LDS XOR-swizzle on all 4 tiles (pre-swizzled glds SOURCE + swizzled
//     reads; rule #21 both-sides) -> kills the 16-way conflict on ds_read_b128
//     (rows stride 128B, 16 lanes/same-col-window).
// (2) 1D grid, n-inner linearization (consecutive blocks share the A panel ->
//     A fetched ~once from HBM; B 4.9MB lives in L2/L3) + bijective XCD chunk
//     remap (m204 formula; nwg % 8 != 0 safe).
// ---------------------------------------------------------------------------
template<int OSPLIT>
__global__ __launch_bounds__(256) void k_gemm_mfma(
    const u16* __restrict__ Ahi, const u16* __restrict__ Alo,
    const u16* __restrict__ Bhi, const u16* __restrict__ Blo,
    const float* __restrict__ bias, float* __restrict__ Cc,
    u16* __restrict__ Chi, u16* __restrict__ Clo,
    int M, int Nc, int NT) {
  __shared__ u16 AsH[128][64];
  __shared__ u16 AsL[128][64];
  __shared__ u16 BsH[128][64];
  __shared__ u16 BsL[128][64];
  int t = threadIdx.x, w = t >> 6, l = t & 63;

  // bijective XCD chunk remap, then n-inner (mt,nt) decode
  int nwg = gridDim.x, bid = blockIdx.x;
  int q8 = nwg >> 3, r8 = nwg & 7;
  int xcd = bid & 7, j8 = bid >> 3;
  int wgid = (xcd < r8 ? xcd * (q8 + 1) : r8 * (q8 + 1) + (xcd - r8) * q8) + j8;
  int mt = wgid / NT, nt = wgid - mt * NT;
  int m0 = mt * 128, n0 = nt * 128;

  int wr = w >> 1, wc = w & 1;
  f32x4 acc[4][4] = {};
  int srow = l >> 3;                       // row within 8-row chunk; = dest row&7
  int scol = ((l & 7) ^ srow) * 8;         // pre-swizzled source col (elements)

  for (int k0 = 0; k0 < 640; k0 += 64) {
    #pragma unroll
    for (int j = 0; j < 4; ++j) {
      int row = 32 * w + 8 * j + srow;
      int ga = m0 + row; if (ga >= M) ga = M - 1;
      size_t offA = (size_t)ga * 640 + k0 + scol;
      size_t offB = (size_t)(n0 + row) * 640 + k0 + scol;
      __builtin_amdgcn_global_load_lds(
          (const __attribute__((address_space(1))) void*)(Ahi + offA),
          (__attribute__((address_space(3))) void*)(&AsH[32 * w + 8 * j][0]), 16, 0, 0);
      __builtin_amdgcn_global_load_lds(
          (const __attribute__((address_space(1))) void*)(Alo + offA),
          (__attribute__((address_space(3))) void*)(&AsL[32 * w + 8 * j][0]), 16, 0, 0);
      __builtin_amdgcn_global_load_lds(
          (const __attribute__((address_space(1))) void*)(Bhi + offB),
          (__attribute__((address_space(3))) void*)(&BsH[32 * w + 8 * j][0]), 16, 0, 0);
      __builtin_amdgcn_global_load_lds(
          (const __attribute__((address_space(1))) void*)(Blo + offB),
          (__attribute__((address_space(3))) void*)(&BsL[32 * w + 8 * j][0]), 16, 0, 0);
    }
    __syncthreads();
    int fr = l & 15, fq = l >> 4;
    const unsigned char* pAH = (const unsigned char*)&AsH[0][0];
    const unsigned char* pAL = (const unsigned char*)&AsL[0][0];
    const unsigned char* pBH = (const unsigned char*)&BsH[0][0];
    const unsigned char* pBL = (const unsigned char*)&BsL[0][0];
    int fsw = (fr & 7) << 4;
    #pragma unroll
    for (int ks = 0; ks < 2; ++ks) {
      int cbyte = (ks * 64 + fq * 16) ^ fsw;
      bf16x8 ah[4], al[4], bh[4], bl[4];
      #pragma unroll
      for (int mi = 0; mi < 4; ++mi) {
        int ra = (wr * 64 + 16 * mi + fr) * 128 + cbyte;
        int rb = (wc * 64 + 16 * mi + fr) * 128 + cbyte;
        ah[mi] = *(const bf16x8*)(pAH + ra);
        al[mi] = *(const bf16x8*)(pAL + ra);
        bh[mi] = *(const bf16x8*)(pBH + rb);
        bl[mi] = *(const bf16x8*)(pBL + rb);
      }
      #pragma unroll
      for (int mi = 0; mi < 4; ++mi)
        #pragma unroll
        for (int ni = 0; ni < 4; ++ni) {
          acc[mi][ni] = __builtin_amdgcn_mfma_f32_16x16x32_bf16(ah[mi], bh[ni], acc[mi][ni], 0, 0, 0);
          acc[mi][ni] = __builtin_amdgcn_mfma_f32_16x16x32_bf16(al[mi], bh[ni], acc[mi][ni], 0, 0, 0);
          acc[mi][ni] = __builtin_amdgcn_mfma_f32_16x16x32_bf16(ah[mi], bl[ni], acc[mi][ni], 0, 0, 0);
        }
    }
    __syncthreads();
  }

  int fr = l & 15, fq = l >> 4;
  #pragma unroll
  for (int mi = 0; mi < 4; ++mi) {
    #pragma unroll
    for (int ni = 0; ni < 4; ++ni) {
      int col = n0 + wc * 64 + 16 * ni + fr;
      float bv = bias[col];
      #pragma unroll
      for (int r = 0; r < 4; ++r) {
        int row = m0 + wr * 64 + 16 * mi + fq * 4 + r;
        if (row < M) {
          float val = acc[mi][ni][r] + bv;
          if (OSPLIT) {
            u16 hh, ll; split_bf16(val, hh, ll);
            Chi[(size_t)row * Nc + col] = hh;
            Clo[(size_t)row * Nc + col] = ll;
          } else {
            Cc[(size_t)row * Nc + col] = val;
          }
        }
      }
    }
  }
}

// ---------------------------------------------------------------------------
// Fused MFMA attention v7 (unchanged from r11): 512 thr, q-tile 128,
// 5 barriers, Khi+Klo resident, single-shot P, MFMA bucket sums via gM,
// hoisted gather indices, direct P write. LDS 157,696 B.
// ---------------------------------------------------------------------------
__global__ __launch_bounds__(512, 2) void k_attn(
    const u16* __restrict__ qkvhi, const u16* __restrict__ qkvlo,
    const u16* __restrict__ tabKhi, const u16* __restrict__ tabKlo,
    const u16* __restrict__ gM,
    const float* __restrict__ tvv, const float* __restrict__ tvh,
    u16* __restrict__ ohi, u16* __restrict__ olo) {
  __shared__ __align__(16) unsigned char LDS[157696];
  unsigned char* Akhi = LDS;
  unsigned char* Aklo = LDS + 34816;
  unsigned char* VhM  = LDS + 69632;
  unsigned char* TvT  = LDS + 112640;
  unsigned char* PvB  = LDS + 120832;
  float* BvBh = (float*)(LDS + 120832);
  unsigned char* Wb   = LDS + 141312;
  unsigned char* Pm   = LDS;

  int bh = blockIdx.x, b = bh / HH, h = bh % HH, qt = blockIdx.y;
  int t = threadIdx.x, w = t >> 6, l = t & 63;
  int fr = l & 15, fq = l >> 4;
  int q0 = 128 * qt;
  const size_t qbase = (size_t)(b * NN) * C3;

  // ---- staging: K hi+lo + tables (glds, pre-swizzled source) ----
  int kr = l >> 3;
  int chunk = ((l & 7) ^ (kr & 7)) * 8;
  for (int i = w; i < 34; i += 8) {
    int rr = 8 * i + kr;
    const u16 *sh, *sl;
    if (rr < 208) {
      int kk = rr > 196 ? 196 : rr;
      sh = qkvhi + qbase + (size_t)kk * C3 + CC + h * DD + chunk;
      sl = qkvlo + qbase + (size_t)kk * C3 + CC + h * DD + chunk;
    } else {
      int tr = rr - 208;
      sh = tabKhi + tr * 64 + chunk;
      sl = tabKlo + tr * 64 + chunk;
    }
    __builtin_amdgcn_global_load_lds(
        (const __attribute__((address_space(1))) void*)sh,
        (__attribute__((address_space(3))) void*)(Akhi + i * 1024), 16, 0, 0);
    __builtin_amdgcn_global_load_lds(
        (const __attribute__((address_space(1))) void*)sl,
        (__attribute__((address_space(3))) void*)(Aklo + i * 1024), 16, 0, 0);
  }
  // M one-hot rows: glds from pre-swizzled gM -> VhM rows 64..95 (linear dest)
  for (int i = w; i < 14; i += 8) {
    __builtin_amdgcn_global_load_lds(
        (const __attribute__((address_space(1))) void*)(gM + i * 512 + l * 8),
        (__attribute__((address_space(3))) void*)(VhM + 28672 + i * 1024), 16, 0, 0);
  }
  // V^T hi [64d][224k] swz
  for (int idx = t; idx < 1576; idx += 512) {
    int k = idx >> 3, d0v = (idx & 7) * 8;
    size_t off = qbase + (size_t)k * C3 + 2 * CC + h * DD + d0v;
    uint4 vh4 = *(const uint4*)(qkvhi + off);
    u16 eh[8] = {(u16)vh4.x, (u16)(vh4.x >> 16), (u16)vh4.y, (u16)(vh4.y >> 16),
                 (u16)vh4.z, (u16)(vh4.z >> 16), (u16)vh4.w, (u16)(vh4.w >> 16)};
    #pragma unroll
    for (int jj = 0; jj < 8; ++jj) {
      int d = d0v + jj;
      int byte = (d * 224 + k) * 2; byte ^= (((d & 7) ^ ((d >> 3) & 7)) << 4);
      *(u16*)(VhM + byte) = eh[jj];
    }
  }
  for (int idx = t; idx < 64 * 27; idx += 512) {   // V pad cols 197..223
    int d = idx / 27, k = 197 + idx % 27;
    int byte = (d * 224 + k) * 2; byte ^= (((d & 7) ^ ((d >> 3) & 7)) << 4);
    *(u16*)(VhM + byte) = 0;
  }
  // TvT [64d][64t]
  for (int i = t; i < 4096; i += 512) {
    int d = i >> 6, tt = i & 63;
    float vv = 0.f;
    if (tt < 30) vv = tvv[tt * 64 + d];
    else if (tt >= 32 && tt < 62) vv = tvh[(tt - 32) * 64 + d];
    int byte = (d * 64 + tt) * 2; byte ^= (((d & 7) ^ ((d >> 3) & 7)) << 4);
    *(u16*)(TvT + byte) = bf16rn(vv);
  }
  // Q frags
  bool active = (q0 + 16 * w) < NN;
  bf16x8 qh[2], ql_[2];
  {
    int qg = q0 + 16 * w + fr; int qc = qg > 196 ? 196 : qg;
    const u16* qr  = qkvhi + qbase + (size_t)qc * C3 + h * DD;
    const u16* qr2 = qkvlo + qbase + (size_t)qc * C3 + h * DD;
    qh[0]  = *(const bf16x8*)(qr + 8 * fq);
    qh[1]  = *(const bf16x8*)(qr + 32 + 8 * fq);
    ql_[0] = *(const bf16x8*)(qr2 + 8 * fq);
    ql_[1] = *(const bf16x8*)(qr2 + 32 + 8 * fq);
  }
  __syncthreads();   // B1: staging done

  // ---- S: fused 3-pass; PvB; gather (hoisted idx); softmax; keep ex+inv ----
  float ex[13][4];
  float inv[4];
  if (active) {
    f32x4 sacc[17] = {};
    #pragma unroll
    for (int ks = 0; ks < 2; ++ks)
      #pragma unroll
      for (int nf = 0; nf < 17; ++nf) {
        int row = 16 * nf + fr;
        int byte = row * 128 + 64 * ks + 16 * fq; byte ^= (row & 7) << 4;
        bf16x8 kf = *(const bf16x8*)(Akhi + byte);
        bf16x8 lf = *(const bf16x8*)(Aklo + byte);
        sacc[nf] = __builtin_amdgcn_mfma_f32_16x16x32_bf16(qh[ks],  kf, sacc[nf], 0, 0, 0);
        sacc[nf] = __builtin_amdgcn_mfma_f32_16x16x32_bf16(ql_[ks], kf, sacc[nf], 0, 0, 0);
        sacc[nf] = __builtin_amdgcn_mfma_f32_16x16x32_bf16(qh[ks],  lf, sacc[nf], 0, 0, 0);
      }
    #pragma unroll
    for (int nf = 13; nf < 17; ++nf)
      #pragma unroll
      for (int r = 0; r < 4; ++r) {
        int c = 16 * (nf - 13) + fr;
        if (c < 60) {
          int row = 16 * w + 4 * fq + r;
          *(u16*)(PvB + row * 160 + 2 * c) = bf16rn(sacc[nf][r]);
        }
      }
    int kd[13], km[13];
    #pragma unroll
    for (int nf = 0; nf < 13; ++nf) {
      int k = 16 * nf + fr;
      int kk = (k >= 1) ? (k - 1) : 0;
      kd[nf] = kk / 14; km[nf] = kk % 14;
    }
    float mrow[4] = {-1e30f, -1e30f, -1e30f, -1e30f};
    #pragma unroll
    for (int r = 0; r < 4; ++r) {
      int qrl = 16 * w + 4 * fq + r; int qg = q0 + qrl;
      int qc = qg > 196 ? 196 : qg;
      int gq = (qc > 0) ? (qc - 1) / 14 : 0;
      int cq = (qc > 0) ? (qc - 1) % 14 : 0;
      const unsigned char* rowb = PvB + qrl * 160;
      int dv = 2 * (15 - gq);
      int dh = 60 + 2 * (15 - cq);
      #pragma unroll
      for (int nf = 0; nf < 13; ++nf) {
        int k = 16 * nf + fr;
        float s;
        if (k < 197) {
          float pv, ph;
          if (qc == 0 || k == 0) {
            pv = bf16tof(*(const u16*)(rowb));
            ph = bf16tof(*(const u16*)(rowb + 60));
          } else {
            pv = bf16tof(*(const u16*)(rowb + dv + 2 * kd[nf]));
            ph = bf16tof(*(const u16*)(rowb + dh + 2 * km[nf]));
          }
          s = (sacc[nf][r] + pv + ph) * SCALE;
        } else s = -1e30f;
        ex[nf][r] = s;
        mrow[r] = fmaxf(mrow[r], s);
      }
    }
    #pragma unroll
    for (int r = 0; r < 4; ++r)
      #pragma unroll
      for (int mk = 1; mk < 16; mk <<= 1) mrow[r] = fmaxf(mrow[r], __shfl_xor(mrow[r], mk));
    float sum[4] = {0.f, 0.f, 0.f, 0.f};
    #pragma unroll
    for (int nf = 0; nf < 13; ++nf)
      #pragma unroll
      for (int r = 0; r < 4; ++r) {
        ex[nf][r] = __expf(ex[nf][r] - mrow[r]);
        sum[r] += ex[nf][r];
      }
    #pragma unroll
    for (int r = 0; r < 4; ++r) {
      #pragma unroll
      for (int mk = 1; mk < 16; mk <<= 1) sum[r] += __shfl_xor(sum[r], mk);
      inv[r] = 1.f / sum[r];
    }
  }
  __syncthreads();   // B2: all K/PvB reads done -> regions reusable

  // ---- P write (direct from ex; zeros for pad / inactive) ----
  #pragma unroll
  for (int nf = 0; nf < 14; ++nf)
    #pragma unroll
    for (int r = 0; r < 4; ++r) {
      int k = 16 * nf + fr;
      int row = 16 * w + 4 * fq + r;
      float p = 0.f;
      if (active && nf < 13 && k < 197) p = ex[nf][r] * inv[r];
      int byte = row * 448 + 2 * k; byte ^= (((row & 7) ^ ((row >> 3) & 7)) << 4);
      *(u16*)(Pm + byte) = bf16rn(p);
    }
  __syncthreads();   // B3: P visible

  // ---- AV + bucket MFMAs ----
  int prow = 16 * w + fr;
  int pswz = ((prow & 7) ^ ((prow >> 3) & 7)) << 4;
  f32x4 ov[4] = {};
  f32x4 om[2] = {};
  #pragma unroll
  for (int ks = 0; ks < 7; ++ks) {
    int co = 64 * ks + 16 * fq;
    bf16x8 pah = *(const bf16x8*)(Pm + ((prow * 448 + co) ^ pswz));
    #pragma unroll
    for (int nf = 0; nf < 4; ++nf) {
      int vrow = 16 * nf + fr;
      int vswz = ((vrow & 7) ^ ((vrow >> 3) & 7)) << 4;
      bf16x8 v = *(const bf16x8*)(VhM + ((vrow * 448 + co) ^ vswz));
      ov[nf] = __builtin_amdgcn_mfma_f32_16x16x32_bf16(pah, v, ov[nf], 0, 0, 0);
    }
    #pragma unroll
    for (int mf = 0; mf < 2; ++mf) {
      int mr = 64 + 16 * mf + fr;
      int mswz = ((mr & 7) ^ ((mr >> 3) & 7)) << 4;
      bf16x8 mv = *(const bf16x8*)(VhM + ((mr * 448 + co) ^ mswz));
      om[mf] = __builtin_amdgcn_mfma_f32_16x16x32_bf16(pah, mv, om[mf], 0, 0, 0);
    }
  }
  #pragma unroll
  for (int mf = 0; mf < 2; ++mf)
    #pragma unroll
    for (int r = 0; r < 4; ++r)
      BvBh[(16 * w + 4 * fq + r) * 32 + 16 * mf + fr] = om[mf][r];
  __syncthreads();   // B4: BvBh ready

  // ---- W build [128][64] bf16 ----
  for (int i = t; i < 8192; i += 512) {
    int q = i >> 6, tt = i & 63;
    int half = tt >> 5, u = tt & 31;
    int qg = q0 + q;
    float val = 0.f;
    if (qg == 0) {
      if (u == 0) {
        #pragma unroll
        for (int a = 0; a < 15; ++a) val += BvBh[q * 32 + 16 * half + a];
      }
    } else if (qg < NN) {
      int m = qg - 1;
      int sel = half ? (m % 14) : (m / 14);
      if (u == 0) val = BvBh[q * 32 + 16 * half + 14];
      else {
        int a = u - 15 + sel;
        if (a >= 0 && a < 14) val = BvBh[q * 32 + 16 * half + a];
      }
    }
    int byte = q * 128 + 2 * tt; byte ^= (((q & 7) ^ ((q >> 3) & 7)) << 4);
    *(u16*)(Wb + byte) = bf16rn(val);
  }
  __syncthreads();   // B5: W ready

  // ---- rel-v MFMA: out_rel = W @ TvT ----
  f32x4 rv[4] = {};
  #pragma unroll
  for (int ks2 = 0; ks2 < 2; ++ks2) {
    int co = 64 * ks2 + 16 * fq;
    bf16x8 wa = *(const bf16x8*)(Wb + ((prow * 128 + co) ^ pswz));
    #pragma unroll
    for (int nf = 0; nf < 4; ++nf) {
      int vrow = 16 * nf + fr;
      int vswz = ((vrow & 7) ^ ((vrow >> 3) & 7)) << 4;
      bf16x8 tv = *(const bf16x8*)(TvT + ((vrow * 128 + co) ^ vswz));
      rv[nf] = __builtin_amdgcn_mfma_f32_16x16x32_bf16(wa, tv, rv[nf], 0, 0, 0);
    }
  }

  // ---- store ----
  #pragma unroll
  for (int r = 0; r < 4; ++r) {
    int qrl = 16 * w + 4 * fq + r;
    int qg = q0 + qrl;
    if (qg >= NN) continue;
    size_t ob = (size_t)(b * NN + qg) * CC + h * DD;
    #pragma unroll
    for (int nf = 0; nf < 4; ++nf) {
      int d = 16 * nf + fr;
      float o = ov[nf][r] + rv[nf][r];
      u16 hh, ll;
      split_bf16(o, hh, ll);
      ohi[ob + d] = hh; olo[ob + d] = ll;
    }
  }
}

// ---------------------------------------------------------------------------
// Workspace (u16 units, ~135.7 MB):
//   qkvhi 24,207,360 | qkvlo 24,207,360 | xhi/xlo 2x8,069,120 (reused ohi/olo)
//   weffhi/lo 2x1,228,800 | wphi/lo 2x409,600 | tabKhi/lo 2x4,096 | gM 7,168
// ---------------------------------------------------------------------------
extern "C" void kernel_launch(void* const* d_in, const int* in_sizes, int n_in,
                              void* d_out, int out_size, void* d_ws, size_t ws_size,
                              hipStream_t stream) {
  (void)in_sizes; (void)n_in; (void)out_size; (void)ws_size;
  const float* x     = (const float*)d_in[0];
  const float* w_qkv = (const float*)d_in[1];
  const float* b_qkv = (const float*)d_in[2];
  const float* la    = (const float*)d_in[3];
  const float* lb    = (const float*)d_in[4];
  const float* tkv   = (const float*)d_in[5];
  const float* tkh   = (const float*)d_in[6];
  const float* tvv   = (const float*)d_in[7];
  const float* tvh   = (const float*)d_in[8];
  const float* wp    = (const float*)d_in[9];
  const float* b_p   = (const float*)d_in[10];

  u16* qkvhi  = (u16*)d_ws;
  u16* qkvlo  = qkvhi + (size_t)24207360;
  u16* xhi    = qkvlo + (size_t)24207360;
  u16* xlo    = xhi + (size_t)8069120;
  u16* ohi    = xhi;                       // alias (x splits dead after gemm1)
  u16* olo    = xlo;
  u16* weffhi = xlo + (size_t)8069120;
  u16* wefflo = weffhi + (size_t)1228800;
  u16* wphi   = wefflo + (size_t)1228800;
  u16* wplo   = wphi + (size_t)409600;
  u16* tabKhi = wplo + (size_t)409600;
  u16* tabKlo = tabKhi + (size_t)4096;
  u16* gM     = tabKlo + (size_t)4096;

  k_weff<<<(C3 * CC) / 256, 256, 0, stream>>>(w_qkv, la, lb, weffhi, wefflo);
  k_cvtw<<<(CC * CC) / 256, 256, 0, stream>>>(wp, wphi, wplo);
  k_prep<<<1, 256, 0, stream>>>(tkv, tkh, tabKhi, tabKlo, gM);
  int n4x = (MTOT * CC) / 4;
  k_cvt<<<(n4x + 255) / 256, 256, 0, stream>>>(x, xhi, xlo, n4x);

  // qkv = x @ weff^T + b_qkv -> split bf16 output
  int nwg1 = ((MTOT + 127) / 128) * (C3 / 128);   // 99*15 = 1485
  k_gemm_mfma<1><<<nwg1, 256, 0, stream>>>(xhi, xlo, weffhi, wefflo, b_qkv,
                                           nullptr, qkvhi, qkvlo, MTOT, C3, C3 / 128);

  // fused attention -> ohi/olo split
  k_attn<<<dim3(BB * HH, 2), 512, 0, stream>>>(qkvhi, qkvlo, tabKhi, tabKlo, gM,
                                               tvv, tvh, ohi, olo);

  // out = o @ perm3(w_proj)^T + b_proj
  int nwg2 = ((MTOT + 127) / 128) * (CC / 128);   // 99*5 = 495
  k_gemm_mfma<0><<<nwg2, 256, 0, stream>>>(ohi, olo, wphi, wplo, b_p,
                                           (float*)d_out, nullptr, nullptr, MTOT, CC, CC / 128);
}

// Round 13
// 289.774 us; speedup vs baseline: 1.6818x; 1.0406x over previous
//
#include <hip/hip_runtime.h>
#include <math.h>

#define BB 64
#define NN 197
#define HH 10
#define DD 64
#define CC 640
#define C3 1920
#define LR 64
#define MTOT (BB*NN)          // 12608
#define SCALE 0.125f

typedef unsigned short u16;
typedef __bf16 bf16x8 __attribute__((ext_vector_type(8)));
typedef float f32x4 __attribute__((ext_vector_type(4)));

__device__ __forceinline__ void split_bf16(float f, u16& hi, u16& lo) {
  unsigned u = __float_as_uint(f);
  unsigned r = u + 0x7FFF + ((u >> 16) & 1);
  u16 hb = (u16)(r >> 16);
  float fh = __uint_as_float((unsigned)hb << 16);
  float dl = f - fh;
  unsigned u2 = __float_as_uint(dl);
  unsigned r2 = u2 + 0x7FFF + ((u2 >> 16) & 1);
  hi = hb; lo = (u16)(r2 >> 16);
}

__device__ __forceinline__ u16 bf16rn(float f) {
  unsigned u = __float_as_uint(f);
  return (u16)((u + 0x7FFF + ((u >> 16) & 1)) >> 16);
}
__device__ __forceinline__ float bf16tof(u16 v) {
  return __uint_as_float((unsigned)v << 16);
}

// ---------------------------------------------------------------------------
// K1: w_eff = perm3(w_qkv + (lora_a @ lora_b)^T) -> bf16 hi/lo split
// ---------------------------------------------------------------------------
__global__ __launch_bounds__(256) void k_weff(
    const float* __restrict__ w_qkv, const float* __restrict__ la,
    const float* __restrict__ lb, u16* __restrict__ whi, u16* __restrict__ wlo) {
  int idx = blockIdx.x * 256 + threadIdx.x;      // covers 1920*640
  int i = idx / CC, j = idx % CC;
  int src = 3 * (i % CC) + (i / CC);
  float acc = w_qkv[(size_t)src * CC + j];
  const float* laj = la + (size_t)j * LR;
  const float* lbs = lb + src;
  #pragma unroll 8
  for (int r = 0; r < LR; ++r) acc = fmaf(laj[r], lbs[(size_t)r * C3], acc);
  u16 h, l; split_bf16(acc, h, l);
  whi[idx] = h; wlo[idx] = l;
}

// fp32 -> bf16 hi/lo split
__global__ __launch_bounds__(256) void k_cvt(
    const float* __restrict__ in, u16* __restrict__ hi, u16* __restrict__ lo, int n4) {
  int i = blockIdx.x * 256 + threadIdx.x;
  if (i >= n4) return;
  float4 v = ((const float4*)in)[i];
  float f[4] = {v.x, v.y, v.z, v.w};
  ushort4 H, L;
  u16 hh, ll;
  split_bf16(f[0], hh, ll); H.x = hh; L.x = ll;
  split_bf16(f[1], hh, ll); H.y = hh; L.y = ll;
  split_bf16(f[2], hh, ll); H.z = hh; L.z = ll;
  split_bf16(f[3], hh, ll); H.w = hh; L.w = ll;
  ((ushort4*)hi)[i] = H;
  ((ushort4*)lo)[i] = L;
}

__device__ __forceinline__ int perm640(int i) {
  return (i < 214) ? 3 * i : (i < 427 ? 3 * (i - 214) + 1 : 3 * (i - 427) + 2);
}

__global__ __launch_bounds__(256) void k_cvtw(
    const float* __restrict__ wp, u16* __restrict__ hi, u16* __restrict__ lo) {
  int idx = blockIdx.x * 256 + threadIdx.x;      // covers 640*640
  int i = idx / CC, j = idx % CC;
  float v = wp[(size_t)perm640(i) * CC + j];
  u16 h, l; split_bf16(v, h, l);
  hi[idx] = h; lo[idx] = l;
}

// ---------------------------------------------------------------------------
// k_prep: (a) tabK rows 0..29 tkv, 30..59 tkh, 60..63 zero -> bf16 hi/lo.
// (b) gM: bucket one-hot matrix M [32 rows][224 k], pre-swizzle-linearized
// for direct glds staging into the V-tile's swizzled layout.
// ---------------------------------------------------------------------------
__global__ __launch_bounds__(256) void k_prep(
    const float* __restrict__ tkv, const float* __restrict__ tkh,
    u16* __restrict__ thi, u16* __restrict__ tlo, u16* __restrict__ gM) {
  for (int idx = threadIdx.x; idx < 4096; idx += 256) {
    int row = idx >> 6, d = idx & 63;
    float v = row < 30 ? tkv[row * 64 + d] : (row < 60 ? tkh[(row - 30) * 64 + d] : 0.f);
    u16 hh, ll; split_bf16(v, hh, ll);
    thi[idx] = hh; tlo[idx] = ll;
  }
  for (int j = threadIdx.x; j < 7168; j += 256) {
    int b = 2 * j;
    u16 v = 0;
    int r0 = b / 448;
    for (int dr = -1; dr <= 1; ++dr) {
      int row = r0 + dr;
      if (row < 0 || row >= 32) continue;
      int g = (row & 7) ^ ((row >> 3) & 7);
      int off = (b ^ (g << 4)) - row * 448;
      if (off >= 0 && off < 448) {
        int k = off >> 1;
        if (k < 197) {
          int a1 = (k == 0) ? 14 : (k - 1) / 14;
          int a2 = (k == 0) ? 14 : (k - 1) % 14;
          if (row < 16) { if (row == a1) v = 0x3F80; }
          else          { if (row - 16 == a2) v = 0x3F80; }
        }
        break;
      }
    }
    gM[j] = v;
  }
}

// ---------------------------------------------------------------------------
// Split-bf16 MFMA GEMM, fused 3-pass. 128x128, BK=64. LDS XOR-swizzle
// (both-sides), 1D n-inner grid + bijective XCD chunk remap. (unchanged r12)
// ---------------------------------------------------------------------------
template<int OSPLIT>
__global__ __launch_bounds__(256) void k_gemm_mfma(
    const u16* __restrict__ Ahi, const u16* __restrict__ Alo,
    const u16* __restrict__ Bhi, const u16* __restrict__ Blo,
    const float* __restrict__ bias, float* __restrict__ Cc,
    u16* __restrict__ Chi, u16* __restrict__ Clo,
    int M, int Nc, int NT) {
  __shared__ u16 AsH[128][64];
  __shared__ u16 AsL[128][64];
  __shared__ u16 BsH[128][64];
  __shared__ u16 BsL[128][64];
  int t = threadIdx.x, w = t >> 6, l = t & 63;

  int nwg = gridDim.x, bid = blockIdx.x;
  int q8 = nwg >> 3, r8 = nwg & 7;
  int xcd = bid & 7, j8 = bid >> 3;
  int wgid = (xcd < r8 ? xcd * (q8 + 1) : r8 * (q8 + 1) + (xcd - r8) * q8) + j8;
  int mt = wgid / NT, nt = wgid - mt * NT;
  int m0 = mt * 128, n0 = nt * 128;

  int wr = w >> 1, wc = w & 1;
  f32x4 acc[4][4] = {};
  int srow = l >> 3;
  int scol = ((l & 7) ^ srow) * 8;

  for (int k0 = 0; k0 < 640; k0 += 64) {
    #pragma unroll
    for (int j = 0; j < 4; ++j) {
      int row = 32 * w + 8 * j + srow;
      int ga = m0 + row; if (ga >= M) ga = M - 1;
      size_t offA = (size_t)ga * 640 + k0 + scol;
      size_t offB = (size_t)(n0 + row) * 640 + k0 + scol;
      __builtin_amdgcn_global_load_lds(
          (const __attribute__((address_space(1))) void*)(Ahi + offA),
          (__attribute__((address_space(3))) void*)(&AsH[32 * w + 8 * j][0]), 16, 0, 0);
      __builtin_amdgcn_global_load_lds(
          (const __attribute__((address_space(1))) void*)(Alo + offA),
          (__attribute__((address_space(3))) void*)(&AsL[32 * w + 8 * j][0]), 16, 0, 0);
      __builtin_amdgcn_global_load_lds(
          (const __attribute__((address_space(1))) void*)(Bhi + offB),
          (__attribute__((address_space(3))) void*)(&BsH[32 * w + 8 * j][0]), 16, 0, 0);
      __builtin_amdgcn_global_load_lds(
          (const __attribute__((address_space(1))) void*)(Blo + offB),
          (__attribute__((address_space(3))) void*)(&BsL[32 * w + 8 * j][0]), 16, 0, 0);
    }
    __syncthreads();
    int fr = l & 15, fq = l >> 4;
    const unsigned char* pAH = (const unsigned char*)&AsH[0][0];
    const unsigned char* pAL = (const unsigned char*)&AsL[0][0];
    const unsigned char* pBH = (const unsigned char*)&BsH[0][0];
    const unsigned char* pBL = (const unsigned char*)&BsL[0][0];
    int fsw = (fr & 7) << 4;
    #pragma unroll
    for (int ks = 0; ks < 2; ++ks) {
      int cbyte = (ks * 64 + fq * 16) ^ fsw;
      bf16x8 ah[4], al[4], bh[4], bl[4];
      #pragma unroll
      for (int mi = 0; mi < 4; ++mi) {
        int ra = (wr * 64 + 16 * mi + fr) * 128 + cbyte;
        int rb = (wc * 64 + 16 * mi + fr) * 128 + cbyte;
        ah[mi] = *(const bf16x8*)(pAH + ra);
        al[mi] = *(const bf16x8*)(pAL + ra);
        bh[mi] = *(const bf16x8*)(pBH + rb);
        bl[mi] = *(const bf16x8*)(pBL + rb);
      }
      #pragma unroll
      for (int mi = 0; mi < 4; ++mi)
        #pragma unroll
        for (int ni = 0; ni < 4; ++ni) {
          acc[mi][ni] = __builtin_amdgcn_mfma_f32_16x16x32_bf16(ah[mi], bh[ni], acc[mi][ni], 0, 0, 0);
          acc[mi][ni] = __builtin_amdgcn_mfma_f32_16x16x32_bf16(al[mi], bh[ni], acc[mi][ni], 0, 0, 0);
          acc[mi][ni] = __builtin_amdgcn_mfma_f32_16x16x32_bf16(ah[mi], bl[ni], acc[mi][ni], 0, 0, 0);
        }
    }
    __syncthreads();
  }

  int fr = l & 15, fq = l >> 4;
  #pragma unroll
  for (int mi = 0; mi < 4; ++mi) {
    #pragma unroll
    for (int ni = 0; ni < 4; ++ni) {
      int col = n0 + wc * 64 + 16 * ni + fr;
      float bv = bias[col];
      #pragma unroll
      for (int r = 0; r < 4; ++r) {
        int row = m0 + wr * 64 + 16 * mi + fq * 4 + r;
        if (row < M) {
          float val = acc[mi][ni][r] + bv;
          if (OSPLIT) {
            u16 hh, ll; split_bf16(val, hh, ll);
            Chi[(size_t)row * Nc + col] = hh;
            Clo[(size_t)row * Nc + col] = ll;
          } else {
            Cc[(size_t)row * Nc + col] = val;
          }
        }
      }
    }
  }
}

// ---------------------------------------------------------------------------
// Fused MFMA attention v8: r12 structure with the post-S tail made fully
// WAVE-LOCAL -> barriers B3/B4/B5 removed (5 -> 2 barriers). Wave w writes &
// reads ONLY its own P rows (16w..16w+15), own BvBh rows, own W rows; same-
// wave LDS write->read needs no barrier (validated r10/r11 PvB pattern).
// W-build rewritten wave-local: lane = (row=16w+(l>>2), tt-block=(l&3)*16),
// packed 2 x ds_write_b128. BvBh stride 32->34 f32 (bank-conflict pad).
// LDS 157,696 B (unchanged layout except BvBh stride).
// ---------------------------------------------------------------------------
__global__ __launch_bounds__(512, 2) void k_attn(
    const u16* __restrict__ qkvhi, const u16* __restrict__ qkvlo,
    const u16* __restrict__ tabKhi, const u16* __restrict__ tabKlo,
    const u16* __restrict__ gM,
    const float* __restrict__ tvv, const float* __restrict__ tvh,
    u16* __restrict__ ohi, u16* __restrict__ olo) {
  __shared__ __align__(16) unsigned char LDS[157696];
  unsigned char* Akhi = LDS;
  unsigned char* Aklo = LDS + 34816;
  unsigned char* VhM  = LDS + 69632;
  unsigned char* TvT  = LDS + 112640;
  unsigned char* PvB  = LDS + 120832;
  float* BvBh = (float*)(LDS + 120832);      // [128] stride 34 f32 (17,408 B)
  unsigned char* Wb   = LDS + 141312;
  unsigned char* Pm   = LDS;

  int bh = blockIdx.x, b = bh / HH, h = bh % HH, qt = blockIdx.y;
  int t = threadIdx.x, w = t >> 6, l = t & 63;
  int fr = l & 15, fq = l >> 4;
  int q0 = 128 * qt;
  const size_t qbase = (size_t)(b * NN) * C3;

  // ---- staging: K hi+lo + tables (glds, pre-swizzled source) ----
  int kr = l >> 3;
  int chunk = ((l & 7) ^ (kr & 7)) * 8;
  for (int i = w; i < 34; i += 8) {
    int rr = 8 * i + kr;
    const u16 *sh, *sl;
    if (rr < 208) {
      int kk = rr > 196 ? 196 : rr;
      sh = qkvhi + qbase + (size_t)kk * C3 + CC + h * DD + chunk;
      sl = qkvlo + qbase + (size_t)kk * C3 + CC + h * DD + chunk;
    } else {
      int tr = rr - 208;
      sh = tabKhi + tr * 64 + chunk;
      sl = tabKlo + tr * 64 + chunk;
    }
    __builtin_amdgcn_global_load_lds(
        (const __attribute__((address_space(1))) void*)sh,
        (__attribute__((address_space(3))) void*)(Akhi + i * 1024), 16, 0, 0);
    __builtin_amdgcn_global_load_lds(
        (const __attribute__((address_space(1))) void*)sl,
        (__attribute__((address_space(3))) void*)(Aklo + i * 1024), 16, 0, 0);
  }
  // M one-hot rows: glds from pre-swizzled gM -> VhM rows 64..95 (linear dest)
  for (int i = w; i < 14; i += 8) {
    __builtin_amdgcn_global_load_lds(
        (const __attribute__((address_space(1))) void*)(gM + i * 512 + l * 8),
        (__attribute__((address_space(3))) void*)(VhM + 28672 + i * 1024), 16, 0, 0);
  }
  // V^T hi [64d][224k] swz
  for (int idx = t; idx < 1576; idx += 512) {
    int k = idx >> 3, d0v = (idx & 7) * 8;
    size_t off = qbase + (size_t)k * C3 + 2 * CC + h * DD + d0v;
    uint4 vh4 = *(const uint4*)(qkvhi + off);
    u16 eh[8] = {(u16)vh4.x, (u16)(vh4.x >> 16), (u16)vh4.y, (u16)(vh4.y >> 16),
                 (u16)vh4.z, (u16)(vh4.z >> 16), (u16)vh4.w, (u16)(vh4.w >> 16)};
    #pragma unroll
    for (int jj = 0; jj < 8; ++jj) {
      int d = d0v + jj;
      int byte = (d * 224 + k) * 2; byte ^= (((d & 7) ^ ((d >> 3) & 7)) << 4);
      *(u16*)(VhM + byte) = eh[jj];
    }
  }
  for (int idx = t; idx < 64 * 27; idx += 512) {   // V pad cols 197..223
    int d = idx / 27, k = 197 + idx % 27;
    int byte = (d * 224 + k) * 2; byte ^= (((d & 7) ^ ((d >> 3) & 7)) << 4);
    *(u16*)(VhM + byte) = 0;
  }
  // TvT [64d][64t]
  for (int i = t; i < 4096; i += 512) {
    int d = i >> 6, tt = i & 63;
    float vv = 0.f;
    if (tt < 30) vv = tvv[tt * 64 + d];
    else if (tt >= 32 && tt < 62) vv = tvh[(tt - 32) * 64 + d];
    int byte = (d * 64 + tt) * 2; byte ^= (((d & 7) ^ ((d >> 3) & 7)) << 4);
    *(u16*)(TvT + byte) = bf16rn(vv);
  }
  // Q frags
  bool active = (q0 + 16 * w) < NN;
  bf16x8 qh[2], ql_[2];
  {
    int qg = q0 + 16 * w + fr; int qc = qg > 196 ? 196 : qg;
    const u16* qr  = qkvhi + qbase + (size_t)qc * C3 + h * DD;
    const u16* qr2 = qkvlo + qbase + (size_t)qc * C3 + h * DD;
    qh[0]  = *(const bf16x8*)(qr + 8 * fq);
    qh[1]  = *(const bf16x8*)(qr + 32 + 8 * fq);
    ql_[0] = *(const bf16x8*)(qr2 + 8 * fq);
    ql_[1] = *(const bf16x8*)(qr2 + 32 + 8 * fq);
  }
  __syncthreads();   // B1: staging done

  // ---- S: fused 3-pass; PvB; gather (hoisted idx); softmax; keep ex+inv ----
  float ex[13][4];
  float inv[4];
  if (active) {
    f32x4 sacc[17] = {};
    #pragma unroll
    for (int ks = 0; ks < 2; ++ks)
      #pragma unroll
      for (int nf = 0; nf < 17; ++nf) {
        int row = 16 * nf + fr;
        int byte = row * 128 + 64 * ks + 16 * fq; byte ^= (row & 7) << 4;
        bf16x8 kf = *(const bf16x8*)(Akhi + byte);
        bf16x8 lf = *(const bf16x8*)(Aklo + byte);
        sacc[nf] = __builtin_amdgcn_mfma_f32_16x16x32_bf16(qh[ks],  kf, sacc[nf], 0, 0, 0);
        sacc[nf] = __builtin_amdgcn_mfma_f32_16x16x32_bf16(ql_[ks], kf, sacc[nf], 0, 0, 0);
        sacc[nf] = __builtin_amdgcn_mfma_f32_16x16x32_bf16(qh[ks],  lf, sacc[nf], 0, 0, 0);
      }
    #pragma unroll
    for (int nf = 13; nf < 17; ++nf)
      #pragma unroll
      for (int r = 0; r < 4; ++r) {
        int c = 16 * (nf - 13) + fr;
        if (c < 60) {
          int row = 16 * w + 4 * fq + r;
          *(u16*)(PvB + row * 160 + 2 * c) = bf16rn(sacc[nf][r]);
        }
      }
    int kd[13], km[13];
    #pragma unroll
    for (int nf = 0; nf < 13; ++nf) {
      int k = 16 * nf + fr;
      int kk = (k >= 1) ? (k - 1) : 0;
      kd[nf] = kk / 14; km[nf] = kk % 14;
    }
    float mrow[4] = {-1e30f, -1e30f, -1e30f, -1e30f};
    #pragma unroll
    for (int r = 0; r < 4; ++r) {
      int qrl = 16 * w + 4 * fq + r; int qg = q0 + qrl;
      int qc = qg > 196 ? 196 : qg;
      int gq = (qc > 0) ? (qc - 1) / 14 : 0;
      int cq = (qc > 0) ? (qc - 1) % 14 : 0;
      const unsigned char* rowb = PvB + qrl * 160;
      int dv = 2 * (15 - gq);
      int dh = 60 + 2 * (15 - cq);
      #pragma unroll
      for (int nf = 0; nf < 13; ++nf) {
        int k = 16 * nf + fr;
        float s;
        if (k < 197) {
          float pv, ph;
          if (qc == 0 || k == 0) {
            pv = bf16tof(*(const u16*)(rowb));
            ph = bf16tof(*(const u16*)(rowb + 60));
          } else {
            pv = bf16tof(*(const u16*)(rowb + dv + 2 * kd[nf]));
            ph = bf16tof(*(const u16*)(rowb + dh + 2 * km[nf]));
          }
          s = (sacc[nf][r] + pv + ph) * SCALE;
        } else s = -1e30f;
        ex[nf][r] = s;
        mrow[r] = fmaxf(mrow[r], s);
      }
    }
    #pragma unroll
    for (int r = 0; r < 4; ++r)
      #pragma unroll
      for (int mk = 1; mk < 16; mk <<= 1) mrow[r] = fmaxf(mrow[r], __shfl_xor(mrow[r], mk));
    float sum[4] = {0.f, 0.f, 0.f, 0.f};
    #pragma unroll
    for (int nf = 0; nf < 13; ++nf)
      #pragma unroll
      for (int r = 0; r < 4; ++r) {
        ex[nf][r] = __expf(ex[nf][r] - mrow[r]);
        sum[r] += ex[nf][r];
      }
    #pragma unroll
    for (int r = 0; r < 4; ++r) {
      #pragma unroll
      for (int mk = 1; mk < 16; mk <<= 1) sum[r] += __shfl_xor(sum[r], mk);
      inv[r] = 1.f / sum[r];
    }
  }
  __syncthreads();   // B2: all K/PvB reads done -> regions reusable (LAST barrier)

  // ---- P write (own rows only; zeros for pad / inactive) ----
  #pragma unroll
  for (int nf = 0; nf < 14; ++nf)
    #pragma unroll
    for (int r = 0; r < 4; ++r) {
      int k = 16 * nf + fr;
      int row = 16 * w + 4 * fq + r;
      float p = 0.f;
      if (active && nf < 13 && k < 197) p = ex[nf][r] * inv[r];
      int byte = row * 448 + 2 * k; byte ^= (((row & 7) ^ ((row >> 3) & 7)) << 4);
      *(u16*)(Pm + byte) = bf16rn(p);
    }
  // (no barrier: AV below reads only this wave's P rows)

  // ---- AV + bucket MFMAs: wave w -> own q rows, 4 d-frags + 2 M-frags ----
  int prow = 16 * w + fr;
  int pswz = ((prow & 7) ^ ((prow >> 3) & 7)) << 4;
  f32x4 ov[4] = {};
  f32x4 om[2] = {};
  #pragma unroll
  for (int ks = 0; ks < 7; ++ks) {
    int co = 64 * ks + 16 * fq;
    bf16x8 pah = *(const bf16x8*)(Pm + ((prow * 448 + co) ^ pswz));
    #pragma unroll
    for (int nf = 0; nf < 4; ++nf) {
      int vrow = 16 * nf + fr;
      int vswz = ((vrow & 7) ^ ((vrow >> 3) & 7)) << 4;
      bf16x8 v = *(const bf16x8*)(VhM + ((vrow * 448 + co) ^ vswz));
      ov[nf] = __builtin_amdgcn_mfma_f32_16x16x32_bf16(pah, v, ov[nf], 0, 0, 0);
    }
    #pragma unroll
    for (int mf = 0; mf < 2; ++mf) {
      int mr = 64 + 16 * mf + fr;
      int mswz = ((mr & 7) ^ ((mr >> 3) & 7)) << 4;
      bf16x8 mv = *(const bf16x8*)(VhM + ((mr * 448 + co) ^ mswz));
      om[mf] = __builtin_amdgcn_mfma_f32_16x16x32_bf16(pah, mv, om[mf], 0, 0, 0);
    }
  }
  // bucket results -> BvBh (own rows, stride 34 f32)
  #pragma unroll
  for (int mf = 0; mf < 2; ++mf)
    #pragma unroll
    for (int r = 0; r < 4; ++r)
      BvBh[(16 * w + 4 * fq + r) * 34 + 16 * mf + fr] = om[mf][r];
  // (no barrier: W build below reads only this wave's BvBh rows)

  // ---- W build (wave-local): lane = (row 16w+(l>>2), tt block (l&3)*16) ----
  {
    int row = 16 * w + (l >> 2);
    int qg = q0 + row;
    int half = (l & 3) >> 1;
    int u0 = (l & 1) * 16;
    const float* bb = &BvBh[row * 34 + 16 * half];
    u16 wv[16];
    if (qg == 0) {
      float s = 0.f;
      #pragma unroll
      for (int a = 0; a < 15; ++a) s += bb[a];
      u16 sv = bf16rn(s);
      #pragma unroll
      for (int j = 0; j < 16; ++j) wv[j] = (u0 + j == 0) ? sv : (u16)0;
    } else if (qg < NN) {
      int m = qg - 1;
      int sel = half ? (m % 14) : (m / 14);
      #pragma unroll
      for (int j = 0; j < 16; ++j) {
        int u = u0 + j;
        float val;
        if (u == 0) val = bb[14];
        else {
          int a = u - 15 + sel;
          val = (a >= 0 && a < 14) ? bb[a] : 0.f;
        }
        wv[j] = bf16rn(val);
      }
    } else {
      #pragma unroll
      for (int j = 0; j < 16; ++j) wv[j] = 0;
    }
    uint4 p0, p1;
    p0.x = wv[0]  | ((unsigned)wv[1]  << 16);
    p0.y = wv[2]  | ((unsigned)wv[3]  << 16);
    p0.z = wv[4]  | ((unsigned)wv[5]  << 16);
    p0.w = wv[6]  | ((unsigned)wv[7]  << 16);
    p1.x = wv[8]  | ((unsigned)wv[9]  << 16);
    p1.y = wv[10] | ((unsigned)wv[11] << 16);
    p1.z = wv[12] | ((unsigned)wv[13] << 16);
    p1.w = wv[14] | ((unsigned)wv[15] << 16);
    int base = row * 128 + (l & 3) * 32;
    int sz = ((row & 7) ^ ((row >> 3) & 7)) << 4;
    *(uint4*)(Wb + (base ^ sz)) = p0;
    *(uint4*)(Wb + ((base + 16) ^ sz)) = p1;
  }
  // (no barrier: rel-v below reads only this wave's W rows)

  // ---- rel-v MFMA: out_rel = W @ TvT ----
  f32x4 rv[4] = {};
  #pragma unroll
  for (int ks2 = 0; ks2 < 2; ++ks2) {
    int co = 64 * ks2 + 16 * fq;
    bf16x8 wa = *(const bf16x8*)(Wb + ((prow * 128 + co) ^ pswz));
    #pragma unroll
    for (int nf = 0; nf < 4; ++nf) {
      int vrow = 16 * nf + fr;
      int vswz = ((vrow & 7) ^ ((vrow >> 3) & 7)) << 4;
      bf16x8 tv = *(const bf16x8*)(TvT + ((vrow * 128 + co) ^ vswz));
      rv[nf] = __builtin_amdgcn_mfma_f32_16x16x32_bf16(wa, tv, rv[nf], 0, 0, 0);
    }
  }

  // ---- store ----
  #pragma unroll
  for (int r = 0; r < 4; ++r) {
    int qrl = 16 * w + 4 * fq + r;
    int qg = q0 + qrl;
    if (qg >= NN) continue;
    size_t ob = (size_t)(b * NN + qg) * CC + h * DD;
    #pragma unroll
    for (int nf = 0; nf < 4; ++nf) {
      int d = 16 * nf + fr;
      float o = ov[nf][r] + rv[nf][r];
      u16 hh, ll;
      split_bf16(o, hh, ll);
      ohi[ob + d] = hh; olo[ob + d] = ll;
    }
  }
}

// ---------------------------------------------------------------------------
// Workspace (u16 units, ~135.7 MB):
//   qkvhi 24,207,360 | qkvlo 24,207,360 | xhi/xlo 2x8,069,120 (reused ohi/olo)
//   weffhi/lo 2x1,228,800 | wphi/lo 2x409,600 | tabKhi/lo 2x4,096 | gM 7,168
// ---------------------------------------------------------------------------
extern "C" void kernel_launch(void* const* d_in, const int* in_sizes, int n_in,
                              void* d_out, int out_size, void* d_ws, size_t ws_size,
                              hipStream_t stream) {
  (void)in_sizes; (void)n_in; (void)out_size; (void)ws_size;
  const float* x     = (const float*)d_in[0];
  const float* w_qkv = (const float*)d_in[1];
  const float* b_qkv = (const float*)d_in[2];
  const float* la    = (const float*)d_in[3];
  const float* lb    = (const float*)d_in[4];
  const float* tkv   = (const float*)d_in[5];
  const float* tkh   = (const float*)d_in[6];
  const float* tvv   = (const float*)d_in[7];
  const float* tvh   = (const float*)d_in[8];
  const float* wp    = (const float*)d_in[9];
  const float* b_p   = (const float*)d_in[10];

  u16* qkvhi  = (u16*)d_ws;
  u16* qkvlo  = qkvhi + (size_t)24207360;
  u16* xhi    = qkvlo + (size_t)24207360;
  u16* xlo    = xhi + (size_t)8069120;
  u16* ohi    = xhi;                       // alias (x splits dead after gemm1)
  u16* olo    = xlo;
  u16* weffhi = xlo + (size_t)8069120;
  u16* wefflo = weffhi + (size_t)1228800;
  u16* wphi   = wefflo + (size_t)1228800;
  u16* wplo   = wphi + (size_t)409600;
  u16* tabKhi = wplo + (size_t)409600;
  u16* tabKlo = tabKhi + (size_t)4096;
  u16* gM     = tabKlo + (size_t)4096;

  k_weff<<<(C3 * CC) / 256, 256, 0, stream>>>(w_qkv, la, lb, weffhi, wefflo);
  k_cvtw<<<(CC * CC) / 256, 256, 0, stream>>>(wp, wphi, wplo);
  k_prep<<<1, 256, 0, stream>>>(tkv, tkh, tabKhi, tabKlo, gM);
  int n4x = (MTOT * CC) / 4;
  k_cvt<<<(n4x + 255) / 256, 256, 0, stream>>>(x, xhi, xlo, n4x);

  // qkv = x @ weff^T + b_qkv -> split bf16 output
  int nwg1 = ((MTOT + 127) / 128) * (C3 / 128);   // 99*15 = 1485
  k_gemm_mfma<1><<<nwg1, 256, 0, stream>>>(xhi, xlo, weffhi, wefflo, b_qkv,
                                           nullptr, qkvhi, qkvlo, MTOT, C3, C3 / 128);

  // fused attention -> ohi/olo split
  k_attn<<<dim3(BB * HH, 2), 512, 0, stream>>>(qkvhi, qkvlo, tabKhi, tabKlo, gM,
                                               tvv, tvh, ohi, olo);

  // out = o @ perm3(w_proj)^T + b_proj
  int nwg2 = ((MTOT + 127) / 128) * (CC / 128);   // 99*5 = 495
  k_gemm_mfma<0><<<nwg2, 256, 0, stream>>>(ohi, olo, wphi, wplo, b_p,
                                           (float*)d_out, nullptr, nullptr, MTOT, CC, CC / 128);
}

// Round 14
// 280.726 us; speedup vs baseline: 1.7360x; 1.0322x over previous
//
#include <hip/hip_runtime.h>
#include <math.h>

#define BB 64
#define NN 197
#define HH 10
#define DD 64
#define CC 640
#define C3 1920
#define LR 64
#define MTOT (BB*NN)          // 12608
#define SCALE 0.125f

typedef unsigned short u16;
typedef __bf16 bf16x8 __attribute__((ext_vector_type(8)));
typedef float f32x4 __attribute__((ext_vector_type(4)));

__device__ __forceinline__ void split_bf16(float f, u16& hi, u16& lo) {
  unsigned u = __float_as_uint(f);
  unsigned r = u + 0x7FFF + ((u >> 16) & 1);
  u16 hb = (u16)(r >> 16);
  float fh = __uint_as_float((unsigned)hb << 16);
  float dl = f - fh;
  unsigned u2 = __float_as_uint(dl);
  unsigned r2 = u2 + 0x7FFF + ((u2 >> 16) & 1);
  hi = hb; lo = (u16)(r2 >> 16);
}

__device__ __forceinline__ u16 bf16rn(float f) {
  unsigned u = __float_as_uint(f);
  return (u16)((u + 0x7FFF + ((u >> 16) & 1)) >> 16);
}
__device__ __forceinline__ float bf16tof(u16 v) {
  return __uint_as_float((unsigned)v << 16);
}

// ---------------------------------------------------------------------------
// K1: w_eff = perm3(w_qkv + (lora_a @ lora_b)^T) -> bf16 hi/lo split
// ---------------------------------------------------------------------------
__global__ __launch_bounds__(256) void k_weff(
    const float* __restrict__ w_qkv, const float* __restrict__ la,
    const float* __restrict__ lb, u16* __restrict__ whi, u16* __restrict__ wlo) {
  int idx = blockIdx.x * 256 + threadIdx.x;      // covers 1920*640
  int i = idx / CC, j = idx % CC;
  int src = 3 * (i % CC) + (i / CC);
  float acc = w_qkv[(size_t)src * CC + j];
  const float* laj = la + (size_t)j * LR;
  const float* lbs = lb + src;
  #pragma unroll 8
  for (int r = 0; r < LR; ++r) acc = fmaf(laj[r], lbs[(size_t)r * C3], acc);
  u16 h, l; split_bf16(acc, h, l);
  whi[idx] = h; wlo[idx] = l;
}

// fp32 -> bf16 hi/lo split
__global__ __launch_bounds__(256) void k_cvt(
    const float* __restrict__ in, u16* __restrict__ hi, u16* __restrict__ lo, int n4) {
  int i = blockIdx.x * 256 + threadIdx.x;
  if (i >= n4) return;
  float4 v = ((const float4*)in)[i];
  float f[4] = {v.x, v.y, v.z, v.w};
  ushort4 H, L;
  u16 hh, ll;
  split_bf16(f[0], hh, ll); H.x = hh; L.x = ll;
  split_bf16(f[1], hh, ll); H.y = hh; L.y = ll;
  split_bf16(f[2], hh, ll); H.z = hh; L.z = ll;
  split_bf16(f[3], hh, ll); H.w = hh; L.w = ll;
  ((ushort4*)hi)[i] = H;
  ((ushort4*)lo)[i] = L;
}

__device__ __forceinline__ int perm640(int i) {
  return (i < 214) ? 3 * i : (i < 427 ? 3 * (i - 214) + 1 : 3 * (i - 427) + 2);
}

__global__ __launch_bounds__(256) void k_cvtw(
    const float* __restrict__ wp, u16* __restrict__ hi, u16* __restrict__ lo) {
  int idx = blockIdx.x * 256 + threadIdx.x;      // covers 640*640
  int i = idx / CC, j = idx % CC;
  float v = wp[(size_t)perm640(i) * CC + j];
  u16 h, l; split_bf16(v, h, l);
  hi[idx] = h; lo[idx] = l;
}

// ---------------------------------------------------------------------------
// k_prep: (a) tabK rows 0..29 tkv, 30..59 tkh, 60..63 zero -> bf16 hi/lo.
// (b) gM: bucket one-hot matrix M [32 rows][224 k], pre-swizzle-linearized
// for direct glds staging into the V-tile's swizzled layout.
// ---------------------------------------------------------------------------
__global__ __launch_bounds__(256) void k_prep(
    const float* __restrict__ tkv, const float* __restrict__ tkh,
    u16* __restrict__ thi, u16* __restrict__ tlo, u16* __restrict__ gM) {
  for (int idx = threadIdx.x; idx < 4096; idx += 256) {
    int row = idx >> 6, d = idx & 63;
    float v = row < 30 ? tkv[row * 64 + d] : (row < 60 ? tkh[(row - 30) * 64 + d] : 0.f);
    u16 hh, ll; split_bf16(v, hh, ll);
    thi[idx] = hh; tlo[idx] = ll;
  }
  for (int j = threadIdx.x; j < 7168; j += 256) {
    int b = 2 * j;
    u16 v = 0;
    int r0 = b / 448;
    for (int dr = -1; dr <= 1; ++dr) {
      int row = r0 + dr;
      if (row < 0 || row >= 32) continue;
      int g = (row & 7) ^ ((row >> 3) & 7);
      int off = (b ^ (g << 4)) - row * 448;
      if (off >= 0 && off < 448) {
        int k = off >> 1;
        if (k < 197) {
          int a1 = (k == 0) ? 14 : (k - 1) / 14;
          int a2 = (k == 0) ? 14 : (k - 1) % 14;
          if (row < 16) { if (row == a1) v = 0x3F80; }
          else          { if (row - 16 == a2) v = 0x3F80; }
        }
        break;
      }
    }
    gM[j] = v;
  }
}

// ---------------------------------------------------------------------------
// Split-bf16 MFMA GEMM, fused 3-pass. 128x128 tile, BK=64, LDS XOR-swizzle,
// 1D n-inner grid + bijective XCD remap. Round-14: 8 waves (512 thr), each
// wave owns a 64x32 sub-tile (wr=w&1 m-half, wc=w>>2.. see below) ->
// acc 4x2 f32x4 = 32 AGPR; total regs <=128 -> 4 waves/SIMD (2 blocks/CU).
// __launch_bounds__(512,4) pins the 128-reg budget (natural need ~110).
// ---------------------------------------------------------------------------
template<int OSPLIT>
__global__ __launch_bounds__(512, 4) void k_gemm_mfma(
    const u16* __restrict__ Ahi, const u16* __restrict__ Alo,
    const u16* __restrict__ Bhi, const u16* __restrict__ Blo,
    const float* __restrict__ bias, float* __restrict__ Cc,
    u16* __restrict__ Chi, u16* __restrict__ Clo,
    int M, int Nc, int NT) {
  __shared__ u16 AsH[128][64];
  __shared__ u16 AsL[128][64];
  __shared__ u16 BsH[128][64];
  __shared__ u16 BsL[128][64];
  int t = threadIdx.x, w = t >> 6, l = t & 63;

  int nwg = gridDim.x, bid = blockIdx.x;
  int q8 = nwg >> 3, r8 = nwg & 7;
  int xcd = bid & 7, j8 = bid >> 3;
  int wgid = (xcd < r8 ? xcd * (q8 + 1) : r8 * (q8 + 1) + (xcd - r8) * q8) + j8;
  int mt = wgid / NT, nt = wgid - mt * NT;
  int m0 = mt * 128, n0 = nt * 128;

  int wr = w & 1, wc = w >> 1;             // m-half (64 rows), n-quarter (32 cols)
  f32x4 acc[4][2] = {};
  int srow = l >> 3;
  int scol = ((l & 7) ^ srow) * 8;

  for (int k0 = 0; k0 < 640; k0 += 64) {
    for (int i = w; i < 16; i += 8) {
      int row = 8 * i + srow;
      int ga = m0 + row; if (ga >= M) ga = M - 1;
      size_t offA = (size_t)ga * 640 + k0 + scol;
      size_t offB = (size_t)(n0 + row) * 640 + k0 + scol;
      __builtin_amdgcn_global_load_lds(
          (const __attribute__((address_space(1))) void*)(Ahi + offA),
          (__attribute__((address_space(3))) void*)(&AsH[8 * i][0]), 16, 0, 0);
      __builtin_amdgcn_global_load_lds(
          (const __attribute__((address_space(1))) void*)(Alo + offA),
          (__attribute__((address_space(3))) void*)(&AsL[8 * i][0]), 16, 0, 0);
      __builtin_amdgcn_global_load_lds(
          (const __attribute__((address_space(1))) void*)(Bhi + offB),
          (__attribute__((address_space(3))) void*)(&BsH[8 * i][0]), 16, 0, 0);
      __builtin_amdgcn_global_load_lds(
          (const __attribute__((address_space(1))) void*)(Blo + offB),
          (__attribute__((address_space(3))) void*)(&BsL[8 * i][0]), 16, 0, 0);
    }
    __syncthreads();
    int fr = l & 15, fq = l >> 4;
    const unsigned char* pAH = (const unsigned char*)&AsH[0][0];
    const unsigned char* pAL = (const unsigned char*)&AsL[0][0];
    const unsigned char* pBH = (const unsigned char*)&BsH[0][0];
    const unsigned char* pBL = (const unsigned char*)&BsL[0][0];
    int fsw = (fr & 7) << 4;
    #pragma unroll
    for (int ks = 0; ks < 2; ++ks) {
      int cbyte = (ks * 64 + fq * 16) ^ fsw;
      bf16x8 ah[4], al[4], bh[2], bl[2];
      #pragma unroll
      for (int mi = 0; mi < 4; ++mi) {
        int ra = (wr * 64 + 16 * mi + fr) * 128 + cbyte;
        ah[mi] = *(const bf16x8*)(pAH + ra);
        al[mi] = *(const bf16x8*)(pAL + ra);
      }
      #pragma unroll
      for (int ni = 0; ni < 2; ++ni) {
        int rb = (wc * 32 + 16 * ni + fr) * 128 + cbyte;
        bh[ni] = *(const bf16x8*)(pBH + rb);
        bl[ni] = *(const bf16x8*)(pBL + rb);
      }
      #pragma unroll
      for (int mi = 0; mi < 4; ++mi)
        #pragma unroll
        for (int ni = 0; ni < 2; ++ni) {
          acc[mi][ni] = __builtin_amdgcn_mfma_f32_16x16x32_bf16(ah[mi], bh[ni], acc[mi][ni], 0, 0, 0);
          acc[mi][ni] = __builtin_amdgcn_mfma_f32_16x16x32_bf16(al[mi], bh[ni], acc[mi][ni], 0, 0, 0);
          acc[mi][ni] = __builtin_amdgcn_mfma_f32_16x16x32_bf16(ah[mi], bl[ni], acc[mi][ni], 0, 0, 0);
        }
    }
    __syncthreads();
  }

  int fr = l & 15, fq = l >> 4;
  #pragma unroll
  for (int mi = 0; mi < 4; ++mi) {
    #pragma unroll
    for (int ni = 0; ni < 2; ++ni) {
      int col = n0 + wc * 32 + 16 * ni + fr;
      float bv = bias[col];
      #pragma unroll
      for (int r = 0; r < 4; ++r) {
        int row = m0 + wr * 64 + 16 * mi + fq * 4 + r;
        if (row < M) {
          float val = acc[mi][ni][r] + bv;
          if (OSPLIT) {
            u16 hh, ll; split_bf16(val, hh, ll);
            Chi[(size_t)row * Nc + col] = hh;
            Clo[(size_t)row * Nc + col] = ll;
          } else {
            Cc[(size_t)row * Nc + col] = val;
          }
        }
      }
    }
  }
}

// ---------------------------------------------------------------------------
// Fused MFMA attention v8 (unchanged from r13): 512 thr, q-tile 128,
// 2 barriers, wave-local post-S tail. LDS 157,696 B.
// ---------------------------------------------------------------------------
__global__ __launch_bounds__(512, 2) void k_attn(
    const u16* __restrict__ qkvhi, const u16* __restrict__ qkvlo,
    const u16* __restrict__ tabKhi, const u16* __restrict__ tabKlo,
    const u16* __restrict__ gM,
    const float* __restrict__ tvv, const float* __restrict__ tvh,
    u16* __restrict__ ohi, u16* __restrict__ olo) {
  __shared__ __align__(16) unsigned char LDS[157696];
  unsigned char* Akhi = LDS;
  unsigned char* Aklo = LDS + 34816;
  unsigned char* VhM  = LDS + 69632;
  unsigned char* TvT  = LDS + 112640;
  unsigned char* PvB  = LDS + 120832;
  float* BvBh = (float*)(LDS + 120832);      // [128] stride 34 f32
  unsigned char* Wb   = LDS + 141312;
  unsigned char* Pm   = LDS;

  int bh = blockIdx.x, b = bh / HH, h = bh % HH, qt = blockIdx.y;
  int t = threadIdx.x, w = t >> 6, l = t & 63;
  int fr = l & 15, fq = l >> 4;
  int q0 = 128 * qt;
  const size_t qbase = (size_t)(b * NN) * C3;

  // ---- staging: K hi+lo + tables (glds, pre-swizzled source) ----
  int kr = l >> 3;
  int chunk = ((l & 7) ^ (kr & 7)) * 8;
  for (int i = w; i < 34; i += 8) {
    int rr = 8 * i + kr;
    const u16 *sh, *sl;
    if (rr < 208) {
      int kk = rr > 196 ? 196 : rr;
      sh = qkvhi + qbase + (size_t)kk * C3 + CC + h * DD + chunk;
      sl = qkvlo + qbase + (size_t)kk * C3 + CC + h * DD + chunk;
    } else {
      int tr = rr - 208;
      sh = tabKhi + tr * 64 + chunk;
      sl = tabKlo + tr * 64 + chunk;
    }
    __builtin_amdgcn_global_load_lds(
        (const __attribute__((address_space(1))) void*)sh,
        (__attribute__((address_space(3))) void*)(Akhi + i * 1024), 16, 0, 0);
    __builtin_amdgcn_global_load_lds(
        (const __attribute__((address_space(1))) void*)sl,
        (__attribute__((address_space(3))) void*)(Aklo + i * 1024), 16, 0, 0);
  }
  // M one-hot rows: glds from pre-swizzled gM -> VhM rows 64..95
  for (int i = w; i < 14; i += 8) {
    __builtin_amdgcn_global_load_lds(
        (const __attribute__((address_space(1))) void*)(gM + i * 512 + l * 8),
        (__attribute__((address_space(3))) void*)(VhM + 28672 + i * 1024), 16, 0, 0);
  }
  // V^T hi [64d][224k] swz
  for (int idx = t; idx < 1576; idx += 512) {
    int k = idx >> 3, d0v = (idx & 7) * 8;
    size_t off = qbase + (size_t)k * C3 + 2 * CC + h * DD + d0v;
    uint4 vh4 = *(const uint4*)(qkvhi + off);
    u16 eh[8] = {(u16)vh4.x, (u16)(vh4.x >> 16), (u16)vh4.y, (u16)(vh4.y >> 16),
                 (u16)vh4.z, (u16)(vh4.z >> 16), (u16)vh4.w, (u16)(vh4.w >> 16)};
    #pragma unroll
    for (int jj = 0; jj < 8; ++jj) {
      int d = d0v + jj;
      int byte = (d * 224 + k) * 2; byte ^= (((d & 7) ^ ((d >> 3) & 7)) << 4);
      *(u16*)(VhM + byte) = eh[jj];
    }
  }
  for (int idx = t; idx < 64 * 27; idx += 512) {   // V pad cols 197..223
    int d = idx / 27, k = 197 + idx % 27;
    int byte = (d * 224 + k) * 2; byte ^= (((d & 7) ^ ((d >> 3) & 7)) << 4);
    *(u16*)(VhM + byte) = 0;
  }
  // TvT [64d][64t]
  for (int i = t; i < 4096; i += 512) {
    int d = i >> 6, tt = i & 63;
    float vv = 0.f;
    if (tt < 30) vv = tvv[tt * 64 + d];
    else if (tt >= 32 && tt < 62) vv = tvh[(tt - 32) * 64 + d];
    int byte = (d * 64 + tt) * 2; byte ^= (((d & 7) ^ ((d >> 3) & 7)) << 4);
    *(u16*)(TvT + byte) = bf16rn(vv);
  }
  // Q frags
  bool active = (q0 + 16 * w) < NN;
  bf16x8 qh[2], ql_[2];
  {
    int qg = q0 + 16 * w + fr; int qc = qg > 196 ? 196 : qg;
    const u16* qr  = qkvhi + qbase + (size_t)qc * C3 + h * DD;
    const u16* qr2 = qkvlo + qbase + (size_t)qc * C3 + h * DD;
    qh[0]  = *(const bf16x8*)(qr + 8 * fq);
    qh[1]  = *(const bf16x8*)(qr + 32 + 8 * fq);
    ql_[0] = *(const bf16x8*)(qr2 + 8 * fq);
    ql_[1] = *(const bf16x8*)(qr2 + 32 + 8 * fq);
  }
  __syncthreads();   // B1: staging done

  // ---- S: fused 3-pass; PvB; gather (hoisted idx); softmax ----
  float ex[13][4];
  float inv[4];
  if (active) {
    f32x4 sacc[17] = {};
    #pragma unroll
    for (int ks = 0; ks < 2; ++ks)
      #pragma unroll
      for (int nf = 0; nf < 17; ++nf) {
        int row = 16 * nf + fr;
        int byte = row * 128 + 64 * ks + 16 * fq; byte ^= (row & 7) << 4;
        bf16x8 kf = *(const bf16x8*)(Akhi + byte);
        bf16x8 lf = *(const bf16x8*)(Aklo + byte);
        sacc[nf] = __builtin_amdgcn_mfma_f32_16x16x32_bf16(qh[ks],  kf, sacc[nf], 0, 0, 0);
        sacc[nf] = __builtin_amdgcn_mfma_f32_16x16x32_bf16(ql_[ks], kf, sacc[nf], 0, 0, 0);
        sacc[nf] = __builtin_amdgcn_mfma_f32_16x16x32_bf16(qh[ks],  lf, sacc[nf], 0, 0, 0);
      }
    #pragma unroll
    for (int nf = 13; nf < 17; ++nf)
      #pragma unroll
      for (int r = 0; r < 4; ++r) {
        int c = 16 * (nf - 13) + fr;
        if (c < 60) {
          int row = 16 * w + 4 * fq + r;
          *(u16*)(PvB + row * 160 + 2 * c) = bf16rn(sacc[nf][r]);
        }
      }
    int kd[13], km[13];
    #pragma unroll
    for (int nf = 0; nf < 13; ++nf) {
      int k = 16 * nf + fr;
      int kk = (k >= 1) ? (k - 1) : 0;
      kd[nf] = kk / 14; km[nf] = kk % 14;
    }
    float mrow[4] = {-1e30f, -1e30f, -1e30f, -1e30f};
    #pragma unroll
    for (int r = 0; r < 4; ++r) {
      int qrl = 16 * w + 4 * fq + r; int qg = q0 + qrl;
      int qc = qg > 196 ? 196 : qg;
      int gq = (qc > 0) ? (qc - 1) / 14 : 0;
      int cq = (qc > 0) ? (qc - 1) % 14 : 0;
      const unsigned char* rowb = PvB + qrl * 160;
      int dv = 2 * (15 - gq);
      int dh = 60 + 2 * (15 - cq);
      #pragma unroll
      for (int nf = 0; nf < 13; ++nf) {
        int k = 16 * nf + fr;
        float s;
        if (k < 197) {
          float pv, ph;
          if (qc == 0 || k == 0) {
            pv = bf16tof(*(const u16*)(rowb));
            ph = bf16tof(*(const u16*)(rowb + 60));
          } else {
            pv = bf16tof(*(const u16*)(rowb + dv + 2 * kd[nf]));
            ph = bf16tof(*(const u16*)(rowb + dh + 2 * km[nf]));
          }
          s = (sacc[nf][r] + pv + ph) * SCALE;
        } else s = -1e30f;
        ex[nf][r] = s;
        mrow[r] = fmaxf(mrow[r], s);
      }
    }
    #pragma unroll
    for (int r = 0; r < 4; ++r)
      #pragma unroll
      for (int mk = 1; mk < 16; mk <<= 1) mrow[r] = fmaxf(mrow[r], __shfl_xor(mrow[r], mk));
    float sum[4] = {0.f, 0.f, 0.f, 0.f};
    #pragma unroll
    for (int nf = 0; nf < 13; ++nf)
      #pragma unroll
      for (int r = 0; r < 4; ++r) {
        ex[nf][r] = __expf(ex[nf][r] - mrow[r]);
        sum[r] += ex[nf][r];
      }
    #pragma unroll
    for (int r = 0; r < 4; ++r) {
      #pragma unroll
      for (int mk = 1; mk < 16; mk <<= 1) sum[r] += __shfl_xor(sum[r], mk);
      inv[r] = 1.f / sum[r];
    }
  }
  __syncthreads();   // B2: all K/PvB reads done (LAST barrier)

  // ---- P write (own rows only) ----
  #pragma unroll
  for (int nf = 0; nf < 14; ++nf)
    #pragma unroll
    for (int r = 0; r < 4; ++r) {
      int k = 16 * nf + fr;
      int row = 16 * w + 4 * fq + r;
      float p = 0.f;
      if (active && nf < 13 && k < 197) p = ex[nf][r] * inv[r];
      int byte = row * 448 + 2 * k; byte ^= (((row & 7) ^ ((row >> 3) & 7)) << 4);
      *(u16*)(Pm + byte) = bf16rn(p);
    }

  // ---- AV + bucket MFMAs (wave-local) ----
  int prow = 16 * w + fr;
  int pswz = ((prow & 7) ^ ((prow >> 3) & 7)) << 4;
  f32x4 ov[4] = {};
  f32x4 om[2] = {};
  #pragma unroll
  for (int ks = 0; ks < 7; ++ks) {
    int co = 64 * ks + 16 * fq;
    bf16x8 pah = *(const bf16x8*)(Pm + ((prow * 448 + co) ^ pswz));
    #pragma unroll
    for (int nf = 0; nf < 4; ++nf) {
      int vrow = 16 * nf + fr;
      int vswz = ((vrow & 7) ^ ((vrow >> 3) & 7)) << 4;
      bf16x8 v = *(const bf16x8*)(VhM + ((vrow * 448 + co) ^ vswz));
      ov[nf] = __builtin_amdgcn_mfma_f32_16x16x32_bf16(pah, v, ov[nf], 0, 0, 0);
    }
    #pragma unroll
    for (int mf = 0; mf < 2; ++mf) {
      int mr = 64 + 16 * mf + fr;
      int mswz = ((mr & 7) ^ ((mr >> 3) & 7)) << 4;
      bf16x8 mv = *(const bf16x8*)(VhM + ((mr * 448 + co) ^ mswz));
      om[mf] = __builtin_amdgcn_mfma_f32_16x16x32_bf16(pah, mv, om[mf], 0, 0, 0);
    }
  }
  #pragma unroll
  for (int mf = 0; mf < 2; ++mf)
    #pragma unroll
    for (int r = 0; r < 4; ++r)
      BvBh[(16 * w + 4 * fq + r) * 34 + 16 * mf + fr] = om[mf][r];

  // ---- W build (wave-local) ----
  {
    int row = 16 * w + (l >> 2);
    int qg = q0 + row;
    int half = (l & 3) >> 1;
    int u0 = (l & 1) * 16;
    const float* bb = &BvBh[row * 34 + 16 * half];
    u16 wv[16];
    if (qg == 0) {
      float s = 0.f;
      #pragma unroll
      for (int a = 0; a < 15; ++a) s += bb[a];
      u16 sv = bf16rn(s);
      #pragma unroll
      for (int j = 0; j < 16; ++j) wv[j] = (u0 + j == 0) ? sv : (u16)0;
    } else if (qg < NN) {
      int m = qg - 1;
      int sel = half ? (m % 14) : (m / 14);
      #pragma unroll
      for (int j = 0; j < 16; ++j) {
        int u = u0 + j;
        float val;
        if (u == 0) val = bb[14];
        else {
          int a = u - 15 + sel;
          val = (a >= 0 && a < 14) ? bb[a] : 0.f;
        }
        wv[j] = bf16rn(val);
      }
    } else {
      #pragma unroll
      for (int j = 0; j < 16; ++j) wv[j] = 0;
    }
    uint4 p0, p1;
    p0.x = wv[0]  | ((unsigned)wv[1]  << 16);
    p0.y = wv[2]  | ((unsigned)wv[3]  << 16);
    p0.z = wv[4]  | ((unsigned)wv[5]  << 16);
    p0.w = wv[6]  | ((unsigned)wv[7]  << 16);
    p1.x = wv[8]  | ((unsigned)wv[9]  << 16);
    p1.y = wv[10] | ((unsigned)wv[11] << 16);
    p1.z = wv[12] | ((unsigned)wv[13] << 16);
    p1.w = wv[14] | ((unsigned)wv[15] << 16);
    int base = row * 128 + (l & 3) * 32;
    int sz = ((row & 7) ^ ((row >> 3) & 7)) << 4;
    *(uint4*)(Wb + (base ^ sz)) = p0;
    *(uint4*)(Wb + ((base + 16) ^ sz)) = p1;
  }

  // ---- rel-v MFMA: out_rel = W @ TvT ----
  f32x4 rv[4] = {};
  #pragma unroll
  for (int ks2 = 0; ks2 < 2; ++ks2) {
    int co = 64 * ks2 + 16 * fq;
    bf16x8 wa = *(const bf16x8*)(Wb + ((prow * 128 + co) ^ pswz));
    #pragma unroll
    for (int nf = 0; nf < 4; ++nf) {
      int vrow = 16 * nf + fr;
      int vswz = ((vrow & 7) ^ ((vrow >> 3) & 7)) << 4;
      bf16x8 tv = *(const bf16x8*)(TvT + ((vrow * 128 + co) ^ vswz));
      rv[nf] = __builtin_amdgcn_mfma_f32_16x16x32_bf16(wa, tv, rv[nf], 0, 0, 0);
    }
  }

  // ---- store ----
  #pragma unroll
  for (int r = 0; r < 4; ++r) {
    int qrl = 16 * w + 4 * fq + r;
    int qg = q0 + qrl;
    if (qg >= NN) continue;
    size_t ob = (size_t)(b * NN + qg) * CC + h * DD;
    #pragma unroll
    for (int nf = 0; nf < 4; ++nf) {
      int d = 16 * nf + fr;
      float o = ov[nf][r] + rv[nf][r];
      u16 hh, ll;
      split_bf16(o, hh, ll);
      ohi[ob + d] = hh; olo[ob + d] = ll;
    }
  }
}

// ---------------------------------------------------------------------------
// Workspace (u16 units, ~135.7 MB):
//   qkvhi 24,207,360 | qkvlo 24,207,360 | xhi/xlo 2x8,069,120 (reused ohi/olo)
//   weffhi/lo 2x1,228,800 | wphi/lo 2x409,600 | tabKhi/lo 2x4,096 | gM 7,168
// ---------------------------------------------------------------------------
extern "C" void kernel_launch(void* const* d_in, const int* in_sizes, int n_in,
                              void* d_out, int out_size, void* d_ws, size_t ws_size,
                              hipStream_t stream) {
  (void)in_sizes; (void)n_in; (void)out_size; (void)ws_size;
  const float* x     = (const float*)d_in[0];
  const float* w_qkv = (const float*)d_in[1];
  const float* b_qkv = (const float*)d_in[2];
  const float* la    = (const float*)d_in[3];
  const float* lb    = (const float*)d_in[4];
  const float* tkv   = (const float*)d_in[5];
  const float* tkh   = (const float*)d_in[6];
  const float* tvv   = (const float*)d_in[7];
  const float* tvh   = (const float*)d_in[8];
  const float* wp    = (const float*)d_in[9];
  const float* b_p   = (const float*)d_in[10];

  u16* qkvhi  = (u16*)d_ws;
  u16* qkvlo  = qkvhi + (size_t)24207360;
  u16* xhi    = qkvlo + (size_t)24207360;
  u16* xlo    = xhi + (size_t)8069120;
  u16* ohi    = xhi;                       // alias (x splits dead after gemm1)
  u16* olo    = xlo;
  u16* weffhi = xlo + (size_t)8069120;
  u16* wefflo = weffhi + (size_t)1228800;
  u16* wphi   = wefflo + (size_t)1228800;
  u16* wplo   = wphi + (size_t)409600;
  u16* tabKhi = wplo + (size_t)409600;
  u16* tabKlo = tabKhi + (size_t)4096;
  u16* gM     = tabKlo + (size_t)4096;

  k_weff<<<(C3 * CC) / 256, 256, 0, stream>>>(w_qkv, la, lb, weffhi, wefflo);
  k_cvtw<<<(CC * CC) / 256, 256, 0, stream>>>(wp, wphi, wplo);
  k_prep<<<1, 256, 0, stream>>>(tkv, tkh, tabKhi, tabKlo, gM);
  int n4x = (MTOT * CC) / 4;
  k_cvt<<<(n4x + 255) / 256, 256, 0, stream>>>(x, xhi, xlo, n4x);

  // qkv = x @ weff^T + b_qkv -> split bf16 output
  int nwg1 = ((MTOT + 127) / 128) * (C3 / 128);   // 99*15 = 1485
  k_gemm_mfma<1><<<nwg1, 512, 0, stream>>>(xhi, xlo, weffhi, wefflo, b_qkv,
                                           nullptr, qkvhi, qkvlo, MTOT, C3, C3 / 128);

  // fused attention -> ohi/olo split
  k_attn<<<dim3(BB * HH, 2), 512, 0, stream>>>(qkvhi, qkvlo, tabKhi, tabKlo, gM,
                                               tvv, tvh, ohi, olo);

  // out = o @ perm3(w_proj)^T + b_proj
  int nwg2 = ((MTOT + 127) / 128) * (CC / 128);   // 99*5 = 495
  k_gemm_mfma<0><<<nwg2, 512, 0, stream>>>(ohi, olo, wphi, wplo, b_p,
                                           (float*)d_out, nullptr, nullptr, MTOT, CC, CC / 128);
}

// Round 15
// 278.788 us; speedup vs baseline: 1.7481x; 1.0070x over previous
//
#include <hip/hip_runtime.h>
#include <math.h>

#define BB 64
#define NN 197
#define HH 10
#define DD 64
#define CC 640
#define C3 1920
#define LR 64
#define MTOT (BB*NN)          // 12608
#define SCALE 0.125f

typedef unsigned short u16;
typedef __bf16 bf16x8 __attribute__((ext_vector_type(8)));
typedef float f32x4 __attribute__((ext_vector_type(4)));

__device__ __forceinline__ void split_bf16(float f, u16& hi, u16& lo) {
  unsigned u = __float_as_uint(f);
  unsigned r = u + 0x7FFF + ((u >> 16) & 1);
  u16 hb = (u16)(r >> 16);
  float fh = __uint_as_float((unsigned)hb << 16);
  float dl = f - fh;
  unsigned u2 = __float_as_uint(dl);
  unsigned r2 = u2 + 0x7FFF + ((u2 >> 16) & 1);
  hi = hb; lo = (u16)(r2 >> 16);
}

__device__ __forceinline__ u16 bf16rn(float f) {
  unsigned u = __float_as_uint(f);
  return (u16)((u + 0x7FFF + ((u >> 16) & 1)) >> 16);
}
__device__ __forceinline__ float bf16tof(u16 v) {
  return __uint_as_float((unsigned)v << 16);
}

// ---------------------------------------------------------------------------
// K1: w_eff = perm3(w_qkv + (lora_a @ lora_b)^T) -> bf16 hi/lo split
// ---------------------------------------------------------------------------
__global__ __launch_bounds__(256) void k_weff(
    const float* __restrict__ w_qkv, const float* __restrict__ la,
    const float* __restrict__ lb, u16* __restrict__ whi, u16* __restrict__ wlo) {
  int idx = blockIdx.x * 256 + threadIdx.x;      // covers 1920*640
  int i = idx / CC, j = idx % CC;
  int src = 3 * (i % CC) + (i / CC);
  float acc = w_qkv[(size_t)src * CC + j];
  const float* laj = la + (size_t)j * LR;
  const float* lbs = lb + src;
  #pragma unroll 8
  for (int r = 0; r < LR; ++r) acc = fmaf(laj[r], lbs[(size_t)r * C3], acc);
  u16 h, l; split_bf16(acc, h, l);
  whi[idx] = h; wlo[idx] = l;
}

// fp32 -> bf16 hi/lo split
__global__ __launch_bounds__(256) void k_cvt(
    const float* __restrict__ in, u16* __restrict__ hi, u16* __restrict__ lo, int n4) {
  int i = blockIdx.x * 256 + threadIdx.x;
  if (i >= n4) return;
  float4 v = ((const float4*)in)[i];
  float f[4] = {v.x, v.y, v.z, v.w};
  ushort4 H, L;
  u16 hh, ll;
  split_bf16(f[0], hh, ll); H.x = hh; L.x = ll;
  split_bf16(f[1], hh, ll); H.y = hh; L.y = ll;
  split_bf16(f[2], hh, ll); H.z = hh; L.z = ll;
  split_bf16(f[3], hh, ll); H.w = hh; L.w = ll;
  ((ushort4*)hi)[i] = H;
  ((ushort4*)lo)[i] = L;
}

__device__ __forceinline__ int perm640(int i) {
  return (i < 214) ? 3 * i : (i < 427 ? 3 * (i - 214) + 1 : 3 * (i - 427) + 2);
}

__global__ __launch_bounds__(256) void k_cvtw(
    const float* __restrict__ wp, u16* __restrict__ hi, u16* __restrict__ lo) {
  int idx = blockIdx.x * 256 + threadIdx.x;      // covers 640*640
  int i = idx / CC, j = idx % CC;
  float v = wp[(size_t)perm640(i) * CC + j];
  u16 h, l; split_bf16(v, h, l);
  hi[idx] = h; lo[idx] = l;
}

// ---------------------------------------------------------------------------
// k_prep: (a) tabK -> bf16 hi/lo. (b) gM: bucket one-hot [32t][224k],
// pre-swizzle-linearized for the V-tile layout. (c) gMT: transposed one-hot
// [224k][32t] bf16, pre-swizzle-linearized for B-frag reads
// (byte ^= ((row>>1)&3)<<4, row-internal).
// ---------------------------------------------------------------------------
__global__ __launch_bounds__(256) void k_prep(
    const float* __restrict__ tkv, const float* __restrict__ tkh,
    u16* __restrict__ thi, u16* __restrict__ tlo, u16* __restrict__ gM,
    u16* __restrict__ gMT) {
  for (int idx = threadIdx.x; idx < 4096; idx += 256) {
    int row = idx >> 6, d = idx & 63;
    float v = row < 30 ? tkv[row * 64 + d] : (row < 60 ? tkh[(row - 30) * 64 + d] : 0.f);
    u16 hh, ll; split_bf16(v, hh, ll);
    thi[idx] = hh; tlo[idx] = ll;
  }
  for (int j = threadIdx.x; j < 7168; j += 256) {
    int b = 2 * j;
    u16 v = 0;
    int r0 = b / 448;
    for (int dr = -1; dr <= 1; ++dr) {
      int row = r0 + dr;
      if (row < 0 || row >= 32) continue;
      int g = (row & 7) ^ ((row >> 3) & 7);
      int off = (b ^ (g << 4)) - row * 448;
      if (off >= 0 && off < 448) {
        int k = off >> 1;
        if (k < 197) {
          int a1 = (k == 0) ? 14 : (k - 1) / 14;
          int a2 = (k == 0) ? 14 : (k - 1) % 14;
          if (row < 16) { if (row == a1) v = 0x3F80; }
          else          { if (row - 16 == a2) v = 0x3F80; }
        }
        break;
      }
    }
    gM[j] = v;
  }
  // gMT: [224 rows=k][32 cols=t] bf16, 64B/row, swizzle row-internal
  for (int j = threadIdx.x; j < 7168; j += 256) {
    int b = 2 * j;
    int row = b >> 6;
    int off = (b & 63) ^ (((row >> 1) & 3) << 4);
    int tcol = off >> 1;
    u16 v = 0;
    if (row < 197) {
      int a1 = (row == 0) ? 14 : (row - 1) / 14;
      int a2 = (row == 0) ? 14 : (row - 1) % 14;
      if (tcol < 16) { if (tcol == a1) v = 0x3F80; }
      else           { if (tcol - 16 == a2) v = 0x3F80; }
    }
    gMT[j] = v;
  }
}

// ---------------------------------------------------------------------------
// Split-bf16 MFMA GEMM (unchanged r14): 8 waves, 64x32 sub-tile/wave,
// LDS XOR-swizzle, n-inner 1D grid + bijective XCD remap, (512,4) bounds.
// ---------------------------------------------------------------------------
template<int OSPLIT>
__global__ __launch_bounds__(512, 4) void k_gemm_mfma(
    const u16* __restrict__ Ahi, const u16* __restrict__ Alo,
    const u16* __restrict__ Bhi, const u16* __restrict__ Blo,
    const float* __restrict__ bias, float* __restrict__ Cc,
    u16* __restrict__ Chi, u16* __restrict__ Clo,
    int M, int Nc, int NT) {
  __shared__ u16 AsH[128][64];
  __shared__ u16 AsL[128][64];
  __shared__ u16 BsH[128][64];
  __shared__ u16 BsL[128][64];
  int t = threadIdx.x, w = t >> 6, l = t & 63;

  int nwg = gridDim.x, bid = blockIdx.x;
  int q8 = nwg >> 3, r8 = nwg & 7;
  int xcd = bid & 7, j8 = bid >> 3;
  int wgid = (xcd < r8 ? xcd * (q8 + 1) : r8 * (q8 + 1) + (xcd - r8) * q8) + j8;
  int mt = wgid / NT, nt = wgid - mt * NT;
  int m0 = mt * 128, n0 = nt * 128;

  int wr = w & 1, wc = w >> 1;
  f32x4 acc[4][2] = {};
  int srow = l >> 3;
  int scol = ((l & 7) ^ srow) * 8;

  for (int k0 = 0; k0 < 640; k0 += 64) {
    for (int i = w; i < 16; i += 8) {
      int row = 8 * i + srow;
      int ga = m0 + row; if (ga >= M) ga = M - 1;
      size_t offA = (size_t)ga * 640 + k0 + scol;
      size_t offB = (size_t)(n0 + row) * 640 + k0 + scol;
      __builtin_amdgcn_global_load_lds(
          (const __attribute__((address_space(1))) void*)(Ahi + offA),
          (__attribute__((address_space(3))) void*)(&AsH[8 * i][0]), 16, 0, 0);
      __builtin_amdgcn_global_load_lds(
          (const __attribute__((address_space(1))) void*)(Alo + offA),
          (__attribute__((address_space(3))) void*)(&AsL[8 * i][0]), 16, 0, 0);
      __builtin_amdgcn_global_load_lds(
          (const __attribute__((address_space(1))) void*)(Bhi + offB),
          (__attribute__((address_space(3))) void*)(&BsH[8 * i][0]), 16, 0, 0);
      __builtin_amdgcn_global_load_lds(
          (const __attribute__((address_space(1))) void*)(Blo + offB),
          (__attribute__((address_space(3))) void*)(&BsL[8 * i][0]), 16, 0, 0);
    }
    __syncthreads();
    int fr = l & 15, fq = l >> 4;
    const unsigned char* pAH = (const unsigned char*)&AsH[0][0];
    const unsigned char* pAL = (const unsigned char*)&AsL[0][0];
    const unsigned char* pBH = (const unsigned char*)&BsH[0][0];
    const unsigned char* pBL = (const unsigned char*)&BsL[0][0];
    int fsw = (fr & 7) << 4;
    #pragma unroll
    for (int ks = 0; ks < 2; ++ks) {
      int cbyte = (ks * 64 + fq * 16) ^ fsw;
      bf16x8 ah[4], al[4], bh[2], bl[2];
      #pragma unroll
      for (int mi = 0; mi < 4; ++mi) {
        int ra = (wr * 64 + 16 * mi + fr) * 128 + cbyte;
        ah[mi] = *(const bf16x8*)(pAH + ra);
        al[mi] = *(const bf16x8*)(pAL + ra);
      }
      #pragma unroll
      for (int ni = 0; ni < 2; ++ni) {
        int rb = (wc * 32 + 16 * ni + fr) * 128 + cbyte;
        bh[ni] = *(const bf16x8*)(pBH + rb);
        bl[ni] = *(const bf16x8*)(pBL + rb);
      }
      #pragma unroll
      for (int mi = 0; mi < 4; ++mi)
        #pragma unroll
        for (int ni = 0; ni < 2; ++ni) {
          acc[mi][ni] = __builtin_amdgcn_mfma_f32_16x16x32_bf16(ah[mi], bh[ni], acc[mi][ni], 0, 0, 0);
          acc[mi][ni] = __builtin_amdgcn_mfma_f32_16x16x32_bf16(al[mi], bh[ni], acc[mi][ni], 0, 0, 0);
          acc[mi][ni] = __builtin_amdgcn_mfma_f32_16x16x32_bf16(ah[mi], bl[ni], acc[mi][ni], 0, 0, 0);
        }
    }
    __syncthreads();
  }

  int fr = l & 15, fq = l >> 4;
  #pragma unroll
  for (int mi = 0; mi < 4; ++mi) {
    #pragma unroll
    for (int ni = 0; ni < 2; ++ni) {
      int col = n0 + wc * 32 + 16 * ni + fr;
      float bv = bias[col];
      #pragma unroll
      for (int r = 0; r < 4; ++r) {
        int row = m0 + wr * 64 + 16 * mi + fq * 4 + r;
        if (row < M) {
          float val = acc[mi][ni][r] + bv;
          if (OSPLIT) {
            u16 hh, ll; split_bf16(val, hh, ll);
            Chi[(size_t)row * Nc + col] = hh;
            Clo[(size_t)row * Nc + col] = ll;
          } else {
            Cc[(size_t)row * Nc + col] = val;
          }
        }
      }
    }
  }
}

// ---------------------------------------------------------------------------
// Fused MFMA attention v9: r13/r14 structure (512 thr, q-tile 128, 2 barriers,
// wave-local tail) with the softmax GATHER moved to MFMA:
// S_rel[q,k] = sum_t Pshift[q][t] * MT[k][t], MT = transposed bucket one-hot
// (staged from gMT into the Wb region -- dead until after B2). Pshift built
// per-lane (8 scalar PvB reads, 1 div/mod) and fed as the A-frag of 13 MFMAs
// accumulating into sacc. Kills 104 scalar LDS reads + ~110 VALU per lane.
// LDS 157,696 B: MT @141312 (S phase) -> Wb @141312 (post-B2).
// ---------------------------------------------------------------------------
__global__ __launch_bounds__(512, 2) void k_attn(
    const u16* __restrict__ qkvhi, const u16* __restrict__ qkvlo,
    const u16* __restrict__ tabKhi, const u16* __restrict__ tabKlo,
    const u16* __restrict__ gM, const u16* __restrict__ gMT,
    const float* __restrict__ tvv, const float* __restrict__ tvh,
    u16* __restrict__ ohi, u16* __restrict__ olo) {
  __shared__ __align__(16) unsigned char LDS[157696];
  unsigned char* Akhi = LDS;
  unsigned char* Aklo = LDS + 34816;
  unsigned char* VhM  = LDS + 69632;
  unsigned char* TvT  = LDS + 112640;
  unsigned char* PvB  = LDS + 120832;
  float* BvBh = (float*)(LDS + 120832);      // [128] stride 34 f32
  unsigned char* MTl  = LDS + 141312;        // [224][32] bf16 swz (S phase)
  unsigned char* Wb   = LDS + 141312;        // post-B2
  unsigned char* Pm   = LDS;

  int bh = blockIdx.x, b = bh / HH, h = bh % HH, qt = blockIdx.y;
  int t = threadIdx.x, w = t >> 6, l = t & 63;
  int fr = l & 15, fq = l >> 4;
  int q0 = 128 * qt;
  const size_t qbase = (size_t)(b * NN) * C3;

  // ---- staging: K hi+lo + tables (glds, pre-swizzled source) ----
  int kr = l >> 3;
  int chunk = ((l & 7) ^ (kr & 7)) * 8;
  for (int i = w; i < 34; i += 8) {
    int rr = 8 * i + kr;
    const u16 *sh, *sl;
    if (rr < 208) {
      int kk = rr > 196 ? 196 : rr;
      sh = qkvhi + qbase + (size_t)kk * C3 + CC + h * DD + chunk;
      sl = qkvlo + qbase + (size_t)kk * C3 + CC + h * DD + chunk;
    } else {
      int tr = rr - 208;
      sh = tabKhi + tr * 64 + chunk;
      sl = tabKlo + tr * 64 + chunk;
    }
    __builtin_amdgcn_global_load_lds(
        (const __attribute__((address_space(1))) void*)sh,
        (__attribute__((address_space(3))) void*)(Akhi + i * 1024), 16, 0, 0);
    __builtin_amdgcn_global_load_lds(
        (const __attribute__((address_space(1))) void*)sl,
        (__attribute__((address_space(3))) void*)(Aklo + i * 1024), 16, 0, 0);
  }
  // M one-hot rows -> VhM rows 64..95
  for (int i = w; i < 14; i += 8) {
    __builtin_amdgcn_global_load_lds(
        (const __attribute__((address_space(1))) void*)(gM + i * 512 + l * 8),
        (__attribute__((address_space(3))) void*)(VhM + 28672 + i * 1024), 16, 0, 0);
  }
  // MT transposed one-hot -> MTl (Wb region, dead until post-B2)
  for (int i = w; i < 14; i += 8) {
    __builtin_amdgcn_global_load_lds(
        (const __attribute__((address_space(1))) void*)(gMT + i * 512 + l * 8),
        (__attribute__((address_space(3))) void*)(MTl + i * 1024), 16, 0, 0);
  }
  // V^T hi [64d][224k] swz
  for (int idx = t; idx < 1576; idx += 512) {
    int k = idx >> 3, d0v = (idx & 7) * 8;
    size_t off = qbase + (size_t)k * C3 + 2 * CC + h * DD + d0v;
    uint4 vh4 = *(const uint4*)(qkvhi + off);
    u16 eh[8] = {(u16)vh4.x, (u16)(vh4.x >> 16), (u16)vh4.y, (u16)(vh4.y >> 16),
                 (u16)vh4.z, (u16)(vh4.z >> 16), (u16)vh4.w, (u16)(vh4.w >> 16)};
    #pragma unroll
    for (int jj = 0; jj < 8; ++jj) {
      int d = d0v + jj;
      int byte = (d * 224 + k) * 2; byte ^= (((d & 7) ^ ((d >> 3) & 7)) << 4);
      *(u16*)(VhM + byte) = eh[jj];
    }
  }
  for (int idx = t; idx < 64 * 27; idx += 512) {   // V pad cols 197..223
    int d = idx / 27, k = 197 + idx % 27;
    int byte = (d * 224 + k) * 2; byte ^= (((d & 7) ^ ((d >> 3) & 7)) << 4);
    *(u16*)(VhM + byte) = 0;
  }
  // TvT [64d][64t]
  for (int i = t; i < 4096; i += 512) {
    int d = i >> 6, tt = i & 63;
    float vv = 0.f;
    if (tt < 30) vv = tvv[tt * 64 + d];
    else if (tt >= 32 && tt < 62) vv = tvh[(tt - 32) * 64 + d];
    int byte = (d * 64 + tt) * 2; byte ^= (((d & 7) ^ ((d >> 3) & 7)) << 4);
    *(u16*)(TvT + byte) = bf16rn(vv);
  }
  // Q frags
  bool active = (q0 + 16 * w) < NN;
  bf16x8 qh[2], ql_[2];
  {
    int qg = q0 + 16 * w + fr; int qc = qg > 196 ? 196 : qg;
    const u16* qr  = qkvhi + qbase + (size_t)qc * C3 + h * DD;
    const u16* qr2 = qkvlo + qbase + (size_t)qc * C3 + h * DD;
    qh[0]  = *(const bf16x8*)(qr + 8 * fq);
    qh[1]  = *(const bf16x8*)(qr + 32 + 8 * fq);
    ql_[0] = *(const bf16x8*)(qr2 + 8 * fq);
    ql_[1] = *(const bf16x8*)(qr2 + 32 + 8 * fq);
  }
  __syncthreads();   // B1: staging done

  // ---- S: fused 3-pass; PvB; Pshift MFMA rel; mask+scale; softmax ----
  float ex[13][4];
  float inv[4];
  if (active) {
    f32x4 sacc[17] = {};
    #pragma unroll
    for (int ks = 0; ks < 2; ++ks)
      #pragma unroll
      for (int nf = 0; nf < 17; ++nf) {
        int row = 16 * nf + fr;
        int byte = row * 128 + 64 * ks + 16 * fq; byte ^= (row & 7) << 4;
        bf16x8 kf = *(const bf16x8*)(Akhi + byte);
        bf16x8 lf = *(const bf16x8*)(Aklo + byte);
        sacc[nf] = __builtin_amdgcn_mfma_f32_16x16x32_bf16(qh[ks],  kf, sacc[nf], 0, 0, 0);
        sacc[nf] = __builtin_amdgcn_mfma_f32_16x16x32_bf16(ql_[ks], kf, sacc[nf], 0, 0, 0);
        sacc[nf] = __builtin_amdgcn_mfma_f32_16x16x32_bf16(qh[ks],  lf, sacc[nf], 0, 0, 0);
      }
    // Pv/Ph table frags -> PvB (own rows; stride 160B)
    #pragma unroll
    for (int nf = 13; nf < 17; ++nf)
      #pragma unroll
      for (int r = 0; r < 4; ++r) {
        int c = 16 * (nf - 13) + fr;
        if (c < 60) {
          int row = 16 * w + 4 * fq + r;
          *(u16*)(PvB + row * 160 + 2 * c) = bf16rn(sacc[nf][r]);
        }
      }
    // Pshift A-frag: lane (fr,fq) holds Pshift[q=16w+fr][t=8fq..8fq+7]
    bf16x8 psf;
    {
      int qrow = 16 * w + fr;
      int qg2 = q0 + qrow; int qc2 = qg2 > 196 ? 196 : qg2;
      const unsigned char* rowb = PvB + qrow * 160;
      u16 tmp[8];
      if (qc2 == 0) {
        u16 v0 = *(const u16*)(rowb);
        u16 h0 = *(const u16*)(rowb + 60);
        #pragma unroll
        for (int j = 0; j < 8; ++j) tmp[j] = (8 * fq + j < 16) ? v0 : h0;
      } else {
        int gq2 = (qc2 - 1) / 14, cq2 = (qc2 - 1) % 14;
        #pragma unroll
        for (int j = 0; j < 8; ++j) {
          int tt2 = 8 * fq + j;
          u16 v = 0;
          if (tt2 < 14)       v = *(const u16*)(rowb + 2 * (tt2 - gq2 + 15));
          else if (tt2 == 14) v = *(const u16*)(rowb);
          else if (tt2 >= 16 && tt2 < 30) v = *(const u16*)(rowb + 60 + 2 * (tt2 - 16 - cq2 + 15));
          else if (tt2 == 30) v = *(const u16*)(rowb + 60);
          tmp[j] = v;
        }
      }
      unsigned p0 = tmp[0] | ((unsigned)tmp[1] << 16);
      unsigned p1 = tmp[2] | ((unsigned)tmp[3] << 16);
      unsigned p2 = tmp[4] | ((unsigned)tmp[5] << 16);
      unsigned p3 = tmp[6] | ((unsigned)tmp[7] << 16);
      uint4 pk = make_uint4(p0, p1, p2, p3);
      psf = *(const bf16x8*)&pk;
    }
    // rel-k via MFMA: sacc[nf] += Pshift @ MT[16nf..16nf+15][32t]
    #pragma unroll
    for (int nf = 0; nf < 13; ++nf) {
      int row = 16 * nf + fr;
      int byte = row * 64 + 16 * fq; byte ^= (((row >> 1) & 3) << 4);
      bf16x8 mtf = *(const bf16x8*)(MTl + byte);
      sacc[nf] = __builtin_amdgcn_mfma_f32_16x16x32_bf16(psf, mtf, sacc[nf], 0, 0, 0);
    }
    // mask + scale + row max
    float mrow[4] = {-1e30f, -1e30f, -1e30f, -1e30f};
    #pragma unroll
    for (int nf = 0; nf < 13; ++nf) {
      int k = 16 * nf + fr;
      bool vk = k < 197;
      #pragma unroll
      for (int r = 0; r < 4; ++r) {
        float s = vk ? sacc[nf][r] * SCALE : -1e30f;
        ex[nf][r] = s;
        mrow[r] = fmaxf(mrow[r], s);
      }
    }
    #pragma unroll
    for (int r = 0; r < 4; ++r)
      #pragma unroll
      for (int mk = 1; mk < 16; mk <<= 1) mrow[r] = fmaxf(mrow[r], __shfl_xor(mrow[r], mk));
    float sum[4] = {0.f, 0.f, 0.f, 0.f};
    #pragma unroll
    for (int nf = 0; nf < 13; ++nf)
      #pragma unroll
      for (int r = 0; r < 4; ++r) {
        ex[nf][r] = __expf(ex[nf][r] - mrow[r]);
        sum[r] += ex[nf][r];
      }
    #pragma unroll
    for (int r = 0; r < 4; ++r) {
      #pragma unroll
      for (int mk = 1; mk < 16; mk <<= 1) sum[r] += __shfl_xor(sum[r], mk);
      inv[r] = 1.f / sum[r];
    }
  }
  __syncthreads();   // B2: all K/PvB/MT reads done (LAST barrier)

  // ---- P write (own rows only) ----
  #pragma unroll
  for (int nf = 0; nf < 14; ++nf)
    #pragma unroll
    for (int r = 0; r < 4; ++r) {
      int k = 16 * nf + fr;
      int row = 16 * w + 4 * fq + r;
      float p = 0.f;
      if (active && nf < 13 && k < 197) p = ex[nf][r] * inv[r];
      int byte = row * 448 + 2 * k; byte ^= (((row & 7) ^ ((row >> 3) & 7)) << 4);
      *(u16*)(Pm + byte) = bf16rn(p);
    }

  // ---- AV + bucket MFMAs (wave-local) ----
  int prow = 16 * w + fr;
  int pswz = ((prow & 7) ^ ((prow >> 3) & 7)) << 4;
  f32x4 ov[4] = {};
  f32x4 om[2] = {};
  #pragma unroll
  for (int ks = 0; ks < 7; ++ks) {
    int co = 64 * ks + 16 * fq;
    bf16x8 pah = *(const bf16x8*)(Pm + ((prow * 448 + co) ^ pswz));
    #pragma unroll
    for (int nf = 0; nf < 4; ++nf) {
      int vrow = 16 * nf + fr;
      int vswz = ((vrow & 7) ^ ((vrow >> 3) & 7)) << 4;
      bf16x8 v = *(const bf16x8*)(VhM + ((vrow * 448 + co) ^ vswz));
      ov[nf] = __builtin_amdgcn_mfma_f32_16x16x32_bf16(pah, v, ov[nf], 0, 0, 0);
    }
    #pragma unroll
    for (int mf = 0; mf < 2; ++mf) {
      int mr = 64 + 16 * mf + fr;
      int mswz = ((mr & 7) ^ ((mr >> 3) & 7)) << 4;
      bf16x8 mv = *(const bf16x8*)(VhM + ((mr * 448 + co) ^ mswz));
      om[mf] = __builtin_amdgcn_mfma_f32_16x16x32_bf16(pah, mv, om[mf], 0, 0, 0);
    }
  }
  #pragma unroll
  for (int mf = 0; mf < 2; ++mf)
    #pragma unroll
    for (int r = 0; r < 4; ++r)
      BvBh[(16 * w + 4 * fq + r) * 34 + 16 * mf + fr] = om[mf][r];

  // ---- W build (wave-local) ----
  {
    int row = 16 * w + (l >> 2);
    int qg = q0 + row;
    int half = (l & 3) >> 1;
    int u0 = (l & 1) * 16;
    const float* bb = &BvBh[row * 34 + 16 * half];
    u16 wv[16];
    if (qg == 0) {
      float s = 0.f;
      #pragma unroll
      for (int a = 0; a < 15; ++a) s += bb[a];
      u16 sv = bf16rn(s);
      #pragma unroll
      for (int j = 0; j < 16; ++j) wv[j] = (u0 + j == 0) ? sv : (u16)0;
    } else if (qg < NN) {
      int m = qg - 1;
      int sel = half ? (m % 14) : (m / 14);
      #pragma unroll
      for (int j = 0; j < 16; ++j) {
        int u = u0 + j;
        float val;
        if (u == 0) val = bb[14];
        else {
          int a = u - 15 + sel;
          val = (a >= 0 && a < 14) ? bb[a] : 0.f;
        }
        wv[j] = bf16rn(val);
      }
    } else {
      #pragma unroll
      for (int j = 0; j < 16; ++j) wv[j] = 0;
    }
    uint4 p0, p1;
    p0.x = wv[0]  | ((unsigned)wv[1]  << 16);
    p0.y = wv[2]  | ((unsigned)wv[3]  << 16);
    p0.z = wv[4]  | ((unsigned)wv[5]  << 16);
    p0.w = wv[6]  | ((unsigned)wv[7]  << 16);
    p1.x = wv[8]  | ((unsigned)wv[9]  << 16);
    p1.y = wv[10] | ((unsigned)wv[11] << 16);
    p1.z = wv[12] | ((unsigned)wv[13] << 16);
    p1.w = wv[14] | ((unsigned)wv[15] << 16);
    int base = row * 128 + (l & 3) * 32;
    int sz = ((row & 7) ^ ((row >> 3) & 7)) << 4;
    *(uint4*)(Wb + (base ^ sz)) = p0;
    *(uint4*)(Wb + ((base + 16) ^ sz)) = p1;
  }

  // ---- rel-v MFMA: out_rel = W @ TvT ----
  f32x4 rv[4] = {};
  #pragma unroll
  for (int ks2 = 0; ks2 < 2; ++ks2) {
    int co = 64 * ks2 + 16 * fq;
    bf16x8 wa = *(const bf16x8*)(Wb + ((prow * 128 + co) ^ pswz));
    #pragma unroll
    for (int nf = 0; nf < 4; ++nf) {
      int vrow = 16 * nf + fr;
      int vswz = ((vrow & 7) ^ ((vrow >> 3) & 7)) << 4;
      bf16x8 tv = *(const bf16x8*)(TvT + ((vrow * 128 + co) ^ vswz));
      rv[nf] = __builtin_amdgcn_mfma_f32_16x16x32_bf16(wa, tv, rv[nf], 0, 0, 0);
    }
  }

  // ---- store ----
  #pragma unroll
  for (int r = 0; r < 4; ++r) {
    int qrl = 16 * w + 4 * fq + r;
    int qg = q0 + qrl;
    if (qg >= NN) continue;
    size_t ob = (size_t)(b * NN + qg) * CC + h * DD;
    #pragma unroll
    for (int nf = 0; nf < 4; ++nf) {
      int d = 16 * nf + fr;
      float o = ov[nf][r] + rv[nf][r];
      u16 hh, ll;
      split_bf16(o, hh, ll);
      ohi[ob + d] = hh; olo[ob + d] = ll;
    }
  }
}

// ---------------------------------------------------------------------------
// Workspace (u16 units, ~135.7 MB):
//   qkvhi 24,207,360 | qkvlo 24,207,360 | xhi/xlo 2x8,069,120 (reused ohi/olo)
//   weffhi/lo 2x1,228,800 | wphi/lo 2x409,600 | tabKhi/lo 2x4,096
//   gM 7,168 | gMT 7,168
// ---------------------------------------------------------------------------
extern "C" void kernel_launch(void* const* d_in, const int* in_sizes, int n_in,
                              void* d_out, int out_size, void* d_ws, size_t ws_size,
                              hipStream_t stream) {
  (void)in_sizes; (void)n_in; (void)out_size; (void)ws_size;
  const float* x     = (const float*)d_in[0];
  const float* w_qkv = (const float*)d_in[1];
  const float* b_qkv = (const float*)d_in[2];
  const float* la    = (const float*)d_in[3];
  const float* lb    = (const float*)d_in[4];
  const float* tkv   = (const float*)d_in[5];
  const float* tkh   = (const float*)d_in[6];
  const float* tvv   = (const float*)d_in[7];
  const float* tvh   = (const float*)d_in[8];
  const float* wp    = (const float*)d_in[9];
  const float* b_p   = (const float*)d_in[10];

  u16* qkvhi  = (u16*)d_ws;
  u16* qkvlo  = qkvhi + (size_t)24207360;
  u16* xhi    = qkvlo + (size_t)24207360;
  u16* xlo    = xhi + (size_t)8069120;
  u16* ohi    = xhi;                       // alias (x splits dead after gemm1)
  u16* olo    = xlo;
  u16* weffhi = xlo + (size_t)8069120;
  u16* wefflo = weffhi + (size_t)1228800;
  u16* wphi   = wefflo + (size_t)1228800;
  u16* wplo   = wphi + (size_t)409600;
  u16* tabKhi = wplo + (size_t)409600;
  u16* tabKlo = tabKhi + (size_t)4096;
  u16* gM     = tabKlo + (size_t)4096;
  u16* gMT    = gM + (size_t)7168;

  k_weff<<<(C3 * CC) / 256, 256, 0, stream>>>(w_qkv, la, lb, weffhi, wefflo);
  k_cvtw<<<(CC * CC) / 256, 256, 0, stream>>>(wp, wphi, wplo);
  k_prep<<<1, 256, 0, stream>>>(tkv, tkh, tabKhi, tabKlo, gM, gMT);
  int n4x = (MTOT * CC) / 4;
  k_cvt<<<(n4x + 255) / 256, 256, 0, stream>>>(x, xhi, xlo, n4x);

  // qkv = x @ weff^T + b_qkv -> split bf16 output
  int nwg1 = ((MTOT + 127) / 128) * (C3 / 128);   // 99*15 = 1485
  k_gemm_mfma<1><<<nwg1, 512, 0, stream>>>(xhi, xlo, weffhi, wefflo, b_qkv,
                                           nullptr, qkvhi, qkvlo, MTOT, C3, C3 / 128);

  // fused attention -> ohi/olo split
  k_attn<<<dim3(BB * HH, 2), 512, 0, stream>>>(qkvhi, qkvlo, tabKhi, tabKlo, gM, gMT,
                                               tvv, tvh, ohi, olo);

  // out = o @ perm3(w_proj)^T + b_proj
  int nwg2 = ((MTOT + 127) / 128) * (CC / 128);   // 99*5 = 495
  k_gemm_mfma<0><<<nwg2, 512, 0, stream>>>(ohi, olo, wphi, wplo, b_p,
                                           (float*)d_out, nullptr, nullptr, MTOT, CC, CC / 128);
}